// Round 12
// baseline (1854.645 us; speedup 1.0000x reference)
//
#include <hip/hip_runtime.h>
#include <hip/hip_fp16.h>
#include <math.h>

#define BB 16
#define CIN 40
#define CH 256
#define NN 1024
#define NLAYERS 6

typedef unsigned short ush;
typedef __attribute__((ext_vector_type(8))) short bh8;
typedef __attribute__((ext_vector_type(8))) _Float16 h8;
typedef __attribute__((ext_vector_type(4))) float f4;

__device__ __forceinline__ ush f2h(float x) {
  __half h = __float2half(x);
  return *(ush*)&h;
}
__device__ __forceinline__ float h2f(ush u) {
  __half h = *(__half*)&u;
  return __half2float(h);
}
__device__ __forceinline__ float fast_tanh(float x) {
  const float e = __expf(2.0f * x);
  return (e - 1.0f) / (e + 1.0f);
}

#define GLD16(gp, lp) __builtin_amdgcn_global_load_lds( \
    (const __attribute__((address_space(1))) void*)(gp), \
    (__attribute__((address_space(3))) void*)(lp), 16, 0, 0)

// ---------- block reduction (256 threads = 4 waves) ----------
__device__ __forceinline__ float blockReduceSum(float v) {
  __shared__ float sred[4];
  const int lane = threadIdx.x & 63;
  const int wid  = threadIdx.x >> 6;
  #pragma unroll
  for (int off = 32; off > 0; off >>= 1) v += __shfl_down(v, off, 64);
  __syncthreads();
  if (lane == 0) sred[wid] = v;
  __syncthreads();
  return sred[0] + sred[1] + sred[2] + sred[3];
}

// ================= gram core (fp16, asym 2-product): A pair + B hi plane, 128x128 ==========
__device__ __forceinline__ void stageG(
    const ush* __restrict__ Ah, const ush* __restrict__ Al,
    const ush* __restrict__ Bh, const int s, const int kt, ush* buf) {
  const int lane = threadIdx.x & 63;
  const int wid = threadIdx.x >> 6;
  const int srow = lane >> 2;
  const int sl = (lane & 3) ^ ((srow >> 1) & 3);
  #pragma unroll
  for (int cc = 0; cc < 6; cc++) {
    const int c = wid * 6 + cc;
    const ush* src;
    if (c < 8)       src = Ah + (size_t)(c * 16 + srow) * s + kt + sl * 8;
    else if (c < 16) src = Al + (size_t)((c - 8) * 16 + srow) * s + kt + sl * 8;
    else             src = Bh + (size_t)((c - 16) * 16 + srow) * s + kt + sl * 8;
    GLD16(src, buf + c * 512 + lane * 8);
  }
}

__device__ __forceinline__ void computeG(const ush* buf, f4 acc[4][4]) {
  const int lane = threadIdx.x & 63;
  const int wid = threadIdx.x >> 6;
  const int wr = wid >> 1, wc = wid & 1;
  const int frow = lane & 15;
  const int slot8 = (((lane >> 4) ^ ((frow >> 1) & 3)) << 3);
  h8 ah[4], al[4], b_[4];
  #pragma unroll
  for (int mi = 0; mi < 4; mi++) {
    const int off = (wr * 64 + mi * 16 + frow) * 32 + slot8;
    ah[mi] = *(const h8*)&buf[off];
    al[mi] = *(const h8*)&buf[4096 + off];
  }
  #pragma unroll
  for (int ni = 0; ni < 4; ni++) {
    const int off = (wc * 64 + ni * 16 + frow) * 32 + slot8;
    b_[ni] = *(const h8*)&buf[8192 + off];
  }
  #pragma unroll
  for (int mi = 0; mi < 4; mi++)
    #pragma unroll
    for (int ni = 0; ni < 4; ni++) {
      acc[mi][ni] = __builtin_amdgcn_mfma_f32_16x16x32_f16(ah[mi], b_[ni], acc[mi][ni], 0, 0, 0);
      acc[mi][ni] = __builtin_amdgcn_mfma_f32_16x16x32_f16(al[mi], b_[ni], acc[mi][ni], 0, 0, 0);
    }
}

// ================= cvall core (fp16): A 1 plane + B 2 planes, 128x128, 2 products ==========
__device__ __forceinline__ void stageCV(
    const ush* __restrict__ Ap, const int sA,
    const ush* __restrict__ Bh, const ush* __restrict__ Bl, const int sB,
    const int kt, ush* buf) {
  const int lane = threadIdx.x & 63;
  const int wid = threadIdx.x >> 6;
  const int srow = lane >> 2;
  const int sl = (lane & 3) ^ ((srow >> 1) & 3);
  #pragma unroll
  for (int cc = 0; cc < 6; cc++) {
    const int c = wid * 6 + cc;
    const ush* src;
    if (c < 8)       src = Ap + (size_t)(c * 16 + srow) * sA + kt + sl * 8;
    else if (c < 16) src = Bh + (size_t)((c - 8) * 16 + srow) * sB + kt + sl * 8;
    else             src = Bl + (size_t)((c - 16) * 16 + srow) * sB + kt + sl * 8;
    GLD16(src, buf + c * 512 + lane * 8);
  }
}

__device__ __forceinline__ void computeCV(const ush* buf, f4 acc[4][4]) {
  const int lane = threadIdx.x & 63;
  const int wid = threadIdx.x >> 6;
  const int wr = wid >> 1, wc = wid & 1;
  const int frow = lane & 15;
  const int slot8 = (((lane >> 4) ^ ((frow >> 1) & 3)) << 3);
  h8 a_[4], bh_[4], bl_[4];
  #pragma unroll
  for (int mi = 0; mi < 4; mi++) {
    const int off = (wr * 64 + mi * 16 + frow) * 32 + slot8;
    a_[mi] = *(const h8*)&buf[off];
  }
  #pragma unroll
  for (int ni = 0; ni < 4; ni++) {
    const int off = (wc * 64 + ni * 16 + frow) * 32 + slot8;
    bh_[ni] = *(const h8*)&buf[4096 + off];
    bl_[ni] = *(const h8*)&buf[8192 + off];
  }
  #pragma unroll
  for (int mi = 0; mi < 4; mi++)
    #pragma unroll
    for (int ni = 0; ni < 4; ni++) {
      acc[mi][ni] = __builtin_amdgcn_mfma_f32_16x16x32_f16(a_[mi], bh_[ni], acc[mi][ni], 0, 0, 0);
      acc[mi][ni] = __builtin_amdgcn_mfma_f32_16x16x32_f16(a_[mi], bl_[ni], acc[mi][ni], 0, 0, 0);
    }
}

// ================= mm1 core (fp16): A 2 planes + B 1 plane, 64x128, 2 products =============
__device__ __forceinline__ void stageMM(
    const ush* __restrict__ Ah, const ush* __restrict__ Al, const int sA,
    const ush* __restrict__ Bp, const int sB, const int kt, ush* buf) {
  const int lane = threadIdx.x & 63;
  const int wid = threadIdx.x >> 6;
  const int srow = lane >> 2;
  const int sl = (lane & 3) ^ ((srow >> 1) & 3);
  #pragma unroll
  for (int cc = 0; cc < 4; cc++) {
    const int c = wid * 4 + cc;
    const ush* src;
    if (c < 4)       src = Ah + (size_t)(c * 16 + srow) * sA + kt + sl * 8;
    else if (c < 8)  src = Al + (size_t)((c - 4) * 16 + srow) * sA + kt + sl * 8;
    else             src = Bp + (size_t)((c - 8) * 16 + srow) * sB + kt + sl * 8;
    GLD16(src, buf + c * 512 + lane * 8);
  }
}

__device__ __forceinline__ void computeMM(const ush* buf, f4 acc[4][2]) {
  const int lane = threadIdx.x & 63;
  const int wid = threadIdx.x >> 6;
  const int frow = lane & 15;
  const int slot8 = (((lane >> 4) ^ ((frow >> 1) & 3)) << 3);
  h8 ah[4], al[4], b_[2];
  #pragma unroll
  for (int mi = 0; mi < 4; mi++) {
    const int off = (mi * 16 + frow) * 32 + slot8;
    ah[mi] = *(const h8*)&buf[off];
    al[mi] = *(const h8*)&buf[2048 + off];
  }
  #pragma unroll
  for (int ni = 0; ni < 2; ni++) {
    const int off = (wid * 32 + ni * 16 + frow) * 32 + slot8;
    b_[ni] = *(const h8*)&buf[4096 + off];
  }
  #pragma unroll
  for (int mi = 0; mi < 4; mi++)
    #pragma unroll
    for (int ni = 0; ni < 2; ni++) {
      acc[mi][ni] = __builtin_amdgcn_mfma_f32_16x16x32_f16(ah[mi], b_[ni], acc[mi][ni], 0, 0, 0);
      acc[mi][ni] = __builtin_amdgcn_mfma_f32_16x16x32_f16(al[mi], b_[ni], acc[mi][ni], 0, 0, 0);
    }
}

// ---------- Z0 = tanh(K0 @ Zin) * mask, 8 outputs/block (+ row stats) ----------
__global__ void k0_kernel(const float* __restrict__ Zin, const float* __restrict__ K0,
                          const float* __restrict__ mask, float* __restrict__ Zc,
                          float* __restrict__ statS1, float* __restrict__ statS2) {
  const int b = blockIdx.y;
  const int o0 = blockIdx.x * 8;
  __shared__ float w[8][CIN];
  for (int i = threadIdx.x; i < 8 * CIN; i += 256)
    w[i / CIN][i % CIN] = K0[(o0 + i / CIN) * CIN + i % CIN];
  __syncthreads();
  float s1[8], s2[8];
  #pragma unroll
  for (int o = 0; o < 8; o++) { s1[o] = 0.f; s2[o] = 0.f; }
  for (int n = threadIdx.x; n < NN; n += 256) {
    float zv[CIN];
    #pragma unroll
    for (int c = 0; c < CIN; c++) zv[c] = Zin[((size_t)b * CIN + c) * NN + n];
    const float mn = mask[b * NN + n];
    #pragma unroll
    for (int o = 0; o < 8; o++) {
      float acc = 0.f;
      #pragma unroll
      for (int c = 0; c < CIN; c++) acc += w[o][c] * zv[c];
      const float z = fast_tanh(acc) * mn;
      Zc[((size_t)b * CH + o0 + o) * NN + n] = z;
      s1[o] += z; s2[o] += z * z;
    }
  }
  for (int o = 0; o < 8; o++) {
    const float r1 = blockReduceSum(s1[o]);
    const float r2 = blockReduceSum(s2[o]);
    if (threadIdx.x == 0) {
      const size_t base = ((size_t)b * CH + o0 + o) * 8;
      statS1[base] = r1; statS2[base] = r2;
      #pragma unroll
      for (int k = 1; k < 8; k++) { statS1[base + k] = 0.f; statS2[base + k] = 0.f; }
    }
  }
}

// ---------- masksum + centered pos-row values ----------
__global__ void masksum_kernel(const float* __restrict__ mask, float* __restrict__ msum,
                               float* __restrict__ posv) {
  const int b = blockIdx.x;
  float v = 0.f, p = 0.f;
  for (int n = threadIdx.x; n < NN; n += 256) {
    const float m = mask[b * NN + n];
    v += m;
    p += 0.5f * ((float)n * (1.0f / (NN - 1))) * m;
  }
  v = blockReduceSum(v);
  p = blockReduceSum(p);
  const float pm = p * (1.0f / NN);
  if (threadIdx.x == 0) msum[b] = v;
  for (int n = threadIdx.x; n < NN; n += 256)
    posv[b * NN + n] = 0.5f * ((float)n * (1.0f / (NN - 1))) * mask[b * NN + n] - pm;
}

// ---------- W prep: fp16 single plane of W and W^T for all 18 matrices ----------
__global__ void wprep_kernel(const float* __restrict__ W, ush* __restrict__ Wm,
                             ush* __restrict__ Wt) {
  __shared__ float t[64][65];
  const int mat = blockIdx.y;
  const int ty = blockIdx.x >> 2, tx = blockIdx.x & 3;
  const float* src = W + (size_t)mat * CH * CH;
  const int tid = threadIdx.x;
  const int lr = tid >> 2;
  const int lc = (tid & 3) * 16;
  float v[16];
  #pragma unroll
  for (int j = 0; j < 16; j += 4)
    *(float4*)&v[j] = *(const float4*)&src[(size_t)(ty * 64 + lr) * CH + tx * 64 + lc + j];
  ush hv[16];
  #pragma unroll
  for (int j = 0; j < 16; j++) {
    hv[j] = f2h(v[j]);
    t[lr][lc + j] = v[j];
  }
  const size_t offm = (size_t)mat * CH * CH + (size_t)(ty * 64 + lr) * CH + tx * 64 + lc;
  #pragma unroll
  for (int j = 0; j < 16; j += 4)
    *(ushort4*)&Wm[offm + j] = *(ushort4*)&hv[j];
  __syncthreads();
  #pragma unroll
  for (int j = 0; j < 16; j++) hv[j] = f2h(t[lc + j][lr]);
  const size_t offt = (size_t)mat * CH * CH + (size_t)(tx * 64 + lr) * CH + ty * 64 + lc;
  #pragma unroll
  for (int j = 0; j < 16; j += 4)
    *(ushort4*)&Wt[offt + j] = *(ushort4*)&hv[j];
}

// ---------- transpose+split: Zcur fp32 [CH][NN] -> fp16 splits [NN][CH] (pre-loop) ----------
__global__ void tsplitZ_kernel(const float* __restrict__ in, ush* __restrict__ Th,
                               ush* __restrict__ Tl) {
  __shared__ float t[32][65];
  const int b = blockIdx.z;
  const int n0 = blockIdx.x * 64;
  const int k0 = blockIdx.y * 32;
  const float* src = in + (size_t)b * CH * NN;
  const int tid = threadIdx.x;
  const int lr = tid >> 3;
  const int lc = (tid & 7) * 8;
  const int gk = k0 + lr;
  *(float4*)&t[lr][lc]     = *(const float4*)&src[(size_t)gk * NN + n0 + lc];
  *(float4*)&t[lr][lc + 4] = *(const float4*)&src[(size_t)gk * NN + n0 + lc + 4];
  __syncthreads();
  const int on = tid >> 2;
  const int ok = (tid & 3) * 8;
  ush hv[8], lv[8];
  #pragma unroll
  for (int j = 0; j < 8; j++) {
    const float v = t[ok + j][on];
    hv[j] = f2h(v); lv[j] = f2h(v - h2f(hv[j]));
  }
  const size_t off = ((size_t)b * NN + n0 + on) * CH + k0 + ok;
  *(ushort4*)&Th[off] = *(ushort4*)&hv[0];
  *(ushort4*)&Th[off + 4] = *(ushort4*)&hv[4];
  *(ushort4*)&Tl[off] = *(ushort4*)&lv[0];
  *(ushort4*)&Tl[off + 4] = *(ushort4*)&lv[4];
}

// ---------- tsplitY2: Z splits -> normalized Y fp16 splits + n2 partials (stats inlined) ----
__global__ void tsplitY2_kernel(const ush* __restrict__ Zsh, const ush* __restrict__ Zsl,
                                const float* __restrict__ mask,
                                const float* __restrict__ statS1, const float* __restrict__ statS2,
                                const float* __restrict__ msum, ush* __restrict__ Th,
                                ush* __restrict__ Tl, float* __restrict__ n2part) {
  __shared__ float smu[32], srs[32];
  const int b = blockIdx.z;
  const int n0 = blockIdx.x * 64;
  const int k0 = blockIdx.y * 32;
  const int tid = threadIdx.x;
  if (tid < 32) {
    const size_t base = ((size_t)b * CH + k0 + tid) * 8;
    float S1 = 0.f, S2 = 0.f;
    #pragma unroll
    for (int k = 0; k < 8; k++) { S1 += statS1[base + k]; S2 += statS2[base + k]; }
    const float M = msum[b];
    const float mu = S1 / M;
    const float q = fmaxf(S2 - mu * S1, 0.f);
    smu[tid] = mu;
    srs[tid] = 1.0f / sqrtf(q / M + 1e-4f);
  }
  __syncthreads();
  const int n = n0 + (tid >> 2);
  const int kl = (tid & 3) * 8;
  const int kc = k0 + kl;
  const float mn = mask[b * NN + n];
  const size_t zoff = ((size_t)b * NN + n) * CH + kc;
  const ushort4 h0 = *(const ushort4*)&Zsh[zoff];
  const ushort4 h1 = *(const ushort4*)&Zsh[zoff + 4];
  const ushort4 l0 = *(const ushort4*)&Zsl[zoff];
  const ushort4 l1 = *(const ushort4*)&Zsl[zoff + 4];
  float val[8];
  val[0] = (h2f(h0.x) + h2f(l0.x) - smu[kl + 0] * mn) * srs[kl + 0];
  val[1] = (h2f(h0.y) + h2f(l0.y) - smu[kl + 1] * mn) * srs[kl + 1];
  val[2] = (h2f(h0.z) + h2f(l0.z) - smu[kl + 2] * mn) * srs[kl + 2];
  val[3] = (h2f(h0.w) + h2f(l0.w) - smu[kl + 3] * mn) * srs[kl + 3];
  val[4] = (h2f(h1.x) + h2f(l1.x) - smu[kl + 4] * mn) * srs[kl + 4];
  val[5] = (h2f(h1.y) + h2f(l1.y) - smu[kl + 5] * mn) * srs[kl + 5];
  val[6] = (h2f(h1.z) + h2f(l1.z) - smu[kl + 6] * mn) * srs[kl + 6];
  val[7] = (h2f(h1.w) + h2f(l1.w) - smu[kl + 7] * mn) * srs[kl + 7];
  float s = 0.f;
  ush hv[8], lv[8];
  #pragma unroll
  for (int j = 0; j < 8; j++) {
    s += val[j] * val[j];
    hv[j] = f2h(val[j]);
    lv[j] = f2h(val[j] - h2f(hv[j]));
  }
  const size_t off = ((size_t)b * NN + n) * CH + kc;
  *(ushort4*)&Th[off] = *(ushort4*)&hv[0];
  *(ushort4*)&Th[off + 4] = *(ushort4*)&hv[4];
  *(ushort4*)&Tl[off] = *(ushort4*)&lv[0];
  *(ushort4*)&Tl[off + 4] = *(ushort4*)&lv[4];
  s += __shfl_xor(s, 1, 64);
  s += __shfl_xor(s, 2, 64);
  if ((tid & 3) == 0) n2part[((size_t)b * 8 + blockIdx.y) * NN + n] = s;
}

// ---------- gram v7: fp16 2-product asym, upper-tri tiles, fp16 D direct stores ----------
__global__ __launch_bounds__(256, 3)
void gram_v7_kernel(const ush* __restrict__ Yth, const ush* __restrict__ Ytl,
                    const float* __restrict__ n2part, const float* __restrict__ mask,
                    const float* __restrict__ posv, ush* __restrict__ Dp,
                    float* __restrict__ sigpart) {
  __shared__ ush lds[24576];           // 2 x 12288 dbuf (48 KB)
  __shared__ float sn2[256];
  __shared__ float spv[256];
  const int bid = blockIdx.x;
  const int logical = (bid & 7) * 72 + (bid >> 3);
  const int b = logical / 36;
  int t = logical - b * 36;
  int ty = 0;
  while (t >= 8 - ty) { t -= 8 - ty; ++ty; }
  const int tx = ty + t;
  const int i0 = ty * 128;
  const int j0 = tx * 128;
  {
    const int tt = threadIdx.x;
    const int nn = (tt < 128) ? (i0 + tt) : (j0 + tt - 128);
    const float pv = posv[b * NN + nn];
    float s = pv * pv;
    #pragma unroll
    for (int kb = 0; kb < 8; kb++) s += n2part[((size_t)b * 8 + kb) * NN + nn];
    sn2[tt] = s;
    spv[tt] = pv;
  }
  const ush* Ah = Yth + (size_t)b * NN * CH + (size_t)i0 * CH;
  const ush* Al = Ytl + (size_t)b * NN * CH + (size_t)i0 * CH;
  const ush* Bh = Yth + (size_t)b * NN * CH + (size_t)j0 * CH;
  f4 acc[4][4];
  const f4 z4 = {0.f, 0.f, 0.f, 0.f};
  #pragma unroll
  for (int mi = 0; mi < 4; mi++)
    #pragma unroll
    for (int ni = 0; ni < 4; ni++) acc[mi][ni] = z4;
  stageG(Ah, Al, Bh, CH, 0, lds);
  __syncthreads();
  int pb = 0;
  for (int kt = 32; kt < CH; kt += 32) {
    stageG(Ah, Al, Bh, CH, kt, lds + (pb ^ 1) * 12288);
    computeG(lds + pb * 12288, acc);
    __syncthreads();
    pb ^= 1;
  }
  computeG(lds + pb * 12288, acc);
  const int lane = threadIdx.x & 63;
  const int wid = threadIdx.x >> 6;
  const int wr = wid >> 1, wc = wid & 1;
  const int frow = lane & 15, hh = lane >> 4;
  const float scale = 3.0f / 257.0f;
  float lsum = 0.f;
  #pragma unroll
  for (int ni = 0; ni < 4; ni++) {
    const int jl = wc * 64 + ni * 16 + frow;
    const int j = j0 + jl;
    const float n2j = sn2[128 + jl];
    const float pj = spv[128 + jl];
    const float mkj = mask[b * NN + j];
    #pragma unroll
    for (int mi = 0; mi < 4; mi++) {
      const int il = wr * 64 + mi * 16 + hh * 4;
      ush dv[4];
      #pragma unroll
      for (int r = 0; r < 4; r++) {
        const int i = i0 + il + r;
        const float g = acc[mi][ni][r] + spv[il + r] * pj;
        const float D = scale * (sn2[il + r] + n2j - 2.0f * g);
        const float d = sqrtf(fmaxf(D, 1e-12f));
        const float mmv = mask[b * NN + i] * mkj;
        const float wd = d * mmv;
        lsum += wd * mmv;
        dv[r] = f2h(wd);
      }
      if (ty != tx) {
        uint2 mr;
        mr.x = (unsigned)dv[0] | ((unsigned)dv[1] << 16);
        mr.y = (unsigned)dv[2] | ((unsigned)dv[3] << 16);
        *(uint2*)&Dp[((size_t)b * NN + j) * NN + i0 + il] = mr;
      }
      #pragma unroll
      for (int r = 0; r < 4; r++) {
        const unsigned v = dv[r];
        const unsigned vp = (unsigned)__shfl_xor((int)v, 1, 64);
        if ((frow & 1) == 0)
          *(unsigned*)&Dp[((size_t)b * NN + i0 + il + r) * NN + j] = v | (vp << 16);
      }
    }
  }
  if (ty != tx) lsum *= 2.0f;
  #pragma unroll
  for (int off = 32; off > 0; off >>= 1) lsum += __shfl_down(lsum, off, 64);
  __syncthreads();
  float* rbuf = (float*)lds;
  if (lane == 0) rbuf[wid] = lsum;
  __syncthreads();
  if (threadIdx.x == 0)
    sigpart[(size_t)b * 64 + ty * 8 + tx] = rbuf[0] + rbuf[1] + rbuf[2] + rbuf[3];
}

// ---------- expw v4: sigma reduce inlined; read fp16 D, write W' fp16 plane ----------
__global__ void expw4_kernel(const ush* __restrict__ Dp, const float* __restrict__ mask,
                             const float* __restrict__ sigpart, const float* __restrict__ msum,
                             ush* __restrict__ Wp) {
  __shared__ float sfb;
  const int b = blockIdx.y, n = blockIdx.x;
  const int t = threadIdx.x;
  {
    float v = 0.f;
    if (t < 64) {
      const int sy = t >> 3, sx = t & 7;
      if (sy <= sx) v = sigpart[b * 64 + t];
    }
    v = blockReduceSum(v);
    if (t == 0) { const float ms = msum[b]; sfb = -10.0f * ms * ms / v; }
  }
  __syncthreads();
  const float fb = sfb;
  const float mn = mask[b * NN + n];
  const size_t roff = ((size_t)b * NN + n) * NN;
  const float4 mk = ((const float4*)(mask + b * NN))[t];
  const ushort4 dp = *(const ushort4*)&Dp[roff + t * 4];
  const float w0 = __expf(fb * h2f(dp.x)) * mn * mk.x;
  const float w1 = __expf(fb * h2f(dp.y)) * mn * mk.y;
  const float w2 = __expf(fb * h2f(dp.z)) * mn * mk.z;
  const float w3 = __expf(fb * h2f(dp.w)) * mn * mk.w;
  const float s = blockReduceSum(w0 + w1 + w2 + w3);
  float v0 = -w0, v1 = -w1, v2 = -w2, v3 = -w3;
  if ((n >> 2) == t) {
    const int r = n & 3;
    if (r == 0) v0 += s; else if (r == 1) v1 += s; else if (r == 2) v2 += s; else v3 += s;
  }
  ushort4 h4;
  h4.x = f2h(v0); h4.y = f2h(v1); h4.z = f2h(v2); h4.w = f2h(v3);
  *(ushort4*)&Wp[roff + t * 4] = h4;
}

// ---------- cvall v4 (fp16): C[g] = Kis[g]*(W[g]@X)*mask; direct fragment stores ----------
__global__ __launch_bounds__(256, 3)
void cvall_kernel(const ush* __restrict__ Ap, const ush* __restrict__ Bth,
                  const ush* __restrict__ Btl, const float* __restrict__ mask,
                  const float* __restrict__ Kis, unsigned int* __restrict__ Cpack,
                  ush* __restrict__ C2h, ush* __restrict__ C2l) {
  __shared__ ush lds[24576];
  const int bid = blockIdx.x;
  const int logical = (bid & 7) * 96 + (bid >> 3);
  const int b = logical / 48;
  const int inner = logical - b * 48;
  const int c0g = inner & 7;
  const int r0g = inner >> 3;
  const int r0 = r0g * 128;
  const int c0 = c0g * 128;
  const ush* Aq = Ap + (size_t)r0 * CH;
  const ush* Bh = Bth + (size_t)b * NN * CH + (size_t)c0 * CH;
  const ush* Bl = Btl + (size_t)b * NN * CH + (size_t)c0 * CH;
  f4 acc[4][4];
  const f4 z4 = {0.f, 0.f, 0.f, 0.f};
  #pragma unroll
  for (int mi = 0; mi < 4; mi++)
    #pragma unroll
    for (int ni = 0; ni < 4; ni++) acc[mi][ni] = z4;
  stageCV(Aq, CH, Bh, Bl, CH, 0, lds);
  __syncthreads();
  int pb = 0;
  for (int kt = 32; kt < CH; kt += 32) {
    stageCV(Aq, CH, Bh, Bl, CH, kt, lds + (pb ^ 1) * 12288);
    computeCV(lds + pb * 12288, acc);
    __syncthreads();
    pb ^= 1;
  }
  computeCV(lds + pb * 12288, acc);
  const int lane = threadIdx.x & 63;
  const int wid = threadIdx.x >> 6;
  const int wr = wid >> 1, wc = wid & 1;
  const int frow = lane & 15, hh = lane >> 4;
  const float alpha = Kis[r0g >> 1];
  #pragma unroll
  for (int ni = 0; ni < 4; ni++) {
    const int jl = wc * 64 + ni * 16 + frow;
    const int col = c0 + jl;
    const float am = alpha * mask[b * NN + col];
    #pragma unroll
    for (int mi = 0; mi < 4; mi++) {
      const int il = wr * 64 + mi * 16 + hh * 4;
      #pragma unroll
      for (int r = 0; r < 4; r++) {
        const int row = r0 + il + r;
        const float v = acc[mi][ni][r] * am;
        const ush h = f2h(v);
        const ush l = f2h(v - h2f(h));
        const unsigned pv = (unsigned)h | ((unsigned)l << 16);
        const unsigned pvp = (unsigned)__shfl_xor((int)pv, 1, 64);
        if ((frow & 1) == 0) {
          if (r0g < 4) {
            uint2 w2; w2.x = pv; w2.y = pvp;
            *(uint2*)&Cpack[((size_t)b * 512 + row) * NN + col] = w2;
          } else {
            const size_t obase = ((size_t)b * 256 + (row - 512)) * NN + col;
            const unsigned hw = (pv & 0xffffu) | (pvp << 16);
            const unsigned lw = (pv >> 16) | (pvp & 0xffff0000u);
            *(unsigned*)&C2h[obase] = hw;
            *(unsigned*)&C2l[obase] = lw;
          }
        }
      }
    }
  }
}

// ---------- mm1 v6 (fp16): out = X@W' + add(packed) ----------
// OUTMODE 0: row-major fp16 split out (+STATS on o)
// OUTMODE 2: outF = zin - 0.01*o (fp32) + transposed fp16 Z-splits [NN][CH] (+STATS on val)
template <int OUTMODE, int STATS>
__global__ __launch_bounds__(256, 5)
void mm1_v6_kernel(const ush* __restrict__ Xh, const ush* __restrict__ Xl, const size_t xStride,
                   const ush* __restrict__ Wp,
                   const unsigned int* __restrict__ addp, const size_t aStride,
                   const float* __restrict__ zin, const float* __restrict__ mask,
                   float* __restrict__ outF, ush* __restrict__ outH, ush* __restrict__ outL,
                   float* __restrict__ statS1, float* __restrict__ statS2) {
  __shared__ ush lds[16384];
  const int bid = blockIdx.x;
  const int logical = (bid & 7) * 64 + (bid >> 3);
  const int b = logical >> 5;
  const int inner = logical & 31;
  const int n0 = (inner & 7) * 128;
  const int r0 = (inner >> 3) * 64;
  const ush* Ah = Xh + (size_t)b * xStride + (size_t)r0 * NN;
  const ush* Al = Xl + (size_t)b * xStride + (size_t)r0 * NN;
  const ush* Bp = Wp + (size_t)b * NN * NN + (size_t)n0 * NN;
  f4 acc[4][2];
  const f4 z4 = {0.f, 0.f, 0.f, 0.f};
  #pragma unroll
  for (int mi = 0; mi < 4; mi++) { acc[mi][0] = z4; acc[mi][1] = z4; }
  stageMM(Ah, Al, NN, Bp, NN, 0, lds);
  __syncthreads();
  int pb = 0;
  for (int kt = 32; kt < NN; kt += 32) {
    stageMM(Ah, Al, NN, Bp, NN, kt, lds + (pb ^ 1) * 8192);
    computeMM(lds + pb * 8192, acc);
    __syncthreads();
    pb ^= 1;
  }
  computeMM(lds + pb * 8192, acc);
  const int lane = threadIdx.x & 63;
  const int wid = threadIdx.x >> 6;
  const int frow = lane & 15, hh = lane >> 4;
  float a1[4][4];
  float a2[4][4];
  if (STATS) {
    #pragma unroll
    for (int mi = 0; mi < 4; mi++)
      #pragma unroll
      for (int r = 0; r < 4; r++) { a1[mi][r] = 0.f; a2[mi][r] = 0.f; }
  }
  __syncthreads();
  unsigned int* tl = (unsigned int*)lds;   // [128][64] swizzled packed splits
  #pragma unroll
  for (int ni = 0; ni < 2; ni++) {
    const int jl = wid * 32 + ni * 16 + frow;
    const int col = n0 + jl;
    const float mk = STATS ? mask[b * NN + col] : 0.f;
    #pragma unroll
    for (int mi = 0; mi < 4; mi++) {
      const int il = mi * 16 + hh * 4;
      unsigned int pv[4];
      #pragma unroll
      for (int r = 0; r < 4; r++) {
        const int row = r0 + il + r;
        const unsigned int av = addp[(size_t)b * aStride + (size_t)row * NN + col];
        const float o = acc[mi][ni][r] + h2f((ush)(av & 0xffffu)) + h2f((ush)(av >> 16));
        float val;
        if (OUTMODE == 2) {
          const size_t ooff = (size_t)b * CH * NN + (size_t)row * NN + col;
          val = zin[ooff] - 0.01f * o;
          outF[ooff] = val;
        } else {
          val = o;
        }
        if (STATS) { a1[mi][r] += val * mk; a2[mi][r] += val * val * mk; }
        const ush h = f2h(val);
        const ush l = f2h(val - h2f(h));
        pv[r] = (unsigned int)h | ((unsigned int)l << 16);
      }
      const int slot = (il >> 2) ^ (jl & 15);
      *(uint4*)&tl[jl * 64 + slot * 4] = *(uint4*)pv;
    }
  }
  __syncthreads();
  if (OUTMODE == 0) {
    const int rrow = threadIdx.x >> 2;
    const int rch = (threadIdx.x & 3) * 32;
    const size_t obase = ((size_t)b * 256 + r0 + rrow) * NN + n0 + rch;
    #pragma unroll
    for (int g = 0; g < 4; g++) {
      unsigned int hw[4], lw[4];
      #pragma unroll
      for (int q = 0; q < 4; q++) {
        unsigned int h2[2], l2[2];
        #pragma unroll
        for (int e = 0; e < 2; e++) {
          const int jl = rch + g * 8 + q * 2 + e;
          const int slot = (rrow >> 2) ^ (jl & 15);
          const unsigned int v = tl[jl * 64 + slot * 4 + (rrow & 3)];
          h2[e] = v & 0xffffu; l2[e] = v >> 16;
        }
        hw[q] = h2[0] | (h2[1] << 16);
        lw[q] = l2[0] | (l2[1] << 16);
      }
      *(uint4*)&outH[obase + g * 8] = *(uint4*)hw;
      *(uint4*)&outL[obase + g * 8] = *(uint4*)lw;
    }
  } else {
    const int nloc = threadIdx.x >> 1;
    const int ch0 = (threadIdx.x & 1) * 32;
    #pragma unroll
    for (int half = 0; half < 2; half++) {
      unsigned int hw[8], lw[8];
      #pragma unroll
      for (int q = 0; q < 8; q++) {
        const int ila = ch0 + half * 16 + q * 2;
        const int ilb = ila + 1;
        const unsigned int va = tl[nloc * 64 + (((ila >> 2) ^ (nloc & 15)) << 2) + (ila & 3)];
        const unsigned int vb = tl[nloc * 64 + (((ilb >> 2) ^ (nloc & 15)) << 2) + (ilb & 3)];
        hw[q] = (va & 0xffffu) | (vb << 16);
        lw[q] = (va >> 16) | (vb & 0xffff0000u);
      }
      const size_t zoff = ((size_t)b * NN + n0 + nloc) * CH + r0 + ch0 + half * 16;
      *(uint4*)&outH[zoff] = *(uint4*)&hw[0];
      *(uint4*)&outH[zoff + 8] = *(uint4*)&hw[4];
      *(uint4*)&outL[zoff] = *(uint4*)&lw[0];
      *(uint4*)&outL[zoff + 8] = *(uint4*)&lw[4];
    }
  }
  if (STATS) {
    #pragma unroll
    for (int mi = 0; mi < 4; mi++)
      #pragma unroll
      for (int r = 0; r < 4; r++) {
        #pragma unroll
        for (int d = 1; d < 16; d <<= 1) {
          a1[mi][r] += __shfl_xor(a1[mi][r], d, 64);
          a2[mi][r] += __shfl_xor(a2[mi][r], d, 64);
        }
      }
    __syncthreads();
    float* s1b = (float*)lds;
    float* s2b = s1b + 256;
    if (frow == 0) {
      #pragma unroll
      for (int mi = 0; mi < 4; mi++)
        #pragma unroll
        for (int r = 0; r < 4; r++) {
          const int row = mi * 16 + hh * 4 + r;
          s1b[wid * 64 + row] = a1[mi][r];
          s2b[wid * 64 + row] = a2[mi][r];
        }
    }
    __syncthreads();
    if (threadIdx.x < 64) {
      const int row = threadIdx.x;
      const float p1 = s1b[row] + s1b[64 + row] + s1b[128 + row] + s1b[192 + row];
      const float p2 = s2b[row] + s2b[64 + row] + s2b[128 + row] + s2b[192 + row];
      const int nblk = n0 >> 7;
      statS1[((size_t)b * CH + r0 + row) * 8 + nblk] = p1;
      statS2[((size_t)b * CH + r0 + row) * 8 + nblk] = p2;
    }
  }
}

// ---------- csq: partial col sums of ((U-rmean)*mask)^2; rmean inlined ----------
__global__ void csq_kernel(const ush* __restrict__ Uh, const ush* __restrict__ Ul,
                           const float* __restrict__ mask, const float* __restrict__ statS1,
                           const float* __restrict__ msum, float* __restrict__ part) {
  __shared__ float srm[16];
  const int b = blockIdx.y, cc = blockIdx.x;
  if (threadIdx.x < 16) {
    const size_t base = ((size_t)b * CH + cc * 16 + threadIdx.x) * 8;
    float S1 = 0.f;
    #pragma unroll
    for (int k = 0; k < 8; k++) S1 += statS1[base + k];
    srm[threadIdx.x] = S1 / msum[b];
  }
  __syncthreads();
  const int n = threadIdx.x * 4;
  const float4 m4 = *(const float4*)&mask[b * NN + n];
  float4 s4 = {0.f, 0.f, 0.f, 0.f};
  for (int r = 0; r < 16; r++) {
    const int c = cc * 16 + r;
    const float rm = srm[r];
    const size_t uoff = ((size_t)b * 256 + c) * NN + n;
    const ushort4 uh = *(const ushort4*)&Uh[uoff];
    const ushort4 ul = *(const ushort4*)&Ul[uoff];
    float a;
    a = (h2f(uh.x) + h2f(ul.x) - rm) * m4.x; s4.x += a * a;
    a = (h2f(uh.y) + h2f(ul.y) - rm) * m4.y; s4.y += a * a;
    a = (h2f(uh.z) + h2f(ul.z) - rm) * m4.z; s4.z += a * a;
    a = (h2f(uh.w) + h2f(ul.w) - rm) * m4.w; s4.w += a * a;
  }
  *(float4*)&part[((size_t)(b * 16 + cc)) * NN + n] = s4;
}

// ---------- tsplitN2: A=relu((U-rmean)*mask*rs); rmean+rs inlined ----------
__global__ void tsplitN2_kernel(const ush* __restrict__ Uh, const ush* __restrict__ Ul,
                                const float* __restrict__ mask, const float* __restrict__ statS1,
                                const float* __restrict__ msum, const float* __restrict__ part,
                                ush* __restrict__ Th, ush* __restrict__ Tl) {
  __shared__ float t[32][65];
  __shared__ float srm[32];
  __shared__ float srsl[64];
  const int b = blockIdx.z;
  const int n0 = blockIdx.x * 64;
  const int k0 = blockIdx.y * 32;
  const int tid = threadIdx.x;
  if (tid < 32) {
    const size_t base = ((size_t)b * CH + k0 + tid) * 8;
    float S1 = 0.f;
    #pragma unroll
    for (int k = 0; k < 8; k++) S1 += statS1[base + k];
    srm[tid] = S1 / msum[b];
  } else if (tid < 96) {
    const int n = n0 + tid - 32;
    float s = 0.001f;
    #pragma unroll
    for (int cc = 0; cc < 16; cc++) s += part[((size_t)(b * 16 + cc)) * NN + n];
    srsl[tid - 32] = 1.0f / sqrtf(s);
  }
  __syncthreads();
  const int lr = tid >> 3;
  const int lc = (tid & 7) * 8;
  const int gc = k0 + lr;
  const float rm = srm[lr];
  const float4 ma = *(const float4*)&mask[b * NN + n0 + lc];
  const float4 mb = *(const float4*)&mask[b * NN + n0 + lc + 4];
  const size_t uoff = ((size_t)b * 256 + gc) * NN + n0 + lc;
  const ushort4 ha = *(const ushort4*)&Uh[uoff];
  const ushort4 hb = *(const ushort4*)&Uh[uoff + 4];
  const ushort4 la = *(const ushort4*)&Ul[uoff];
  const ushort4 lb = *(const ushort4*)&Ul[uoff + 4];
  t[lr][lc + 0] = fmaxf((h2f(ha.x) + h2f(la.x) - rm) * ma.x * srsl[lc + 0], 0.f);
  t[lr][lc + 1] = fmaxf((h2f(ha.y) + h2f(la.y) - rm) * ma.y * srsl[lc + 1], 0.f);
  t[lr][lc + 2] = fmaxf((h2f(ha.z) + h2f(la.z) - rm) * ma.z * srsl[lc + 2], 0.f);
  t[lr][lc + 3] = fmaxf((h2f(ha.w) + h2f(la.w) - rm) * ma.w * srsl[lc + 3], 0.f);
  t[lr][lc + 4] = fmaxf((h2f(hb.x) + h2f(lb.x) - rm) * mb.x * srsl[lc + 4], 0.f);
  t[lr][lc + 5] = fmaxf((h2f(hb.y) + h2f(lb.y) - rm) * mb.y * srsl[lc + 5], 0.f);
  t[lr][lc + 6] = fmaxf((h2f(hb.z) + h2f(lb.z) - rm) * mb.z * srsl[lc + 6], 0.f);
  t[lr][lc + 7] = fmaxf((h2f(hb.w) + h2f(lb.w) - rm) * mb.w * srsl[lc + 7], 0.f);
  __syncthreads();
  const int on = tid >> 2;
  const int ok = (tid & 3) * 8;
  ush hv[8], lv[8];
  #pragma unroll
  for (int j = 0; j < 8; j++) {
    const float v = t[ok + j][on];
    hv[j] = f2h(v); lv[j] = f2h(v - h2f(hv[j]));
  }
  const size_t off = ((size_t)b * NN + n0 + on) * CH + k0 + ok;
  *(ushort4*)&Th[off] = *(ushort4*)&hv[0];
  *(ushort4*)&Th[off + 4] = *(ushort4*)&hv[4];
  *(ushort4*)&Tl[off] = *(ushort4*)&lv[0];
  *(ushort4*)&Tl[off + 4] = *(ushort4*)&lv[4];
}

// ---------- Zout = (Wend @ Z)*mask; write + centered copy ----------
__global__ void zout_kernel(const float* __restrict__ Z, const float* __restrict__ Wend,
                            const float* __restrict__ mask, float* __restrict__ outZ,
                            float* __restrict__ Zcent) {
  const int b = blockIdx.x;
  __shared__ float w[3 * CH];
  for (int i = threadIdx.x; i < 3 * CH; i += 256) w[i] = Wend[i];
  __syncthreads();
  float a[3][4];
  #pragma unroll
  for (int j = 0; j < 4; j++) { a[0][j] = 0.f; a[1][j] = 0.f; a[2][j] = 0.f; }
  const float* Zb = Z + (size_t)b * CH * NN;
  for (int c = 0; c < CH; c++) {
    const float w0 = w[c], w1 = w[CH + c], w2 = w[2 * CH + c];
    #pragma unroll
    for (int j = 0; j < 4; j++) {
      float zv = Zb[(size_t)c * NN + threadIdx.x + j * 256];
      a[0][j] += w0 * zv; a[1][j] += w1 * zv; a[2][j] += w2 * zv;
    }
  }
  float sum[3] = {0.f, 0.f, 0.f};
  #pragma unroll
  for (int j = 0; j < 4; j++) {
    const int n = threadIdx.x + j * 256;
    const float mv = mask[b * NN + n];
    #pragma unroll
    for (int o = 0; o < 3; o++) {
      a[o][j] *= mv;
      outZ[((size_t)b * 3 + o) * NN + n] = a[o][j];
      sum[o] += a[o][j];
    }
  }
  for (int o = 0; o < 3; o++) {
    float s = blockReduceSum(sum[o]);
    const float mean = s * (1.0f / NN);
    #pragma unroll
    for (int j = 0; j < 4; j++) {
      const int n = threadIdx.x + j * 256;
      Zcent[((size_t)b * 3 + o) * NN + n] = a[o][j] - mean;
    }
  }
}

// ---------- final distances ----------
__global__ void dist_kernel(const float* __restrict__ Zcent, float* __restrict__ outD) {
  const int b = blockIdx.z;
  const int n = blockIdx.y;
  const int m = blockIdx.x * 256 + threadIdx.x;
  const float* Zb = Zcent + (size_t)b * 3 * NN;
  const float x0 = Zb[n], x1 = Zb[NN + n], x2 = Zb[2 * NN + n];
  const float d0 = x0 - Zb[m], d1 = x1 - Zb[NN + m], d2 = x2 - Zb[2 * NN + m];
  const float D = d0 * d0 + d1 * d1 + d2 * d2;
  outD[((size_t)b * NN + n) * NN + m] = sqrtf(fmaxf(D, 1e-12f));
}

extern "C" void kernel_launch(void* const* d_in, const int* in_sizes, int n_in,
                              void* d_out, int out_size, void* d_ws, size_t ws_size,
                              hipStream_t stream) {
  const float* Zin  = (const float*)d_in[0];
  const float* mask = (const float*)d_in[1];
  const float* K0   = (const float*)d_in[2];
  const float* Knet = (const float*)d_in[3];
  const float* W    = (const float*)d_in[4];
  const float* Wend = (const float*)d_in[5];
  float* out = (float*)d_out;

  // d_out dist region (64 MB): Wp fp16 (32 MB) | Dp fp16 (32 MB)
  ush* Wp = (ush*)out;
  ush* Dp = Wp + (size_t)BB * NN * NN;
  float* outZ = out + (size_t)BB * NN * NN;

  float* p = (float*)d_ws;
  // union: gram phase {Yth | Ytl fp16 [NN][CH]}; GEMM phase {Cpack u32 | C2h | C2l fp16}
  float* uni = p; p += (size_t)BB * 768 * NN;     // 50.33 MB
  ush* Yth = (ush*)uni;
  ush* Ytl = Yth + (size_t)BB * NN * CH;
  unsigned int* Cpack = (unsigned int*)uni;
  ush* C2h = (ush*)(uni + (size_t)BB * 512 * NN);
  ush* C2l = C2h + (size_t)BB * 256 * NN;

  float* Zcur = p; p += (size_t)BB * CH * NN;
  ush* Thb = (ush*)p; p += (size_t)BB * NN * CH / 2;   // T / A-splits (shared)
  ush* Tlb = (ush*)p; p += (size_t)BB * NN * CH / 2;
  ush* Zsh = (ush*)p; p += (size_t)BB * NN * CH / 2;   // Z transposed fp16 splits
  ush* Zsl = (ush*)p; p += (size_t)BB * NN * CH / 2;
  ush* Wm = (ush*)p; p += (size_t)18 * CH * CH / 2;
  ush* Wt = (ush*)p; p += (size_t)18 * CH * CH / 2;
  float* msum  = p; p += BB;
  float* posv  = p; p += BB * NN;
  float* sigp  = p; p += BB * 64;
  float* statS1= p; p += (size_t)BB * CH * 8;
  float* statS2= p; p += (size_t)BB * CH * 8;
  float* n2part= p; p += (size_t)BB * 8 * NN;
  float* partb = p; p += (size_t)BB * 16 * NN;
  float* Zcent = p; p += BB * 3 * NN;

  const dim3 gtsZ(NN / 64, CH / 32, BB);
  const size_t sC = (size_t)512 * NN;
  const size_t sT = (size_t)CH * NN;

  masksum_kernel<<<BB, 256, 0, stream>>>(mask, msum, posv);
  wprep_kernel<<<dim3(16, 18), 256, 0, stream>>>(W, Wm, Wt);
  k0_kernel<<<dim3(CH / 8, BB), 256, 0, stream>>>(Zin, K0, mask, Zcur, statS1, statS2);
  tsplitZ_kernel<<<gtsZ, 256, 0, stream>>>(Zcur, Zsh, Zsl);

  for (int layer = 0; layer < NLAYERS; layer++) {
    tsplitY2_kernel<<<gtsZ, 256, 0, stream>>>(Zsh, Zsl, mask, statS1, statS2, msum,
                                              Yth, Ytl, n2part);
    gram_v7_kernel<<<576, 256, 0, stream>>>(Yth, Ytl, n2part, mask, posv, Dp, sigp);
    expw4_kernel<<<dim3(NN, BB), 256, 0, stream>>>(Dp, mask, sigp, msum, Wp);

    const ush* Am = Wm + (size_t)layer * 3 * CH * CH;
    const ush* At = Wt + (size_t)layer * 3 * CH * CH;
    const float* Ki = Knet + layer * 3;

    // ---- Ai = C0 + (C1 + C2@L)@L, C = Ki*(Wi@Z)*mask, L rows = W' ----
    cvall_kernel<<<768, 256, 0, stream>>>(Am, Zsh, Zsl, mask, Ki, Cpack, C2h, C2l);
    mm1_v6_kernel<0, 0><<<512, 256, 0, stream>>>(C2h, C2l, sT, Wp,
        Cpack + (size_t)256 * NN, sC, nullptr, nullptr, nullptr, Thb, Tlb, nullptr, nullptr);
    mm1_v6_kernel<0, 1><<<512, 256, 0, stream>>>(Thb, Tlb, sT, Wp,
        Cpack, sC, nullptr, mask, nullptr, C2h, C2l, statS1, statS2);

    csq_kernel<<<dim3(16, BB), 256, 0, stream>>>(C2h, C2l, mask, statS1, msum, partb);
    tsplitN2_kernel<<<gtsZ, 256, 0, stream>>>(C2h, C2l, mask, statS1, msum, partb, Thb, Tlb);

    // ---- Z -= 0.01 * (C0 + (C1 + C2@L)@L), C = Ki*(Wi^T@A)*mask ----
    cvall_kernel<<<768, 256, 0, stream>>>(At, Thb, Tlb, mask, Ki, Cpack, C2h, C2l);
    mm1_v6_kernel<0, 0><<<512, 256, 0, stream>>>(C2h, C2l, sT, Wp,
        Cpack + (size_t)256 * NN, sC, nullptr, nullptr, nullptr, Thb, Tlb, nullptr, nullptr);
    mm1_v6_kernel<2, 1><<<512, 256, 0, stream>>>(Thb, Tlb, sT, Wp,
        Cpack, sC, Zcur, mask, Zcur, Zsh, Zsl, statS1, statS2);
  }

  zout_kernel<<<BB, 256, 0, stream>>>(Zcur, Wend, mask, outZ, Zcent);
  dist_kernel<<<dim3(NN / 256, NN, BB), 256, 0, stream>>>(Zcent, out);
}

// Round 13
// 1808.398 us; speedup vs baseline: 1.0256x; 1.0256x over previous
//
#include <hip/hip_runtime.h>
#include <hip/hip_fp16.h>
#include <math.h>

#define BB 16
#define CIN 40
#define CH 256
#define NN 1024
#define NLAYERS 6

typedef unsigned short ush;
typedef __attribute__((ext_vector_type(8))) _Float16 h8;
typedef __attribute__((ext_vector_type(4))) float f4;

__device__ __forceinline__ ush f2h(float x) {
  __half h = __float2half(x);
  return *(ush*)&h;
}
__device__ __forceinline__ float h2f(ush u) {
  __half h = *(__half*)&u;
  return __half2float(h);
}
__device__ __forceinline__ float fast_tanh(float x) {
  const float e = __expf(2.0f * x);
  return (e - 1.0f) / (e + 1.0f);
}

#define GLD16(gp, lp) __builtin_amdgcn_global_load_lds( \
    (const __attribute__((address_space(1))) void*)(gp), \
    (__attribute__((address_space(3))) void*)(lp), 16, 0, 0)

// ---------- block reduction (256 threads = 4 waves) ----------
__device__ __forceinline__ float blockReduceSum(float v) {
  __shared__ float sred[4];
  const int lane = threadIdx.x & 63;
  const int wid  = threadIdx.x >> 6;
  #pragma unroll
  for (int off = 32; off > 0; off >>= 1) v += __shfl_down(v, off, 64);
  __syncthreads();
  if (lane == 0) sred[wid] = v;
  __syncthreads();
  return sred[0] + sred[1] + sred[2] + sred[3];
}

// ================= gram core (fp16, asym 2-product): A pair + B hi plane, 128x128 ==========
__device__ __forceinline__ void stageG(
    const ush* __restrict__ Ah, const ush* __restrict__ Al,
    const ush* __restrict__ Bh, const int s, const int kt, ush* buf) {
  const int lane = threadIdx.x & 63;
  const int wid = threadIdx.x >> 6;
  const int srow = lane >> 2;
  const int sl = (lane & 3) ^ ((srow >> 1) & 3);
  #pragma unroll
  for (int cc = 0; cc < 6; cc++) {
    const int c = wid * 6 + cc;
    const ush* src;
    if (c < 8)       src = Ah + (size_t)(c * 16 + srow) * s + kt + sl * 8;
    else if (c < 16) src = Al + (size_t)((c - 8) * 16 + srow) * s + kt + sl * 8;
    else             src = Bh + (size_t)((c - 16) * 16 + srow) * s + kt + sl * 8;
    GLD16(src, buf + c * 512 + lane * 8);
  }
}

__device__ __forceinline__ void computeG(const ush* buf, f4 acc[4][4]) {
  const int lane = threadIdx.x & 63;
  const int wid = threadIdx.x >> 6;
  const int wr = wid >> 1, wc = wid & 1;
  const int frow = lane & 15;
  const int slot8 = (((lane >> 4) ^ ((frow >> 1) & 3)) << 3);
  h8 ah[4], al[4], b_[4];
  #pragma unroll
  for (int mi = 0; mi < 4; mi++) {
    const int off = (wr * 64 + mi * 16 + frow) * 32 + slot8;
    ah[mi] = *(const h8*)&buf[off];
    al[mi] = *(const h8*)&buf[4096 + off];
  }
  #pragma unroll
  for (int ni = 0; ni < 4; ni++) {
    const int off = (wc * 64 + ni * 16 + frow) * 32 + slot8;
    b_[ni] = *(const h8*)&buf[8192 + off];
  }
  #pragma unroll
  for (int mi = 0; mi < 4; mi++)
    #pragma unroll
    for (int ni = 0; ni < 4; ni++) {
      acc[mi][ni] = __builtin_amdgcn_mfma_f32_16x16x32_f16(ah[mi], b_[ni], acc[mi][ni], 0, 0, 0);
      acc[mi][ni] = __builtin_amdgcn_mfma_f32_16x16x32_f16(al[mi], b_[ni], acc[mi][ni], 0, 0, 0);
    }
}

// ================= cvall core (fp16): A 1 plane + B 2 planes, 128x128, 2 products ==========
__device__ __forceinline__ void stageCV(
    const ush* __restrict__ Ap, const int sA,
    const ush* __restrict__ Bh, const ush* __restrict__ Bl, const int sB,
    const int kt, ush* buf) {
  const int lane = threadIdx.x & 63;
  const int wid = threadIdx.x >> 6;
  const int srow = lane >> 2;
  const int sl = (lane & 3) ^ ((srow >> 1) & 3);
  #pragma unroll
  for (int cc = 0; cc < 6; cc++) {
    const int c = wid * 6 + cc;
    const ush* src;
    if (c < 8)       src = Ap + (size_t)(c * 16 + srow) * sA + kt + sl * 8;
    else if (c < 16) src = Bh + (size_t)((c - 8) * 16 + srow) * sB + kt + sl * 8;
    else             src = Bl + (size_t)((c - 16) * 16 + srow) * sB + kt + sl * 8;
    GLD16(src, buf + c * 512 + lane * 8);
  }
}

__device__ __forceinline__ void computeCV(const ush* buf, f4 acc[4][4]) {
  const int lane = threadIdx.x & 63;
  const int wid = threadIdx.x >> 6;
  const int wr = wid >> 1, wc = wid & 1;
  const int frow = lane & 15;
  const int slot8 = (((lane >> 4) ^ ((frow >> 1) & 3)) << 3);
  h8 a_[4], bh_[4], bl_[4];
  #pragma unroll
  for (int mi = 0; mi < 4; mi++) {
    const int off = (wr * 64 + mi * 16 + frow) * 32 + slot8;
    a_[mi] = *(const h8*)&buf[off];
  }
  #pragma unroll
  for (int ni = 0; ni < 4; ni++) {
    const int off = (wc * 64 + ni * 16 + frow) * 32 + slot8;
    bh_[ni] = *(const h8*)&buf[4096 + off];
    bl_[ni] = *(const h8*)&buf[8192 + off];
  }
  #pragma unroll
  for (int mi = 0; mi < 4; mi++)
    #pragma unroll
    for (int ni = 0; ni < 4; ni++) {
      acc[mi][ni] = __builtin_amdgcn_mfma_f32_16x16x32_f16(a_[mi], bh_[ni], acc[mi][ni], 0, 0, 0);
      acc[mi][ni] = __builtin_amdgcn_mfma_f32_16x16x32_f16(a_[mi], bl_[ni], acc[mi][ni], 0, 0, 0);
    }
}

// ================= mm1 core (fp16): A 2 planes + B 1 plane, 64x128, 2 products =============
__device__ __forceinline__ void stageMM(
    const ush* __restrict__ Ah, const ush* __restrict__ Al, const int sA,
    const ush* __restrict__ Bp, const int sB, const int kt, ush* buf) {
  const int lane = threadIdx.x & 63;
  const int wid = threadIdx.x >> 6;
  const int srow = lane >> 2;
  const int sl = (lane & 3) ^ ((srow >> 1) & 3);
  #pragma unroll
  for (int cc = 0; cc < 4; cc++) {
    const int c = wid * 4 + cc;
    const ush* src;
    if (c < 4)       src = Ah + (size_t)(c * 16 + srow) * sA + kt + sl * 8;
    else if (c < 8)  src = Al + (size_t)((c - 4) * 16 + srow) * sA + kt + sl * 8;
    else             src = Bp + (size_t)((c - 8) * 16 + srow) * sB + kt + sl * 8;
    GLD16(src, buf + c * 512 + lane * 8);
  }
}

__device__ __forceinline__ void computeMM(const ush* buf, f4 acc[4][2]) {
  const int lane = threadIdx.x & 63;
  const int wid = threadIdx.x >> 6;
  const int frow = lane & 15;
  const int slot8 = (((lane >> 4) ^ ((frow >> 1) & 3)) << 3);
  h8 ah[4], al[4], b_[2];
  #pragma unroll
  for (int mi = 0; mi < 4; mi++) {
    const int off = (mi * 16 + frow) * 32 + slot8;
    ah[mi] = *(const h8*)&buf[off];
    al[mi] = *(const h8*)&buf[2048 + off];
  }
  #pragma unroll
  for (int ni = 0; ni < 2; ni++) {
    const int off = (wid * 32 + ni * 16 + frow) * 32 + slot8;
    b_[ni] = *(const h8*)&buf[4096 + off];
  }
  #pragma unroll
  for (int mi = 0; mi < 4; mi++)
    #pragma unroll
    for (int ni = 0; ni < 2; ni++) {
      acc[mi][ni] = __builtin_amdgcn_mfma_f32_16x16x32_f16(ah[mi], b_[ni], acc[mi][ni], 0, 0, 0);
      acc[mi][ni] = __builtin_amdgcn_mfma_f32_16x16x32_f16(al[mi], b_[ni], acc[mi][ni], 0, 0, 0);
    }
}

// ---------- Z0 = tanh(K0 @ Zin) * mask, 8 outputs/block, accumulator form ----------
__global__ void k0_kernel(const float* __restrict__ Zin, const float* __restrict__ K0,
                          const float* __restrict__ mask, float* __restrict__ Zc,
                          float* __restrict__ statS1, float* __restrict__ statS2) {
  const int b = blockIdx.y;
  const int o0 = blockIdx.x * 8;
  __shared__ float w[8][CIN];
  for (int i = threadIdx.x; i < 8 * CIN; i += 256)
    w[i / CIN][i % CIN] = K0[(o0 + i / CIN) * CIN + i % CIN];
  __syncthreads();
  float s1[8], s2[8];
  #pragma unroll
  for (int o = 0; o < 8; o++) { s1[o] = 0.f; s2[o] = 0.f; }
  for (int n = threadIdx.x; n < NN; n += 256) {
    const float mn = mask[b * NN + n];
    float acc[8];
    #pragma unroll
    for (int o = 0; o < 8; o++) acc[o] = 0.f;
    for (int c = 0; c < CIN; c++) {
      const float zv = Zin[((size_t)b * CIN + c) * NN + n];
      #pragma unroll
      for (int o = 0; o < 8; o++) acc[o] += w[o][c] * zv;
    }
    #pragma unroll
    for (int o = 0; o < 8; o++) {
      const float z = fast_tanh(acc[o]) * mn;
      Zc[((size_t)b * CH + o0 + o) * NN + n] = z;
      s1[o] += z; s2[o] += z * z;
    }
  }
  for (int o = 0; o < 8; o++) {
    const float r1 = blockReduceSum(s1[o]);
    const float r2 = blockReduceSum(s2[o]);
    if (threadIdx.x == 0) {
      const size_t base = ((size_t)b * CH + o0 + o) * 8;
      statS1[base] = r1; statS2[base] = r2;
      #pragma unroll
      for (int k = 1; k < 8; k++) { statS1[base + k] = 0.f; statS2[base + k] = 0.f; }
    }
  }
}

// ---------- masksum + centered pos-row values ----------
__global__ void masksum_kernel(const float* __restrict__ mask, float* __restrict__ msum,
                               float* __restrict__ posv) {
  const int b = blockIdx.x;
  float v = 0.f, p = 0.f;
  for (int n = threadIdx.x; n < NN; n += 256) {
    const float m = mask[b * NN + n];
    v += m;
    p += 0.5f * ((float)n * (1.0f / (NN - 1))) * m;
  }
  v = blockReduceSum(v);
  p = blockReduceSum(p);
  const float pm = p * (1.0f / NN);
  if (threadIdx.x == 0) msum[b] = v;
  for (int n = threadIdx.x; n < NN; n += 256)
    posv[b * NN + n] = 0.5f * ((float)n * (1.0f / (NN - 1))) * mask[b * NN + n] - pm;
}

// ---------- W prep: fp16 single plane of W and W^T for all 18 matrices ----------
__global__ void wprep_kernel(const float* __restrict__ W, ush* __restrict__ Wm,
                             ush* __restrict__ Wt) {
  __shared__ float t[64][65];
  const int mat = blockIdx.y;
  const int ty = blockIdx.x >> 2, tx = blockIdx.x & 3;
  const float* src = W + (size_t)mat * CH * CH;
  const int tid = threadIdx.x;
  const int lr = tid >> 2;
  const int lc = (tid & 3) * 16;
  float v[16];
  #pragma unroll
  for (int j = 0; j < 16; j += 4)
    *(float4*)&v[j] = *(const float4*)&src[(size_t)(ty * 64 + lr) * CH + tx * 64 + lc + j];
  ush hv[16];
  #pragma unroll
  for (int j = 0; j < 16; j++) {
    hv[j] = f2h(v[j]);
    t[lr][lc + j] = v[j];
  }
  const size_t offm = (size_t)mat * CH * CH + (size_t)(ty * 64 + lr) * CH + tx * 64 + lc;
  #pragma unroll
  for (int j = 0; j < 16; j += 4)
    *(ushort4*)&Wm[offm + j] = *(ushort4*)&hv[j];
  __syncthreads();
  #pragma unroll
  for (int j = 0; j < 16; j++) hv[j] = f2h(t[lc + j][lr]);
  const size_t offt = (size_t)mat * CH * CH + (size_t)(tx * 64 + lr) * CH + ty * 64 + lc;
  #pragma unroll
  for (int j = 0; j < 16; j += 4)
    *(ushort4*)&Wt[offt + j] = *(ushort4*)&hv[j];
}

// ---------- transpose+split: Zcur fp32 [CH][NN] -> fp16 splits [NN][CH] (pre-loop) ----------
__global__ void tsplitZ_kernel(const float* __restrict__ in, ush* __restrict__ Th,
                               ush* __restrict__ Tl) {
  __shared__ float t[32][65];
  const int b = blockIdx.z;
  const int n0 = blockIdx.x * 64;
  const int k0 = blockIdx.y * 32;
  const float* src = in + (size_t)b * CH * NN;
  const int tid = threadIdx.x;
  const int lr = tid >> 3;
  const int lc = (tid & 7) * 8;
  const int gk = k0 + lr;
  *(float4*)&t[lr][lc]     = *(const float4*)&src[(size_t)gk * NN + n0 + lc];
  *(float4*)&t[lr][lc + 4] = *(const float4*)&src[(size_t)gk * NN + n0 + lc + 4];
  __syncthreads();
  const int on = tid >> 2;
  const int ok = (tid & 3) * 8;
  ush hv[8], lv[8];
  #pragma unroll
  for (int j = 0; j < 8; j++) {
    const float v = t[ok + j][on];
    hv[j] = f2h(v); lv[j] = f2h(v - h2f(hv[j]));
  }
  const size_t off = ((size_t)b * NN + n0 + on) * CH + k0 + ok;
  *(ushort4*)&Th[off] = *(ushort4*)&hv[0];
  *(ushort4*)&Th[off + 4] = *(ushort4*)&hv[4];
  *(ushort4*)&Tl[off] = *(ushort4*)&lv[0];
  *(ushort4*)&Tl[off + 4] = *(ushort4*)&lv[4];
}

// ---------- tsplitY2: Z splits -> normalized Y fp16 splits + n2 partials (stats inlined) ----
__global__ void tsplitY2_kernel(const ush* __restrict__ Zsh, const ush* __restrict__ Zsl,
                                const float* __restrict__ mask,
                                const float* __restrict__ statS1, const float* __restrict__ statS2,
                                const float* __restrict__ msum, ush* __restrict__ Th,
                                ush* __restrict__ Tl, float* __restrict__ n2part) {
  __shared__ float smu[32], srs[32];
  const int b = blockIdx.z;
  const int n0 = blockIdx.x * 64;
  const int k0 = blockIdx.y * 32;
  const int tid = threadIdx.x;
  if (tid < 32) {
    const size_t base = ((size_t)b * CH + k0 + tid) * 8;
    float S1 = 0.f, S2 = 0.f;
    #pragma unroll
    for (int k = 0; k < 8; k++) { S1 += statS1[base + k]; S2 += statS2[base + k]; }
    const float M = msum[b];
    const float mu = S1 / M;
    const float q = fmaxf(S2 - mu * S1, 0.f);
    smu[tid] = mu;
    srs[tid] = 1.0f / sqrtf(q / M + 1e-4f);
  }
  __syncthreads();
  const int n = n0 + (tid >> 2);
  const int kl = (tid & 3) * 8;
  const int kc = k0 + kl;
  const float mn = mask[b * NN + n];
  const size_t zoff = ((size_t)b * NN + n) * CH + kc;
  const ushort4 h0 = *(const ushort4*)&Zsh[zoff];
  const ushort4 h1 = *(const ushort4*)&Zsh[zoff + 4];
  const ushort4 l0 = *(const ushort4*)&Zsl[zoff];
  const ushort4 l1 = *(const ushort4*)&Zsl[zoff + 4];
  float val[8];
  val[0] = (h2f(h0.x) + h2f(l0.x) - smu[kl + 0] * mn) * srs[kl + 0];
  val[1] = (h2f(h0.y) + h2f(l0.y) - smu[kl + 1] * mn) * srs[kl + 1];
  val[2] = (h2f(h0.z) + h2f(l0.z) - smu[kl + 2] * mn) * srs[kl + 2];
  val[3] = (h2f(h0.w) + h2f(l0.w) - smu[kl + 3] * mn) * srs[kl + 3];
  val[4] = (h2f(h1.x) + h2f(l1.x) - smu[kl + 4] * mn) * srs[kl + 4];
  val[5] = (h2f(h1.y) + h2f(l1.y) - smu[kl + 5] * mn) * srs[kl + 5];
  val[6] = (h2f(h1.z) + h2f(l1.z) - smu[kl + 6] * mn) * srs[kl + 6];
  val[7] = (h2f(h1.w) + h2f(l1.w) - smu[kl + 7] * mn) * srs[kl + 7];
  float s = 0.f;
  ush hv[8], lv[8];
  #pragma unroll
  for (int j = 0; j < 8; j++) {
    s += val[j] * val[j];
    hv[j] = f2h(val[j]);
    lv[j] = f2h(val[j] - h2f(hv[j]));
  }
  const size_t off = ((size_t)b * NN + n) * CH + kc;
  *(ushort4*)&Th[off] = *(ushort4*)&hv[0];
  *(ushort4*)&Th[off + 4] = *(ushort4*)&hv[4];
  *(ushort4*)&Tl[off] = *(ushort4*)&lv[0];
  *(ushort4*)&Tl[off + 4] = *(ushort4*)&lv[4];
  s += __shfl_xor(s, 1, 64);
  s += __shfl_xor(s, 2, 64);
  if ((tid & 3) == 0) n2part[((size_t)b * 8 + blockIdx.y) * NN + n] = s;
}

// ---------- gram v7: fp16 2-product asym, upper-tri tiles, fp16 D direct stores ----------
__global__ __launch_bounds__(256, 3)
void gram_v7_kernel(const ush* __restrict__ Yth, const ush* __restrict__ Ytl,
                    const float* __restrict__ n2part, const float* __restrict__ mask,
                    const float* __restrict__ posv, ush* __restrict__ Dp,
                    float* __restrict__ sigpart) {
  __shared__ ush lds[24576];           // 2 x 12288 dbuf (48 KB)
  __shared__ float sn2[256];
  __shared__ float spv[256];
  const int bid = blockIdx.x;
  const int logical = (bid & 7) * 72 + (bid >> 3);
  const int b = logical / 36;
  int t = logical - b * 36;
  int ty = 0;
  while (t >= 8 - ty) { t -= 8 - ty; ++ty; }
  const int tx = ty + t;
  const int i0 = ty * 128;
  const int j0 = tx * 128;
  {
    const int tt = threadIdx.x;
    const int nn = (tt < 128) ? (i0 + tt) : (j0 + tt - 128);
    const float pv = posv[b * NN + nn];
    float s = pv * pv;
    #pragma unroll
    for (int kb = 0; kb < 8; kb++) s += n2part[((size_t)b * 8 + kb) * NN + nn];
    sn2[tt] = s;
    spv[tt] = pv;
  }
  const ush* Ah = Yth + (size_t)b * NN * CH + (size_t)i0 * CH;
  const ush* Al = Ytl + (size_t)b * NN * CH + (size_t)i0 * CH;
  const ush* Bh = Yth + (size_t)b * NN * CH + (size_t)j0 * CH;
  f4 acc[4][4];
  const f4 z4 = {0.f, 0.f, 0.f, 0.f};
  #pragma unroll
  for (int mi = 0; mi < 4; mi++)
    #pragma unroll
    for (int ni = 0; ni < 4; ni++) acc[mi][ni] = z4;
  stageG(Ah, Al, Bh, CH, 0, lds);
  __syncthreads();
  int pb = 0;
  for (int kt = 32; kt < CH; kt += 32) {
    stageG(Ah, Al, Bh, CH, kt, lds + (pb ^ 1) * 12288);
    computeG(lds + pb * 12288, acc);
    __syncthreads();
    pb ^= 1;
  }
  computeG(lds + pb * 12288, acc);
  const int lane = threadIdx.x & 63;
  const int wid = threadIdx.x >> 6;
  const int wr = wid >> 1, wc = wid & 1;
  const int frow = lane & 15, hh = lane >> 4;
  const float scale = 3.0f / 257.0f;
  float lsum = 0.f;
  #pragma unroll
  for (int ni = 0; ni < 4; ni++) {
    const int jl = wc * 64 + ni * 16 + frow;
    const int j = j0 + jl;
    const float n2j = sn2[128 + jl];
    const float pj = spv[128 + jl];
    const float mkj = mask[b * NN + j];
    #pragma unroll
    for (int mi = 0; mi < 4; mi++) {
      const int il = wr * 64 + mi * 16 + hh * 4;
      ush dv[4];
      #pragma unroll
      for (int r = 0; r < 4; r++) {
        const int i = i0 + il + r;
        const float g = acc[mi][ni][r] + spv[il + r] * pj;
        const float D = scale * (sn2[il + r] + n2j - 2.0f * g);
        const float d = sqrtf(fmaxf(D, 1e-12f));
        const float mmv = mask[b * NN + i] * mkj;
        const float wd = d * mmv;
        lsum += wd * mmv;
        dv[r] = f2h(wd);
      }
      if (ty != tx) {
        uint2 mr;
        mr.x = (unsigned)dv[0] | ((unsigned)dv[1] << 16);
        mr.y = (unsigned)dv[2] | ((unsigned)dv[3] << 16);
        *(uint2*)&Dp[((size_t)b * NN + j) * NN + i0 + il] = mr;
      }
      #pragma unroll
      for (int r = 0; r < 4; r++) {
        const unsigned v = dv[r];
        const unsigned vp = (unsigned)__shfl_xor((int)v, 1, 64);
        if ((frow & 1) == 0)
          *(unsigned*)&Dp[((size_t)b * NN + i0 + il + r) * NN + j] = v | (vp << 16);
      }
    }
  }
  if (ty != tx) lsum *= 2.0f;
  #pragma unroll
  for (int off = 32; off > 0; off >>= 1) lsum += __shfl_down(lsum, off, 64);
  __syncthreads();
  float* rbuf = (float*)lds;
  if (lane == 0) rbuf[wid] = lsum;
  __syncthreads();
  if (threadIdx.x == 0)
    sigpart[(size_t)b * 64 + ty * 8 + tx] = rbuf[0] + rbuf[1] + rbuf[2] + rbuf[3];
}

// ---------- expw v4: sigma reduce inlined; read fp16 D, write W' fp16 plane ----------
__global__ void expw4_kernel(const ush* __restrict__ Dp, const float* __restrict__ mask,
                             const float* __restrict__ sigpart, const float* __restrict__ msum,
                             ush* __restrict__ Wp) {
  __shared__ float sfb;
  const int b = blockIdx.y, n = blockIdx.x;
  const int t = threadIdx.x;
  {
    float v = 0.f;
    if (t < 64) {
      const int sy = t >> 3, sx = t & 7;
      if (sy <= sx) v = sigpart[b * 64 + t];
    }
    v = blockReduceSum(v);
    if (t == 0) { const float ms = msum[b]; sfb = -10.0f * ms * ms / v; }
  }
  __syncthreads();
  const float fb = sfb;
  const float mn = mask[b * NN + n];
  const size_t roff = ((size_t)b * NN + n) * NN;
  const float4 mk = ((const float4*)(mask + b * NN))[t];
  const ushort4 dp = *(const ushort4*)&Dp[roff + t * 4];
  const float w0 = __expf(fb * h2f(dp.x)) * mn * mk.x;
  const float w1 = __expf(fb * h2f(dp.y)) * mn * mk.y;
  const float w2 = __expf(fb * h2f(dp.z)) * mn * mk.z;
  const float w3 = __expf(fb * h2f(dp.w)) * mn * mk.w;
  const float s = blockReduceSum(w0 + w1 + w2 + w3);
  float v0 = -w0, v1 = -w1, v2 = -w2, v3 = -w3;
  if ((n >> 2) == t) {
    const int r = n & 3;
    if (r == 0) v0 += s; else if (r == 1) v1 += s; else if (r == 2) v2 += s; else v3 += s;
  }
  ushort4 h4;
  h4.x = f2h(v0); h4.y = f2h(v1); h4.z = f2h(v2); h4.w = f2h(v3);
  *(ushort4*)&Wp[roff + t * 4] = h4;
}

// ---------- cvall v4 (fp16): C[g] = Kis[g]*(W[g]@X)*mask; direct fragment stores ----------
__global__ __launch_bounds__(256, 3)
void cvall_kernel(const ush* __restrict__ Ap, const ush* __restrict__ Bth,
                  const ush* __restrict__ Btl, const float* __restrict__ mask,
                  const float* __restrict__ Kis, unsigned int* __restrict__ Cpack,
                  ush* __restrict__ C2h, ush* __restrict__ C2l) {
  __shared__ ush lds[24576];
  const int bid = blockIdx.x;
  const int logical = (bid & 7) * 96 + (bid >> 3);
  const int b = logical / 48;
  const int inner = logical - b * 48;
  const int c0g = inner & 7;
  const int r0g = inner >> 3;
  const int r0 = r0g * 128;
  const int c0 = c0g * 128;
  const ush* Aq = Ap + (size_t)r0 * CH;
  const ush* Bh = Bth + (size_t)b * NN * CH + (size_t)c0 * CH;
  const ush* Bl = Btl + (size_t)b * NN * CH + (size_t)c0 * CH;
  f4 acc[4][4];
  const f4 z4 = {0.f, 0.f, 0.f, 0.f};
  #pragma unroll
  for (int mi = 0; mi < 4; mi++)
    #pragma unroll
    for (int ni = 0; ni < 4; ni++) acc[mi][ni] = z4;
  stageCV(Aq, CH, Bh, Bl, CH, 0, lds);
  __syncthreads();
  int pb = 0;
  for (int kt = 32; kt < CH; kt += 32) {
    stageCV(Aq, CH, Bh, Bl, CH, kt, lds + (pb ^ 1) * 12288);
    computeCV(lds + pb * 12288, acc);
    __syncthreads();
    pb ^= 1;
  }
  computeCV(lds + pb * 12288, acc);
  const int lane = threadIdx.x & 63;
  const int wid = threadIdx.x >> 6;
  const int wr = wid >> 1, wc = wid & 1;
  const int frow = lane & 15, hh = lane >> 4;
  const float alpha = Kis[r0g >> 1];
  #pragma unroll
  for (int ni = 0; ni < 4; ni++) {
    const int jl = wc * 64 + ni * 16 + frow;
    const int col = c0 + jl;
    const float am = alpha * mask[b * NN + col];
    #pragma unroll
    for (int mi = 0; mi < 4; mi++) {
      const int il = wr * 64 + mi * 16 + hh * 4;
      #pragma unroll
      for (int r = 0; r < 4; r++) {
        const int row = r0 + il + r;
        const float v = acc[mi][ni][r] * am;
        const ush h = f2h(v);
        const ush l = f2h(v - h2f(h));
        const unsigned pv = (unsigned)h | ((unsigned)l << 16);
        const unsigned pvp = (unsigned)__shfl_xor((int)pv, 1, 64);
        if ((frow & 1) == 0) {
          if (r0g < 4) {
            uint2 w2; w2.x = pv; w2.y = pvp;
            *(uint2*)&Cpack[((size_t)b * 512 + row) * NN + col] = w2;
          } else {
            const size_t obase = ((size_t)b * 256 + (row - 512)) * NN + col;
            const unsigned hw = (pv & 0xffffu) | (pvp << 16);
            const unsigned lw = (pv >> 16) | (pvp & 0xffff0000u);
            *(unsigned*)&C2h[obase] = hw;
            *(unsigned*)&C2l[obase] = lw;
          }
        }
      }
    }
  }
}

// ---------- mm1 v6 (fp16): out = X@W' + add(packed) ----------
// OUTMODE 0: row-major fp16 split out (+STATS on o)
// OUTMODE 2: outF = zin - 0.01*o (fp32) + transposed fp16 Z-splits [NN][CH] (+STATS on val)
template <int OUTMODE, int STATS>
__global__ __launch_bounds__(256, 5)
void mm1_v6_kernel(const ush* __restrict__ Xh, const ush* __restrict__ Xl, const size_t xStride,
                   const ush* __restrict__ Wp,
                   const unsigned int* __restrict__ addp, const size_t aStride,
                   const float* __restrict__ zin, const float* __restrict__ mask,
                   float* __restrict__ outF, ush* __restrict__ outH, ush* __restrict__ outL,
                   float* __restrict__ statS1, float* __restrict__ statS2) {
  __shared__ ush lds[16384];
  const int bid = blockIdx.x;
  const int logical = (bid & 7) * 64 + (bid >> 3);
  const int b = logical >> 5;
  const int inner = logical & 31;
  const int n0 = (inner & 7) * 128;
  const int r0 = (inner >> 3) * 64;
  const ush* Ah = Xh + (size_t)b * xStride + (size_t)r0 * NN;
  const ush* Al = Xl + (size_t)b * xStride + (size_t)r0 * NN;
  const ush* Bp = Wp + (size_t)b * NN * NN + (size_t)n0 * NN;
  f4 acc[4][2];
  const f4 z4 = {0.f, 0.f, 0.f, 0.f};
  #pragma unroll
  for (int mi = 0; mi < 4; mi++) { acc[mi][0] = z4; acc[mi][1] = z4; }
  stageMM(Ah, Al, NN, Bp, NN, 0, lds);
  __syncthreads();
  int pb = 0;
  for (int kt = 32; kt < NN; kt += 32) {
    stageMM(Ah, Al, NN, Bp, NN, kt, lds + (pb ^ 1) * 8192);
    computeMM(lds + pb * 8192, acc);
    __syncthreads();
    pb ^= 1;
  }
  computeMM(lds + pb * 8192, acc);
  const int lane = threadIdx.x & 63;
  const int wid = threadIdx.x >> 6;
  const int frow = lane & 15, hh = lane >> 4;
  float a1[4][4];
  float a2[4][4];
  if (STATS) {
    #pragma unroll
    for (int mi = 0; mi < 4; mi++)
      #pragma unroll
      for (int r = 0; r < 4; r++) { a1[mi][r] = 0.f; a2[mi][r] = 0.f; }
  }
  __syncthreads();
  unsigned int* tl = (unsigned int*)lds;   // [128][64] swizzled packed splits
  #pragma unroll
  for (int ni = 0; ni < 2; ni++) {
    const int jl = wid * 32 + ni * 16 + frow;
    const int col = n0 + jl;
    const float mk = STATS ? mask[b * NN + col] : 0.f;
    #pragma unroll
    for (int mi = 0; mi < 4; mi++) {
      const int il = mi * 16 + hh * 4;
      unsigned int pv[4];
      #pragma unroll
      for (int r = 0; r < 4; r++) {
        const int row = r0 + il + r;
        const unsigned int av = addp[(size_t)b * aStride + (size_t)row * NN + col];
        const float o = acc[mi][ni][r] + h2f((ush)(av & 0xffffu)) + h2f((ush)(av >> 16));
        float val;
        if (OUTMODE == 2) {
          const size_t ooff = (size_t)b * CH * NN + (size_t)row * NN + col;
          val = zin[ooff] - 0.01f * o;
          outF[ooff] = val;
        } else {
          val = o;
        }
        if (STATS) { a1[mi][r] += val * mk; a2[mi][r] += val * val * mk; }
        const ush h = f2h(val);
        const ush l = f2h(val - h2f(h));
        pv[r] = (unsigned int)h | ((unsigned int)l << 16);
      }
      const int slot = (il >> 2) ^ (jl & 15);
      *(uint4*)&tl[jl * 64 + slot * 4] = *(uint4*)pv;
    }
  }
  __syncthreads();
  if (OUTMODE == 0) {
    const int rrow = threadIdx.x >> 2;
    const int rch = (threadIdx.x & 3) * 32;
    const size_t obase = ((size_t)b * 256 + r0 + rrow) * NN + n0 + rch;
    #pragma unroll
    for (int g = 0; g < 4; g++) {
      unsigned int hw[4], lw[4];
      #pragma unroll
      for (int q = 0; q < 4; q++) {
        unsigned int h2[2], l2[2];
        #pragma unroll
        for (int e = 0; e < 2; e++) {
          const int jl = rch + g * 8 + q * 2 + e;
          const int slot = (rrow >> 2) ^ (jl & 15);
          const unsigned int v = tl[jl * 64 + slot * 4 + (rrow & 3)];
          h2[e] = v & 0xffffu; l2[e] = v >> 16;
        }
        hw[q] = h2[0] | (h2[1] << 16);
        lw[q] = l2[0] | (l2[1] << 16);
      }
      *(uint4*)&outH[obase + g * 8] = *(uint4*)hw;
      *(uint4*)&outL[obase + g * 8] = *(uint4*)lw;
    }
  } else {
    const int nloc = threadIdx.x >> 1;
    const int ch0 = (threadIdx.x & 1) * 32;
    #pragma unroll
    for (int half = 0; half < 2; half++) {
      unsigned int hw[8], lw[8];
      #pragma unroll
      for (int q = 0; q < 8; q++) {
        const int ila = ch0 + half * 16 + q * 2;
        const int ilb = ila + 1;
        const unsigned int va = tl[nloc * 64 + (((ila >> 2) ^ (nloc & 15)) << 2) + (ila & 3)];
        const unsigned int vb = tl[nloc * 64 + (((ilb >> 2) ^ (nloc & 15)) << 2) + (ilb & 3)];
        hw[q] = (va & 0xffffu) | (vb << 16);
        lw[q] = (va >> 16) | (vb & 0xffff0000u);
      }
      const size_t zoff = ((size_t)b * NN + n0 + nloc) * CH + r0 + ch0 + half * 16;
      *(uint4*)&outH[zoff] = *(uint4*)&hw[0];
      *(uint4*)&outH[zoff + 8] = *(uint4*)&hw[4];
      *(uint4*)&outL[zoff] = *(uint4*)&lw[0];
      *(uint4*)&outL[zoff + 8] = *(uint4*)&lw[4];
    }
  }
  if (STATS) {
    #pragma unroll
    for (int mi = 0; mi < 4; mi++)
      #pragma unroll
      for (int r = 0; r < 4; r++) {
        #pragma unroll
        for (int d = 1; d < 16; d <<= 1) {
          a1[mi][r] += __shfl_xor(a1[mi][r], d, 64);
          a2[mi][r] += __shfl_xor(a2[mi][r], d, 64);
        }
      }
    __syncthreads();
    float* s1b = (float*)lds;
    float* s2b = s1b + 256;
    if (frow == 0) {
      #pragma unroll
      for (int mi = 0; mi < 4; mi++)
        #pragma unroll
        for (int r = 0; r < 4; r++) {
          const int row = mi * 16 + hh * 4 + r;
          s1b[wid * 64 + row] = a1[mi][r];
          s2b[wid * 64 + row] = a2[mi][r];
        }
    }
    __syncthreads();
    if (threadIdx.x < 64) {
      const int row = threadIdx.x;
      const float p1 = s1b[row] + s1b[64 + row] + s1b[128 + row] + s1b[192 + row];
      const float p2 = s2b[row] + s2b[64 + row] + s2b[128 + row] + s2b[192 + row];
      const int nblk = n0 >> 7;
      statS1[((size_t)b * CH + r0 + row) * 8 + nblk] = p1;
      statS2[((size_t)b * CH + r0 + row) * 8 + nblk] = p2;
    }
  }
}

// ---------- csq: partial col sums of ((U-rmean)*mask)^2; rmean inlined ----------
__global__ void csq_kernel(const ush* __restrict__ Uh, const ush* __restrict__ Ul,
                           const float* __restrict__ mask, const float* __restrict__ statS1,
                           const float* __restrict__ msum, float* __restrict__ part) {
  __shared__ float srm[16];
  const int b = blockIdx.y, cc = blockIdx.x;
  if (threadIdx.x < 16) {
    const size_t base = ((size_t)b * CH + cc * 16 + threadIdx.x) * 8;
    float S1 = 0.f;
    #pragma unroll
    for (int k = 0; k < 8; k++) S1 += statS1[base + k];
    srm[threadIdx.x] = S1 / msum[b];
  }
  __syncthreads();
  const int n = threadIdx.x * 4;
  const float4 m4 = *(const float4*)&mask[b * NN + n];
  float4 s4 = {0.f, 0.f, 0.f, 0.f};
  for (int r = 0; r < 16; r++) {
    const int c = cc * 16 + r;
    const float rm = srm[r];
    const size_t uoff = ((size_t)b * 256 + c) * NN + n;
    const ushort4 uh = *(const ushort4*)&Uh[uoff];
    const ushort4 ul = *(const ushort4*)&Ul[uoff];
    float a;
    a = (h2f(uh.x) + h2f(ul.x) - rm) * m4.x; s4.x += a * a;
    a = (h2f(uh.y) + h2f(ul.y) - rm) * m4.y; s4.y += a * a;
    a = (h2f(uh.z) + h2f(ul.z) - rm) * m4.z; s4.z += a * a;
    a = (h2f(uh.w) + h2f(ul.w) - rm) * m4.w; s4.w += a * a;
  }
  *(float4*)&part[((size_t)(b * 16 + cc)) * NN + n] = s4;
}

// ---------- tsplitN2: A=relu((U-rmean)*mask*rs); rmean+rs inlined ----------
__global__ void tsplitN2_kernel(const ush* __restrict__ Uh, const ush* __restrict__ Ul,
                                const float* __restrict__ mask, const float* __restrict__ statS1,
                                const float* __restrict__ msum, const float* __restrict__ part,
                                ush* __restrict__ Th, ush* __restrict__ Tl) {
  __shared__ float t[32][65];
  __shared__ float srm[32];
  __shared__ float srsl[64];
  const int b = blockIdx.z;
  const int n0 = blockIdx.x * 64;
  const int k0 = blockIdx.y * 32;
  const int tid = threadIdx.x;
  if (tid < 32) {
    const size_t base = ((size_t)b * CH + k0 + tid) * 8;
    float S1 = 0.f;
    #pragma unroll
    for (int k = 0; k < 8; k++) S1 += statS1[base + k];
    srm[tid] = S1 / msum[b];
  } else if (tid < 96) {
    const int n = n0 + tid - 32;
    float s = 0.001f;
    #pragma unroll
    for (int cc = 0; cc < 16; cc++) s += part[((size_t)(b * 16 + cc)) * NN + n];
    srsl[tid - 32] = 1.0f / sqrtf(s);
  }
  __syncthreads();
  const int lr = tid >> 3;
  const int lc = (tid & 7) * 8;
  const int gc = k0 + lr;
  const float rm = srm[lr];
  const float4 ma = *(const float4*)&mask[b * NN + n0 + lc];
  const float4 mb = *(const float4*)&mask[b * NN + n0 + lc + 4];
  const size_t uoff = ((size_t)b * 256 + gc) * NN + n0 + lc;
  const ushort4 ha = *(const ushort4*)&Uh[uoff];
  const ushort4 hb = *(const ushort4*)&Uh[uoff + 4];
  const ushort4 la = *(const ushort4*)&Ul[uoff];
  const ushort4 lb = *(const ushort4*)&Ul[uoff + 4];
  t[lr][lc + 0] = fmaxf((h2f(ha.x) + h2f(la.x) - rm) * ma.x * srsl[lc + 0], 0.f);
  t[lr][lc + 1] = fmaxf((h2f(ha.y) + h2f(la.y) - rm) * ma.y * srsl[lc + 1], 0.f);
  t[lr][lc + 2] = fmaxf((h2f(ha.z) + h2f(la.z) - rm) * ma.z * srsl[lc + 2], 0.f);
  t[lr][lc + 3] = fmaxf((h2f(ha.w) + h2f(la.w) - rm) * ma.w * srsl[lc + 3], 0.f);
  t[lr][lc + 4] = fmaxf((h2f(hb.x) + h2f(lb.x) - rm) * mb.x * srsl[lc + 4], 0.f);
  t[lr][lc + 5] = fmaxf((h2f(hb.y) + h2f(lb.y) - rm) * mb.y * srsl[lc + 5], 0.f);
  t[lr][lc + 6] = fmaxf((h2f(hb.z) + h2f(lb.z) - rm) * mb.z * srsl[lc + 6], 0.f);
  t[lr][lc + 7] = fmaxf((h2f(hb.w) + h2f(lb.w) - rm) * mb.w * srsl[lc + 7], 0.f);
  __syncthreads();
  const int on = tid >> 2;
  const int ok = (tid & 3) * 8;
  ush hv[8], lv[8];
  #pragma unroll
  for (int j = 0; j < 8; j++) {
    const float v = t[ok + j][on];
    hv[j] = f2h(v); lv[j] = f2h(v - h2f(hv[j]));
  }
  const size_t off = ((size_t)b * NN + n0 + on) * CH + k0 + ok;
  *(ushort4*)&Th[off] = *(ushort4*)&hv[0];
  *(ushort4*)&Th[off + 4] = *(ushort4*)&hv[4];
  *(ushort4*)&Tl[off] = *(ushort4*)&lv[0];
  *(ushort4*)&Tl[off + 4] = *(ushort4*)&lv[4];
}

// ---------- Zout = (Wend @ Z)*mask; write + centered copy ----------
__global__ void zout_kernel(const float* __restrict__ Z, const float* __restrict__ Wend,
                            const float* __restrict__ mask, float* __restrict__ outZ,
                            float* __restrict__ Zcent) {
  const int b = blockIdx.x;
  __shared__ float w[3 * CH];
  for (int i = threadIdx.x; i < 3 * CH; i += 256) w[i] = Wend[i];
  __syncthreads();
  float a[3][4];
  #pragma unroll
  for (int j = 0; j < 4; j++) { a[0][j] = 0.f; a[1][j] = 0.f; a[2][j] = 0.f; }
  const float* Zb = Z + (size_t)b * CH * NN;
  for (int c = 0; c < CH; c++) {
    const float w0 = w[c], w1 = w[CH + c], w2 = w[2 * CH + c];
    #pragma unroll
    for (int j = 0; j < 4; j++) {
      float zv = Zb[(size_t)c * NN + threadIdx.x + j * 256];
      a[0][j] += w0 * zv; a[1][j] += w1 * zv; a[2][j] += w2 * zv;
    }
  }
  float sum[3] = {0.f, 0.f, 0.f};
  #pragma unroll
  for (int j = 0; j < 4; j++) {
    const int n = threadIdx.x + j * 256;
    const float mv = mask[b * NN + n];
    #pragma unroll
    for (int o = 0; o < 3; o++) {
      a[o][j] *= mv;
      outZ[((size_t)b * 3 + o) * NN + n] = a[o][j];
      sum[o] += a[o][j];
    }
  }
  for (int o = 0; o < 3; o++) {
    float s = blockReduceSum(sum[o]);
    const float mean = s * (1.0f / NN);
    #pragma unroll
    for (int j = 0; j < 4; j++) {
      const int n = threadIdx.x + j * 256;
      Zcent[((size_t)b * 3 + o) * NN + n] = a[o][j] - mean;
    }
  }
}

// ---------- final distances ----------
__global__ void dist_kernel(const float* __restrict__ Zcent, float* __restrict__ outD) {
  const int b = blockIdx.z;
  const int n = blockIdx.y;
  const int m = blockIdx.x * 256 + threadIdx.x;
  const float* Zb = Zcent + (size_t)b * 3 * NN;
  const float x0 = Zb[n], x1 = Zb[NN + n], x2 = Zb[2 * NN + n];
  const float d0 = x0 - Zb[m], d1 = x1 - Zb[NN + m], d2 = x2 - Zb[2 * NN + m];
  const float D = d0 * d0 + d1 * d1 + d2 * d2;
  outD[((size_t)b * NN + n) * NN + m] = sqrtf(fmaxf(D, 1e-12f));
}

extern "C" void kernel_launch(void* const* d_in, const int* in_sizes, int n_in,
                              void* d_out, int out_size, void* d_ws, size_t ws_size,
                              hipStream_t stream) {
  const float* Zin  = (const float*)d_in[0];
  const float* mask = (const float*)d_in[1];
  const float* K0   = (const float*)d_in[2];
  const float* Knet = (const float*)d_in[3];
  const float* W    = (const float*)d_in[4];
  const float* Wend = (const float*)d_in[5];
  float* out = (float*)d_out;

  // d_out dist region (64 MB): Wp fp16 (32 MB) | Dp fp16 (32 MB)
  ush* Wp = (ush*)out;
  ush* Dp = Wp + (size_t)BB * NN * NN;
  float* outZ = out + (size_t)BB * NN * NN;

  float* p = (float*)d_ws;
  // union: gram phase {Yth | Ytl fp16 [NN][CH]}; GEMM phase {Cpack u32 | C2h | C2l fp16}
  float* uni = p; p += (size_t)BB * 768 * NN;     // 50.33 MB
  ush* Yth = (ush*)uni;
  ush* Ytl = Yth + (size_t)BB * NN * CH;
  unsigned int* Cpack = (unsigned int*)uni;
  ush* C2h = (ush*)(uni + (size_t)BB * 512 * NN);
  ush* C2l = C2h + (size_t)BB * 256 * NN;

  float* Zcur = p; p += (size_t)BB * CH * NN;
  ush* Thb = (ush*)p; p += (size_t)BB * NN * CH / 2;   // T / A-splits (shared)
  ush* Tlb = (ush*)p; p += (size_t)BB * NN * CH / 2;
  ush* Zsh = (ush*)p; p += (size_t)BB * NN * CH / 2;   // Z transposed fp16 splits
  ush* Zsl = (ush*)p; p += (size_t)BB * NN * CH / 2;
  ush* Wm = (ush*)p; p += (size_t)18 * CH * CH / 2;
  ush* Wt = (ush*)p; p += (size_t)18 * CH * CH / 2;
  float* msum  = p; p += BB;
  float* posv  = p; p += BB * NN;
  float* sigp  = p; p += BB * 64;
  float* statS1= p; p += (size_t)BB * CH * 8;
  float* statS2= p; p += (size_t)BB * CH * 8;
  float* n2part= p; p += (size_t)BB * 8 * NN;
  float* partb = p; p += (size_t)BB * 16 * NN;
  float* Zcent = p; p += BB * 3 * NN;

  const dim3 gtsZ(NN / 64, CH / 32, BB);
  const size_t sC = (size_t)512 * NN;
  const size_t sT = (size_t)CH * NN;

  masksum_kernel<<<BB, 256, 0, stream>>>(mask, msum, posv);
  wprep_kernel<<<dim3(16, 18), 256, 0, stream>>>(W, Wm, Wt);
  k0_kernel<<<dim3(CH / 8, BB), 256, 0, stream>>>(Zin, K0, mask, Zcur, statS1, statS2);
  tsplitZ_kernel<<<gtsZ, 256, 0, stream>>>(Zcur, Zsh, Zsl);

  for (int layer = 0; layer < NLAYERS; layer++) {
    tsplitY2_kernel<<<gtsZ, 256, 0, stream>>>(Zsh, Zsl, mask, statS1, statS2, msum,
                                              Yth, Ytl, n2part);
    gram_v7_kernel<<<576, 256, 0, stream>>>(Yth, Ytl, n2part, mask, posv, Dp, sigp);
    expw4_kernel<<<dim3(NN, BB), 256, 0, stream>>>(Dp, mask, sigp, msum, Wp);

    const ush* Am = Wm + (size_t)layer * 3 * CH * CH;
    const ush* At = Wt + (size_t)layer * 3 * CH * CH;
    const float* Ki = Knet + layer * 3;

    // ---- Ai = C0 + (C1 + C2@L)@L, C = Ki*(Wi@Z)*mask, L rows = W' ----
    cvall_kernel<<<768, 256, 0, stream>>>(Am, Zsh, Zsl, mask, Ki, Cpack, C2h, C2l);
    mm1_v6_kernel<0, 0><<<512, 256, 0, stream>>>(C2h, C2l, sT, Wp,
        Cpack + (size_t)256 * NN, sC, nullptr, nullptr, nullptr, Thb, Tlb, nullptr, nullptr);
    mm1_v6_kernel<0, 1><<<512, 256, 0, stream>>>(Thb, Tlb, sT, Wp,
        Cpack, sC, nullptr, mask, nullptr, C2h, C2l, statS1, statS2);

    csq_kernel<<<dim3(16, BB), 256, 0, stream>>>(C2h, C2l, mask, statS1, msum, partb);
    tsplitN2_kernel<<<gtsZ, 256, 0, stream>>>(C2h, C2l, mask, statS1, msum, partb, Thb, Tlb);

    // ---- Z -= 0.01 * (C0 + (C1 + C2@L)@L), C = Ki*(Wi^T@A)*mask ----
    cvall_kernel<<<768, 256, 0, stream>>>(At, Thb, Tlb, mask, Ki, Cpack, C2h, C2l);
    mm1_v6_kernel<0, 0><<<512, 256, 0, stream>>>(C2h, C2l, sT, Wp,
        Cpack + (size_t)256 * NN, sC, nullptr, nullptr, nullptr, Thb, Tlb, nullptr, nullptr);
    mm1_v6_kernel<2, 1><<<512, 256, 0, stream>>>(Thb, Tlb, sT, Wp,
        Cpack, sC, Zcur, mask, Zcur, Zsh, Zsl, statS1, statS2);
  }

  zout_kernel<<<BB, 256, 0, stream>>>(Zcur, Wend, mask, outZ, Zcent);
  dist_kernel<<<dim3(NN / 256, NN, BB), 256, 0, stream>>>(Zcent, out);
}

// Round 14
// 1802.233 us; speedup vs baseline: 1.0291x; 1.0034x over previous
//
#include <hip/hip_runtime.h>
#include <hip/hip_fp16.h>
#include <math.h>

#define BB 16
#define CIN 40
#define CH 256
#define NN 1024
#define NLAYERS 6

typedef unsigned short ush;
typedef __attribute__((ext_vector_type(8))) _Float16 h8;
typedef __attribute__((ext_vector_type(4))) float f4;

__device__ __forceinline__ ush f2h(float x) {
  __half h = __float2half(x);
  return *(ush*)&h;
}
__device__ __forceinline__ float h2f(ush u) {
  __half h = *(__half*)&u;
  return __half2float(h);
}
__device__ __forceinline__ float fast_tanh(float x) {
  const float e = __expf(2.0f * x);
  return (e - 1.0f) / (e + 1.0f);
}

#define GLD16(gp, lp) __builtin_amdgcn_global_load_lds( \
    (const __attribute__((address_space(1))) void*)(gp), \
    (__attribute__((address_space(3))) void*)(lp), 16, 0, 0)

// ---------- block reduction (256 threads = 4 waves) ----------
__device__ __forceinline__ float blockReduceSum(float v) {
  __shared__ float sred[4];
  const int lane = threadIdx.x & 63;
  const int wid  = threadIdx.x >> 6;
  #pragma unroll
  for (int off = 32; off > 0; off >>= 1) v += __shfl_down(v, off, 64);
  __syncthreads();
  if (lane == 0) sred[wid] = v;
  __syncthreads();
  return sred[0] + sred[1] + sred[2] + sred[3];
}

// ================= gram core (fp16, asym 2-product): A pair + B hi plane, 128x128 ==========
__device__ __forceinline__ void stageG(
    const ush* __restrict__ Ah, const ush* __restrict__ Al,
    const ush* __restrict__ Bh, const int s, const int kt, ush* buf) {
  const int lane = threadIdx.x & 63;
  const int wid = threadIdx.x >> 6;
  const int srow = lane >> 2;
  const int sl = (lane & 3) ^ ((srow >> 1) & 3);
  #pragma unroll
  for (int cc = 0; cc < 6; cc++) {
    const int c = wid * 6 + cc;
    const ush* src;
    if (c < 8)       src = Ah + (size_t)(c * 16 + srow) * s + kt + sl * 8;
    else if (c < 16) src = Al + (size_t)((c - 8) * 16 + srow) * s + kt + sl * 8;
    else             src = Bh + (size_t)((c - 16) * 16 + srow) * s + kt + sl * 8;
    GLD16(src, buf + c * 512 + lane * 8);
  }
}

__device__ __forceinline__ void computeG(const ush* buf, f4 acc[4][4]) {
  const int lane = threadIdx.x & 63;
  const int wid = threadIdx.x >> 6;
  const int wr = wid >> 1, wc = wid & 1;
  const int frow = lane & 15;
  const int slot8 = (((lane >> 4) ^ ((frow >> 1) & 3)) << 3);
  h8 ah[4], al[4], b_[4];
  #pragma unroll
  for (int mi = 0; mi < 4; mi++) {
    const int off = (wr * 64 + mi * 16 + frow) * 32 + slot8;
    ah[mi] = *(const h8*)&buf[off];
    al[mi] = *(const h8*)&buf[4096 + off];
  }
  #pragma unroll
  for (int ni = 0; ni < 4; ni++) {
    const int off = (wc * 64 + ni * 16 + frow) * 32 + slot8;
    b_[ni] = *(const h8*)&buf[8192 + off];
  }
  #pragma unroll
  for (int mi = 0; mi < 4; mi++)
    #pragma unroll
    for (int ni = 0; ni < 4; ni++) {
      acc[mi][ni] = __builtin_amdgcn_mfma_f32_16x16x32_f16(ah[mi], b_[ni], acc[mi][ni], 0, 0, 0);
      acc[mi][ni] = __builtin_amdgcn_mfma_f32_16x16x32_f16(al[mi], b_[ni], acc[mi][ni], 0, 0, 0);
    }
}

// ================= cvall core (fp16): A 1 plane + B 2 planes, 128x128, 2 products ==========
__device__ __forceinline__ void stageCV(
    const ush* __restrict__ Ap, const int sA,
    const ush* __restrict__ Bh, const ush* __restrict__ Bl, const int sB,
    const int kt, ush* buf) {
  const int lane = threadIdx.x & 63;
  const int wid = threadIdx.x >> 6;
  const int srow = lane >> 2;
  const int sl = (lane & 3) ^ ((srow >> 1) & 3);
  #pragma unroll
  for (int cc = 0; cc < 6; cc++) {
    const int c = wid * 6 + cc;
    const ush* src;
    if (c < 8)       src = Ap + (size_t)(c * 16 + srow) * sA + kt + sl * 8;
    else if (c < 16) src = Bh + (size_t)((c - 8) * 16 + srow) * sB + kt + sl * 8;
    else             src = Bl + (size_t)((c - 16) * 16 + srow) * sB + kt + sl * 8;
    GLD16(src, buf + c * 512 + lane * 8);
  }
}

__device__ __forceinline__ void computeCV(const ush* buf, f4 acc[4][4]) {
  const int lane = threadIdx.x & 63;
  const int wid = threadIdx.x >> 6;
  const int wr = wid >> 1, wc = wid & 1;
  const int frow = lane & 15;
  const int slot8 = (((lane >> 4) ^ ((frow >> 1) & 3)) << 3);
  h8 a_[4], bh_[4], bl_[4];
  #pragma unroll
  for (int mi = 0; mi < 4; mi++) {
    const int off = (wr * 64 + mi * 16 + frow) * 32 + slot8;
    a_[mi] = *(const h8*)&buf[off];
  }
  #pragma unroll
  for (int ni = 0; ni < 4; ni++) {
    const int off = (wc * 64 + ni * 16 + frow) * 32 + slot8;
    bh_[ni] = *(const h8*)&buf[4096 + off];
    bl_[ni] = *(const h8*)&buf[8192 + off];
  }
  #pragma unroll
  for (int mi = 0; mi < 4; mi++)
    #pragma unroll
    for (int ni = 0; ni < 4; ni++) {
      acc[mi][ni] = __builtin_amdgcn_mfma_f32_16x16x32_f16(a_[mi], bh_[ni], acc[mi][ni], 0, 0, 0);
      acc[mi][ni] = __builtin_amdgcn_mfma_f32_16x16x32_f16(a_[mi], bl_[ni], acc[mi][ni], 0, 0, 0);
    }
}

// ================= mm1 core (fp16): A 2 planes + B 1 plane, 64x128, 2 products =============
__device__ __forceinline__ void stageMM(
    const ush* __restrict__ Ah, const ush* __restrict__ Al, const int sA,
    const ush* __restrict__ Bp, const int sB, const int kt, ush* buf) {
  const int lane = threadIdx.x & 63;
  const int wid = threadIdx.x >> 6;
  const int srow = lane >> 2;
  const int sl = (lane & 3) ^ ((srow >> 1) & 3);
  #pragma unroll
  for (int cc = 0; cc < 4; cc++) {
    const int c = wid * 4 + cc;
    const ush* src;
    if (c < 4)       src = Ah + (size_t)(c * 16 + srow) * sA + kt + sl * 8;
    else if (c < 8)  src = Al + (size_t)((c - 4) * 16 + srow) * sA + kt + sl * 8;
    else             src = Bp + (size_t)((c - 8) * 16 + srow) * sB + kt + sl * 8;
    GLD16(src, buf + c * 512 + lane * 8);
  }
}

__device__ __forceinline__ void computeMM(const ush* buf, f4 acc[4][2]) {
  const int lane = threadIdx.x & 63;
  const int wid = threadIdx.x >> 6;
  const int frow = lane & 15;
  const int slot8 = (((lane >> 4) ^ ((frow >> 1) & 3)) << 3);
  h8 ah[4], al[4], b_[2];
  #pragma unroll
  for (int mi = 0; mi < 4; mi++) {
    const int off = (mi * 16 + frow) * 32 + slot8;
    ah[mi] = *(const h8*)&buf[off];
    al[mi] = *(const h8*)&buf[2048 + off];
  }
  #pragma unroll
  for (int ni = 0; ni < 2; ni++) {
    const int off = (wid * 32 + ni * 16 + frow) * 32 + slot8;
    b_[ni] = *(const h8*)&buf[4096 + off];
  }
  #pragma unroll
  for (int mi = 0; mi < 4; mi++)
    #pragma unroll
    for (int ni = 0; ni < 2; ni++) {
      acc[mi][ni] = __builtin_amdgcn_mfma_f32_16x16x32_f16(ah[mi], b_[ni], acc[mi][ni], 0, 0, 0);
      acc[mi][ni] = __builtin_amdgcn_mfma_f32_16x16x32_f16(al[mi], b_[ni], acc[mi][ni], 0, 0, 0);
    }
}

// ---------- Z0 = tanh(K0 @ Zin) * mask, 8 outputs/block, fully unrolled reductions ----------
__global__ void k0_kernel(const float* __restrict__ Zin, const float* __restrict__ K0,
                          const float* __restrict__ mask, float* __restrict__ Zc,
                          float* __restrict__ statS1, float* __restrict__ statS2) {
  const int b = blockIdx.y;
  const int o0 = blockIdx.x * 8;
  __shared__ float w[8][CIN];
  __shared__ float sred1[4][8];
  __shared__ float sred2[4][8];
  for (int i = threadIdx.x; i < 8 * CIN; i += 256)
    w[i / CIN][i % CIN] = K0[(o0 + i / CIN) * CIN + i % CIN];
  __syncthreads();
  float s1[8], s2[8];
  #pragma unroll
  for (int o = 0; o < 8; o++) { s1[o] = 0.f; s2[o] = 0.f; }
  for (int n = threadIdx.x; n < NN; n += 256) {
    const float mn = mask[b * NN + n];
    float acc[8];
    #pragma unroll
    for (int o = 0; o < 8; o++) acc[o] = 0.f;
    for (int c = 0; c < CIN; c++) {
      const float zv = Zin[((size_t)b * CIN + c) * NN + n];
      #pragma unroll
      for (int o = 0; o < 8; o++) acc[o] += w[o][c] * zv;
    }
    #pragma unroll
    for (int o = 0; o < 8; o++) {
      const float z = fast_tanh(acc[o]) * mn;
      Zc[((size_t)b * CH + o0 + o) * NN + n] = z;
      s1[o] += z; s2[o] += z * z;
    }
  }
  const int lane = threadIdx.x & 63;
  const int wid = threadIdx.x >> 6;
  #pragma unroll
  for (int o = 0; o < 8; o++) {
    float r1 = s1[o], r2 = s2[o];
    #pragma unroll
    for (int off = 32; off > 0; off >>= 1) {
      r1 += __shfl_down(r1, off, 64);
      r2 += __shfl_down(r2, off, 64);
    }
    if (lane == 0) { sred1[wid][o] = r1; sred2[wid][o] = r2; }
  }
  __syncthreads();
  if (threadIdx.x < 8) {
    const int o = threadIdx.x;
    const float r1 = sred1[0][o] + sred1[1][o] + sred1[2][o] + sred1[3][o];
    const float r2 = sred2[0][o] + sred2[1][o] + sred2[2][o] + sred2[3][o];
    const size_t base = ((size_t)b * CH + o0 + o) * 8;
    statS1[base] = r1; statS2[base] = r2;
    #pragma unroll
    for (int k = 1; k < 8; k++) { statS1[base + k] = 0.f; statS2[base + k] = 0.f; }
  }
}

// ---------- masksum + centered pos-row values ----------
__global__ void masksum_kernel(const float* __restrict__ mask, float* __restrict__ msum,
                               float* __restrict__ posv) {
  const int b = blockIdx.x;
  float v = 0.f, p = 0.f;
  for (int n = threadIdx.x; n < NN; n += 256) {
    const float m = mask[b * NN + n];
    v += m;
    p += 0.5f * ((float)n * (1.0f / (NN - 1))) * m;
  }
  v = blockReduceSum(v);
  p = blockReduceSum(p);
  const float pm = p * (1.0f / NN);
  if (threadIdx.x == 0) msum[b] = v;
  for (int n = threadIdx.x; n < NN; n += 256)
    posv[b * NN + n] = 0.5f * ((float)n * (1.0f / (NN - 1))) * mask[b * NN + n] - pm;
}

// ---------- W prep: fp16 single plane of W and W^T for all 18 matrices ----------
__global__ void wprep_kernel(const float* __restrict__ W, ush* __restrict__ Wm,
                             ush* __restrict__ Wt) {
  __shared__ float t[64][65];
  const int mat = blockIdx.y;
  const int ty = blockIdx.x >> 2, tx = blockIdx.x & 3;
  const float* src = W + (size_t)mat * CH * CH;
  const int tid = threadIdx.x;
  const int lr = tid >> 2;
  const int lc = (tid & 3) * 16;
  float v[16];
  #pragma unroll
  for (int j = 0; j < 16; j += 4)
    *(float4*)&v[j] = *(const float4*)&src[(size_t)(ty * 64 + lr) * CH + tx * 64 + lc + j];
  ush hv[16];
  #pragma unroll
  for (int j = 0; j < 16; j++) {
    hv[j] = f2h(v[j]);
    t[lr][lc + j] = v[j];
  }
  const size_t offm = (size_t)mat * CH * CH + (size_t)(ty * 64 + lr) * CH + tx * 64 + lc;
  #pragma unroll
  for (int j = 0; j < 16; j += 4)
    *(ushort4*)&Wm[offm + j] = *(ushort4*)&hv[j];
  __syncthreads();
  #pragma unroll
  for (int j = 0; j < 16; j++) hv[j] = f2h(t[lc + j][lr]);
  const size_t offt = (size_t)mat * CH * CH + (size_t)(tx * 64 + lr) * CH + ty * 64 + lc;
  #pragma unroll
  for (int j = 0; j < 16; j += 4)
    *(ushort4*)&Wt[offt + j] = *(ushort4*)&hv[j];
}

// ---------- transpose+split: Zcur fp32 [CH][NN] -> fp16 splits [NN][CH] (pre-loop) ----------
__global__ void tsplitZ_kernel(const float* __restrict__ in, ush* __restrict__ Th,
                               ush* __restrict__ Tl) {
  __shared__ float t[32][65];
  const int b = blockIdx.z;
  const int n0 = blockIdx.x * 64;
  const int k0 = blockIdx.y * 32;
  const float* src = in + (size_t)b * CH * NN;
  const int tid = threadIdx.x;
  const int lr = tid >> 3;
  const int lc = (tid & 7) * 8;
  const int gk = k0 + lr;
  *(float4*)&t[lr][lc]     = *(const float4*)&src[(size_t)gk * NN + n0 + lc];
  *(float4*)&t[lr][lc + 4] = *(const float4*)&src[(size_t)gk * NN + n0 + lc + 4];
  __syncthreads();
  const int on = tid >> 2;
  const int ok = (tid & 3) * 8;
  ush hv[8], lv[8];
  #pragma unroll
  for (int j = 0; j < 8; j++) {
    const float v = t[ok + j][on];
    hv[j] = f2h(v); lv[j] = f2h(v - h2f(hv[j]));
  }
  const size_t off = ((size_t)b * NN + n0 + on) * CH + k0 + ok;
  *(ushort4*)&Th[off] = *(ushort4*)&hv[0];
  *(ushort4*)&Th[off + 4] = *(ushort4*)&hv[4];
  *(ushort4*)&Tl[off] = *(ushort4*)&lv[0];
  *(ushort4*)&Tl[off + 4] = *(ushort4*)&lv[4];
}

// ---------- tsplitY2: Z splits -> normalized Y fp16 splits + n2 partials (stats inlined) ----
__global__ void tsplitY2_kernel(const ush* __restrict__ Zsh, const ush* __restrict__ Zsl,
                                const float* __restrict__ mask,
                                const float* __restrict__ statS1, const float* __restrict__ statS2,
                                const float* __restrict__ msum, ush* __restrict__ Th,
                                ush* __restrict__ Tl, float* __restrict__ n2part) {
  __shared__ float smu[32], srs[32];
  const int b = blockIdx.z;
  const int n0 = blockIdx.x * 64;
  const int k0 = blockIdx.y * 32;
  const int tid = threadIdx.x;
  if (tid < 32) {
    const size_t base = ((size_t)b * CH + k0 + tid) * 8;
    float S1 = 0.f, S2 = 0.f;
    #pragma unroll
    for (int k = 0; k < 8; k++) { S1 += statS1[base + k]; S2 += statS2[base + k]; }
    const float M = msum[b];
    const float mu = S1 / M;
    const float q = fmaxf(S2 - mu * S1, 0.f);
    smu[tid] = mu;
    srs[tid] = 1.0f / sqrtf(q / M + 1e-4f);
  }
  __syncthreads();
  const int n = n0 + (tid >> 2);
  const int kl = (tid & 3) * 8;
  const int kc = k0 + kl;
  const float mn = mask[b * NN + n];
  const size_t zoff = ((size_t)b * NN + n) * CH + kc;
  const ushort4 h0 = *(const ushort4*)&Zsh[zoff];
  const ushort4 h1 = *(const ushort4*)&Zsh[zoff + 4];
  const ushort4 l0 = *(const ushort4*)&Zsl[zoff];
  const ushort4 l1 = *(const ushort4*)&Zsl[zoff + 4];
  float val[8];
  val[0] = (h2f(h0.x) + h2f(l0.x) - smu[kl + 0] * mn) * srs[kl + 0];
  val[1] = (h2f(h0.y) + h2f(l0.y) - smu[kl + 1] * mn) * srs[kl + 1];
  val[2] = (h2f(h0.z) + h2f(l0.z) - smu[kl + 2] * mn) * srs[kl + 2];
  val[3] = (h2f(h0.w) + h2f(l0.w) - smu[kl + 3] * mn) * srs[kl + 3];
  val[4] = (h2f(h1.x) + h2f(l1.x) - smu[kl + 4] * mn) * srs[kl + 4];
  val[5] = (h2f(h1.y) + h2f(l1.y) - smu[kl + 5] * mn) * srs[kl + 5];
  val[6] = (h2f(h1.z) + h2f(l1.z) - smu[kl + 6] * mn) * srs[kl + 6];
  val[7] = (h2f(h1.w) + h2f(l1.w) - smu[kl + 7] * mn) * srs[kl + 7];
  float s = 0.f;
  ush hv[8], lv[8];
  #pragma unroll
  for (int j = 0; j < 8; j++) {
    s += val[j] * val[j];
    hv[j] = f2h(val[j]);
    lv[j] = f2h(val[j] - h2f(hv[j]));
  }
  const size_t off = ((size_t)b * NN + n) * CH + kc;
  *(ushort4*)&Th[off] = *(ushort4*)&hv[0];
  *(ushort4*)&Th[off + 4] = *(ushort4*)&hv[4];
  *(ushort4*)&Tl[off] = *(ushort4*)&lv[0];
  *(ushort4*)&Tl[off + 4] = *(ushort4*)&lv[4];
  s += __shfl_xor(s, 1, 64);
  s += __shfl_xor(s, 2, 64);
  if ((tid & 3) == 0) n2part[((size_t)b * 8 + blockIdx.y) * NN + n] = s;
}

// ---------- gram v7: fp16 2-product asym, upper-tri tiles, fp16 D direct stores ----------
__global__ __launch_bounds__(256, 3)
void gram_v7_kernel(const ush* __restrict__ Yth, const ush* __restrict__ Ytl,
                    const float* __restrict__ n2part, const float* __restrict__ mask,
                    const float* __restrict__ posv, ush* __restrict__ Dp,
                    float* __restrict__ sigpart) {
  __shared__ ush lds[24576];           // 2 x 12288 dbuf (48 KB)
  __shared__ float sn2[256];
  __shared__ float spv[256];
  const int bid = blockIdx.x;
  const int logical = (bid & 7) * 72 + (bid >> 3);
  const int b = logical / 36;
  int t = logical - b * 36;
  int ty = 0;
  while (t >= 8 - ty) { t -= 8 - ty; ++ty; }
  const int tx = ty + t;
  const int i0 = ty * 128;
  const int j0 = tx * 128;
  {
    const int tt = threadIdx.x;
    const int nn = (tt < 128) ? (i0 + tt) : (j0 + tt - 128);
    const float pv = posv[b * NN + nn];
    float s = pv * pv;
    #pragma unroll
    for (int kb = 0; kb < 8; kb++) s += n2part[((size_t)b * 8 + kb) * NN + nn];
    sn2[tt] = s;
    spv[tt] = pv;
  }
  const ush* Ah = Yth + (size_t)b * NN * CH + (size_t)i0 * CH;
  const ush* Al = Ytl + (size_t)b * NN * CH + (size_t)i0 * CH;
  const ush* Bh = Yth + (size_t)b * NN * CH + (size_t)j0 * CH;
  f4 acc[4][4];
  const f4 z4 = {0.f, 0.f, 0.f, 0.f};
  #pragma unroll
  for (int mi = 0; mi < 4; mi++)
    #pragma unroll
    for (int ni = 0; ni < 4; ni++) acc[mi][ni] = z4;
  stageG(Ah, Al, Bh, CH, 0, lds);
  __syncthreads();
  int pb = 0;
  for (int kt = 32; kt < CH; kt += 32) {
    stageG(Ah, Al, Bh, CH, kt, lds + (pb ^ 1) * 12288);
    computeG(lds + pb * 12288, acc);
    __syncthreads();
    pb ^= 1;
  }
  computeG(lds + pb * 12288, acc);
  const int lane = threadIdx.x & 63;
  const int wid = threadIdx.x >> 6;
  const int wr = wid >> 1, wc = wid & 1;
  const int frow = lane & 15, hh = lane >> 4;
  const float scale = 3.0f / 257.0f;
  float lsum = 0.f;
  #pragma unroll
  for (int ni = 0; ni < 4; ni++) {
    const int jl = wc * 64 + ni * 16 + frow;
    const int j = j0 + jl;
    const float n2j = sn2[128 + jl];
    const float pj = spv[128 + jl];
    const float mkj = mask[b * NN + j];
    #pragma unroll
    for (int mi = 0; mi < 4; mi++) {
      const int il = wr * 64 + mi * 16 + hh * 4;
      ush dv[4];
      #pragma unroll
      for (int r = 0; r < 4; r++) {
        const int i = i0 + il + r;
        const float g = acc[mi][ni][r] + spv[il + r] * pj;
        const float D = scale * (sn2[il + r] + n2j - 2.0f * g);
        const float d = sqrtf(fmaxf(D, 1e-12f));
        const float mmv = mask[b * NN + i] * mkj;
        const float wd = d * mmv;
        lsum += wd * mmv;
        dv[r] = f2h(wd);
      }
      if (ty != tx) {
        uint2 mr;
        mr.x = (unsigned)dv[0] | ((unsigned)dv[1] << 16);
        mr.y = (unsigned)dv[2] | ((unsigned)dv[3] << 16);
        *(uint2*)&Dp[((size_t)b * NN + j) * NN + i0 + il] = mr;
      }
      #pragma unroll
      for (int r = 0; r < 4; r++) {
        const unsigned v = dv[r];
        const unsigned vp = (unsigned)__shfl_xor((int)v, 1, 64);
        if ((frow & 1) == 0)
          *(unsigned*)&Dp[((size_t)b * NN + i0 + il + r) * NN + j] = v | (vp << 16);
      }
    }
  }
  if (ty != tx) lsum *= 2.0f;
  #pragma unroll
  for (int off = 32; off > 0; off >>= 1) lsum += __shfl_down(lsum, off, 64);
  __syncthreads();
  float* rbuf = (float*)lds;
  if (lane == 0) rbuf[wid] = lsum;
  __syncthreads();
  if (threadIdx.x == 0)
    sigpart[(size_t)b * 64 + ty * 8 + tx] = rbuf[0] + rbuf[1] + rbuf[2] + rbuf[3];
}

// ---------- expw v4: sigma reduce inlined; read fp16 D, write W' fp16 plane ----------
__global__ void expw4_kernel(const ush* __restrict__ Dp, const float* __restrict__ mask,
                             const float* __restrict__ sigpart, const float* __restrict__ msum,
                             ush* __restrict__ Wp) {
  __shared__ float sfb;
  const int b = blockIdx.y, n = blockIdx.x;
  const int t = threadIdx.x;
  {
    float v = 0.f;
    if (t < 64) {
      const int sy = t >> 3, sx = t & 7;
      if (sy <= sx) v = sigpart[b * 64 + t];
    }
    v = blockReduceSum(v);
    if (t == 0) { const float ms = msum[b]; sfb = -10.0f * ms * ms / v; }
  }
  __syncthreads();
  const float fb = sfb;
  const float mn = mask[b * NN + n];
  const size_t roff = ((size_t)b * NN + n) * NN;
  const float4 mk = ((const float4*)(mask + b * NN))[t];
  const ushort4 dp = *(const ushort4*)&Dp[roff + t * 4];
  const float w0 = __expf(fb * h2f(dp.x)) * mn * mk.x;
  const float w1 = __expf(fb * h2f(dp.y)) * mn * mk.y;
  const float w2 = __expf(fb * h2f(dp.z)) * mn * mk.z;
  const float w3 = __expf(fb * h2f(dp.w)) * mn * mk.w;
  const float s = blockReduceSum(w0 + w1 + w2 + w3);
  float v0 = -w0, v1 = -w1, v2 = -w2, v3 = -w3;
  if ((n >> 2) == t) {
    const int r = n & 3;
    if (r == 0) v0 += s; else if (r == 1) v1 += s; else if (r == 2) v2 += s; else v3 += s;
  }
  ushort4 h4;
  h4.x = f2h(v0); h4.y = f2h(v1); h4.z = f2h(v2); h4.w = f2h(v3);
  *(ushort4*)&Wp[roff + t * 4] = h4;
}

// ---------- cvall v4 (fp16): C[g] = Kis[g]*(W[g]@X)*mask; direct fragment stores ----------
__global__ __launch_bounds__(256, 3)
void cvall_kernel(const ush* __restrict__ Ap, const ush* __restrict__ Bth,
                  const ush* __restrict__ Btl, const float* __restrict__ mask,
                  const float* __restrict__ Kis, unsigned int* __restrict__ Cpack,
                  ush* __restrict__ C2h, ush* __restrict__ C2l) {
  __shared__ ush lds[24576];
  const int bid = blockIdx.x;
  const int logical = (bid & 7) * 96 + (bid >> 3);
  const int b = logical / 48;
  const int inner = logical - b * 48;
  const int c0g = inner & 7;
  const int r0g = inner >> 3;
  const int r0 = r0g * 128;
  const int c0 = c0g * 128;
  const ush* Aq = Ap + (size_t)r0 * CH;
  const ush* Bh = Bth + (size_t)b * NN * CH + (size_t)c0 * CH;
  const ush* Bl = Btl + (size_t)b * NN * CH + (size_t)c0 * CH;
  f4 acc[4][4];
  const f4 z4 = {0.f, 0.f, 0.f, 0.f};
  #pragma unroll
  for (int mi = 0; mi < 4; mi++)
    #pragma unroll
    for (int ni = 0; ni < 4; ni++) acc[mi][ni] = z4;
  stageCV(Aq, CH, Bh, Bl, CH, 0, lds);
  __syncthreads();
  int pb = 0;
  for (int kt = 32; kt < CH; kt += 32) {
    stageCV(Aq, CH, Bh, Bl, CH, kt, lds + (pb ^ 1) * 12288);
    computeCV(lds + pb * 12288, acc);
    __syncthreads();
    pb ^= 1;
  }
  computeCV(lds + pb * 12288, acc);
  const int lane = threadIdx.x & 63;
  const int wid = threadIdx.x >> 6;
  const int wr = wid >> 1, wc = wid & 1;
  const int frow = lane & 15, hh = lane >> 4;
  const float alpha = Kis[r0g >> 1];
  #pragma unroll
  for (int ni = 0; ni < 4; ni++) {
    const int jl = wc * 64 + ni * 16 + frow;
    const int col = c0 + jl;
    const float am = alpha * mask[b * NN + col];
    #pragma unroll
    for (int mi = 0; mi < 4; mi++) {
      const int il = wr * 64 + mi * 16 + hh * 4;
      #pragma unroll
      for (int r = 0; r < 4; r++) {
        const int row = r0 + il + r;
        const float v = acc[mi][ni][r] * am;
        const ush h = f2h(v);
        const ush l = f2h(v - h2f(h));
        const unsigned pv = (unsigned)h | ((unsigned)l << 16);
        const unsigned pvp = (unsigned)__shfl_xor((int)pv, 1, 64);
        if ((frow & 1) == 0) {
          if (r0g < 4) {
            uint2 w2; w2.x = pv; w2.y = pvp;
            *(uint2*)&Cpack[((size_t)b * 512 + row) * NN + col] = w2;
          } else {
            const size_t obase = ((size_t)b * 256 + (row - 512)) * NN + col;
            const unsigned hw = (pv & 0xffffu) | (pvp << 16);
            const unsigned lw = (pv >> 16) | (pvp & 0xffff0000u);
            *(unsigned*)&C2h[obase] = hw;
            *(unsigned*)&C2l[obase] = lw;
          }
        }
      }
    }
  }
}

// ---------- mm1 v6 (fp16): out = X@W' + add(packed) ----------
// OUTMODE 0: row-major fp16 split out (+STATS on o)
// OUTMODE 2: outF = zin - 0.01*o (fp32) + transposed fp16 Z-splits [NN][CH] (+STATS on val)
template <int OUTMODE, int STATS>
__global__ __launch_bounds__(256, 5)
void mm1_v6_kernel(const ush* __restrict__ Xh, const ush* __restrict__ Xl, const size_t xStride,
                   const ush* __restrict__ Wp,
                   const unsigned int* __restrict__ addp, const size_t aStride,
                   const float* __restrict__ zin, const float* __restrict__ mask,
                   float* __restrict__ outF, ush* __restrict__ outH, ush* __restrict__ outL,
                   float* __restrict__ statS1, float* __restrict__ statS2) {
  __shared__ ush lds[16384];
  const int bid = blockIdx.x;
  const int logical = (bid & 7) * 64 + (bid >> 3);
  const int b = logical >> 5;
  const int inner = logical & 31;
  const int n0 = (inner & 7) * 128;
  const int r0 = (inner >> 3) * 64;
  const ush* Ah = Xh + (size_t)b * xStride + (size_t)r0 * NN;
  const ush* Al = Xl + (size_t)b * xStride + (size_t)r0 * NN;
  const ush* Bp = Wp + (size_t)b * NN * NN + (size_t)n0 * NN;
  f4 acc[4][2];
  const f4 z4 = {0.f, 0.f, 0.f, 0.f};
  #pragma unroll
  for (int mi = 0; mi < 4; mi++) { acc[mi][0] = z4; acc[mi][1] = z4; }
  stageMM(Ah, Al, NN, Bp, NN, 0, lds);
  __syncthreads();
  int pb = 0;
  for (int kt = 32; kt < NN; kt += 32) {
    stageMM(Ah, Al, NN, Bp, NN, kt, lds + (pb ^ 1) * 8192);
    computeMM(lds + pb * 8192, acc);
    __syncthreads();
    pb ^= 1;
  }
  computeMM(lds + pb * 8192, acc);
  const int lane = threadIdx.x & 63;
  const int wid = threadIdx.x >> 6;
  const int frow = lane & 15, hh = lane >> 4;
  float a1[4][4];
  float a2[4][4];
  if (STATS) {
    #pragma unroll
    for (int mi = 0; mi < 4; mi++)
      #pragma unroll
      for (int r = 0; r < 4; r++) { a1[mi][r] = 0.f; a2[mi][r] = 0.f; }
  }
  __syncthreads();
  unsigned int* tl = (unsigned int*)lds;   // [128][64] swizzled packed splits
  #pragma unroll
  for (int ni = 0; ni < 2; ni++) {
    const int jl = wid * 32 + ni * 16 + frow;
    const int col = n0 + jl;
    const float mk = STATS ? mask[b * NN + col] : 0.f;
    #pragma unroll
    for (int mi = 0; mi < 4; mi++) {
      const int il = mi * 16 + hh * 4;
      unsigned int pv[4];
      #pragma unroll
      for (int r = 0; r < 4; r++) {
        const int row = r0 + il + r;
        const unsigned int av = addp[(size_t)b * aStride + (size_t)row * NN + col];
        const float o = acc[mi][ni][r] + h2f((ush)(av & 0xffffu)) + h2f((ush)(av >> 16));
        float val;
        if (OUTMODE == 2) {
          const size_t ooff = (size_t)b * CH * NN + (size_t)row * NN + col;
          val = zin[ooff] - 0.01f * o;
          outF[ooff] = val;
        } else {
          val = o;
        }
        if (STATS) { a1[mi][r] += val * mk; a2[mi][r] += val * val * mk; }
        const ush h = f2h(val);
        const ush l = f2h(val - h2f(h));
        pv[r] = (unsigned int)h | ((unsigned int)l << 16);
      }
      const int slot = (il >> 2) ^ (jl & 15);
      *(uint4*)&tl[jl * 64 + slot * 4] = *(uint4*)pv;
    }
  }
  __syncthreads();
  if (OUTMODE == 0) {
    const int rrow = threadIdx.x >> 2;
    const int rch = (threadIdx.x & 3) * 32;
    const size_t obase = ((size_t)b * 256 + r0 + rrow) * NN + n0 + rch;
    #pragma unroll
    for (int g = 0; g < 4; g++) {
      unsigned int hw[4], lw[4];
      #pragma unroll
      for (int q = 0; q < 4; q++) {
        unsigned int h2[2], l2[2];
        #pragma unroll
        for (int e = 0; e < 2; e++) {
          const int jl = rch + g * 8 + q * 2 + e;
          const int slot = (rrow >> 2) ^ (jl & 15);
          const unsigned int v = tl[jl * 64 + slot * 4 + (rrow & 3)];
          h2[e] = v & 0xffffu; l2[e] = v >> 16;
        }
        hw[q] = h2[0] | (h2[1] << 16);
        lw[q] = l2[0] | (l2[1] << 16);
      }
      *(uint4*)&outH[obase + g * 8] = *(uint4*)hw;
      *(uint4*)&outL[obase + g * 8] = *(uint4*)lw;
    }
  } else {
    const int nloc = threadIdx.x >> 1;
    const int ch0 = (threadIdx.x & 1) * 32;
    #pragma unroll
    for (int half = 0; half < 2; half++) {
      unsigned int hw[8], lw[8];
      #pragma unroll
      for (int q = 0; q < 8; q++) {
        const int ila = ch0 + half * 16 + q * 2;
        const int ilb = ila + 1;
        const unsigned int va = tl[nloc * 64 + (((ila >> 2) ^ (nloc & 15)) << 2) + (ila & 3)];
        const unsigned int vb = tl[nloc * 64 + (((ilb >> 2) ^ (nloc & 15)) << 2) + (ilb & 3)];
        hw[q] = (va & 0xffffu) | (vb << 16);
        lw[q] = (va >> 16) | (vb & 0xffff0000u);
      }
      const size_t zoff = ((size_t)b * NN + n0 + nloc) * CH + r0 + ch0 + half * 16;
      *(uint4*)&outH[zoff] = *(uint4*)&hw[0];
      *(uint4*)&outH[zoff + 8] = *(uint4*)&hw[4];
      *(uint4*)&outL[zoff] = *(uint4*)&lw[0];
      *(uint4*)&outL[zoff + 8] = *(uint4*)&lw[4];
    }
  }
  if (STATS) {
    #pragma unroll
    for (int mi = 0; mi < 4; mi++)
      #pragma unroll
      for (int r = 0; r < 4; r++) {
        #pragma unroll
        for (int d = 1; d < 16; d <<= 1) {
          a1[mi][r] += __shfl_xor(a1[mi][r], d, 64);
          a2[mi][r] += __shfl_xor(a2[mi][r], d, 64);
        }
      }
    __syncthreads();
    float* s1b = (float*)lds;
    float* s2b = s1b + 256;
    if (frow == 0) {
      #pragma unroll
      for (int mi = 0; mi < 4; mi++)
        #pragma unroll
        for (int r = 0; r < 4; r++) {
          const int row = mi * 16 + hh * 4 + r;
          s1b[wid * 64 + row] = a1[mi][r];
          s2b[wid * 64 + row] = a2[mi][r];
        }
    }
    __syncthreads();
    if (threadIdx.x < 64) {
      const int row = threadIdx.x;
      const float p1 = s1b[row] + s1b[64 + row] + s1b[128 + row] + s1b[192 + row];
      const float p2 = s2b[row] + s2b[64 + row] + s2b[128 + row] + s2b[192 + row];
      const int nblk = n0 >> 7;
      statS1[((size_t)b * CH + r0 + row) * 8 + nblk] = p1;
      statS2[((size_t)b * CH + r0 + row) * 8 + nblk] = p2;
    }
  }
}

// ---------- csq: partial col sums of ((U-rmean)*mask)^2; rmean inlined ----------
__global__ void csq_kernel(const ush* __restrict__ Uh, const ush* __restrict__ Ul,
                           const float* __restrict__ mask, const float* __restrict__ statS1,
                           const float* __restrict__ msum, float* __restrict__ part) {
  __shared__ float srm[16];
  const int b = blockIdx.y, cc = blockIdx.x;
  if (threadIdx.x < 16) {
    const size_t base = ((size_t)b * CH + cc * 16 + threadIdx.x) * 8;
    float S1 = 0.f;
    #pragma unroll
    for (int k = 0; k < 8; k++) S1 += statS1[base + k];
    srm[threadIdx.x] = S1 / msum[b];
  }
  __syncthreads();
  const int n = threadIdx.x * 4;
  const float4 m4 = *(const float4*)&mask[b * NN + n];
  float4 s4 = {0.f, 0.f, 0.f, 0.f};
  for (int r = 0; r < 16; r++) {
    const int c = cc * 16 + r;
    const float rm = srm[r];
    const size_t uoff = ((size_t)b * 256 + c) * NN + n;
    const ushort4 uh = *(const ushort4*)&Uh[uoff];
    const ushort4 ul = *(const ushort4*)&Ul[uoff];
    float a;
    a = (h2f(uh.x) + h2f(ul.x) - rm) * m4.x; s4.x += a * a;
    a = (h2f(uh.y) + h2f(ul.y) - rm) * m4.y; s4.y += a * a;
    a = (h2f(uh.z) + h2f(ul.z) - rm) * m4.z; s4.z += a * a;
    a = (h2f(uh.w) + h2f(ul.w) - rm) * m4.w; s4.w += a * a;
  }
  *(float4*)&part[((size_t)(b * 16 + cc)) * NN + n] = s4;
}

// ---------- tsplitN2: A=relu((U-rmean)*mask*rs); rmean+rs inlined ----------
__global__ void tsplitN2_kernel(const ush* __restrict__ Uh, const ush* __restrict__ Ul,
                                const float* __restrict__ mask, const float* __restrict__ statS1,
                                const float* __restrict__ msum, const float* __restrict__ part,
                                ush* __restrict__ Th, ush* __restrict__ Tl) {
  __shared__ float t[32][65];
  __shared__ float srm[32];
  __shared__ float srsl[64];
  const int b = blockIdx.z;
  const int n0 = blockIdx.x * 64;
  const int k0 = blockIdx.y * 32;
  const int tid = threadIdx.x;
  if (tid < 32) {
    const size_t base = ((size_t)b * CH + k0 + tid) * 8;
    float S1 = 0.f;
    #pragma unroll
    for (int k = 0; k < 8; k++) S1 += statS1[base + k];
    srm[tid] = S1 / msum[b];
  } else if (tid < 96) {
    const int n = n0 + tid - 32;
    float s = 0.001f;
    #pragma unroll
    for (int cc = 0; cc < 16; cc++) s += part[((size_t)(b * 16 + cc)) * NN + n];
    srsl[tid - 32] = 1.0f / sqrtf(s);
  }
  __syncthreads();
  const int lr = tid >> 3;
  const int lc = (tid & 7) * 8;
  const int gc = k0 + lr;
  const float rm = srm[lr];
  const float4 ma = *(const float4*)&mask[b * NN + n0 + lc];
  const float4 mb = *(const float4*)&mask[b * NN + n0 + lc + 4];
  const size_t uoff = ((size_t)b * 256 + gc) * NN + n0 + lc;
  const ushort4 ha = *(const ushort4*)&Uh[uoff];
  const ushort4 hb = *(const ushort4*)&Uh[uoff + 4];
  const ushort4 la = *(const ushort4*)&Ul[uoff];
  const ushort4 lb = *(const ushort4*)&Ul[uoff + 4];
  t[lr][lc + 0] = fmaxf((h2f(ha.x) + h2f(la.x) - rm) * ma.x * srsl[lc + 0], 0.f);
  t[lr][lc + 1] = fmaxf((h2f(ha.y) + h2f(la.y) - rm) * ma.y * srsl[lc + 1], 0.f);
  t[lr][lc + 2] = fmaxf((h2f(ha.z) + h2f(la.z) - rm) * ma.z * srsl[lc + 2], 0.f);
  t[lr][lc + 3] = fmaxf((h2f(ha.w) + h2f(la.w) - rm) * ma.w * srsl[lc + 3], 0.f);
  t[lr][lc + 4] = fmaxf((h2f(hb.x) + h2f(lb.x) - rm) * mb.x * srsl[lc + 4], 0.f);
  t[lr][lc + 5] = fmaxf((h2f(hb.y) + h2f(lb.y) - rm) * mb.y * srsl[lc + 5], 0.f);
  t[lr][lc + 6] = fmaxf((h2f(hb.z) + h2f(lb.z) - rm) * mb.z * srsl[lc + 6], 0.f);
  t[lr][lc + 7] = fmaxf((h2f(hb.w) + h2f(lb.w) - rm) * mb.w * srsl[lc + 7], 0.f);
  __syncthreads();
  const int on = tid >> 2;
  const int ok = (tid & 3) * 8;
  ush hv[8], lv[8];
  #pragma unroll
  for (int j = 0; j < 8; j++) {
    const float v = t[ok + j][on];
    hv[j] = f2h(v); lv[j] = f2h(v - h2f(hv[j]));
  }
  const size_t off = ((size_t)b * NN + n0 + on) * CH + k0 + ok;
  *(ushort4*)&Th[off] = *(ushort4*)&hv[0];
  *(ushort4*)&Th[off + 4] = *(ushort4*)&hv[4];
  *(ushort4*)&Tl[off] = *(ushort4*)&lv[0];
  *(ushort4*)&Tl[off + 4] = *(ushort4*)&lv[4];
}

// ---------- Zout = (Wend @ Z)*mask; write + centered copy ----------
__global__ void zout_kernel(const float* __restrict__ Z, const float* __restrict__ Wend,
                            const float* __restrict__ mask, float* __restrict__ outZ,
                            float* __restrict__ Zcent) {
  const int b = blockIdx.x;
  __shared__ float w[3 * CH];
  for (int i = threadIdx.x; i < 3 * CH; i += 256) w[i] = Wend[i];
  __syncthreads();
  float a[3][4];
  #pragma unroll
  for (int j = 0; j < 4; j++) { a[0][j] = 0.f; a[1][j] = 0.f; a[2][j] = 0.f; }
  const float* Zb = Z + (size_t)b * CH * NN;
  for (int c = 0; c < CH; c++) {
    const float w0 = w[c], w1 = w[CH + c], w2 = w[2 * CH + c];
    #pragma unroll
    for (int j = 0; j < 4; j++) {
      float zv = Zb[(size_t)c * NN + threadIdx.x + j * 256];
      a[0][j] += w0 * zv; a[1][j] += w1 * zv; a[2][j] += w2 * zv;
    }
  }
  float sum[3] = {0.f, 0.f, 0.f};
  #pragma unroll
  for (int j = 0; j < 4; j++) {
    const int n = threadIdx.x + j * 256;
    const float mv = mask[b * NN + n];
    #pragma unroll
    for (int o = 0; o < 3; o++) {
      a[o][j] *= mv;
      outZ[((size_t)b * 3 + o) * NN + n] = a[o][j];
      sum[o] += a[o][j];
    }
  }
  for (int o = 0; o < 3; o++) {
    float s = blockReduceSum(sum[o]);
    const float mean = s * (1.0f / NN);
    #pragma unroll
    for (int j = 0; j < 4; j++) {
      const int n = threadIdx.x + j * 256;
      Zcent[((size_t)b * 3 + o) * NN + n] = a[o][j] - mean;
    }
  }
}

// ---------- final distances ----------
__global__ void dist_kernel(const float* __restrict__ Zcent, float* __restrict__ outD) {
  const int b = blockIdx.z;
  const int n = blockIdx.y;
  const int m = blockIdx.x * 256 + threadIdx.x;
  const float* Zb = Zcent + (size_t)b * 3 * NN;
  const float x0 = Zb[n], x1 = Zb[NN + n], x2 = Zb[2 * NN + n];
  const float d0 = x0 - Zb[m], d1 = x1 - Zb[NN + m], d2 = x2 - Zb[2 * NN + m];
  const float D = d0 * d0 + d1 * d1 + d2 * d2;
  outD[((size_t)b * NN + n) * NN + m] = sqrtf(fmaxf(D, 1e-12f));
}

extern "C" void kernel_launch(void* const* d_in, const int* in_sizes, int n_in,
                              void* d_out, int out_size, void* d_ws, size_t ws_size,
                              hipStream_t stream) {
  const float* Zin  = (const float*)d_in[0];
  const float* mask = (const float*)d_in[1];
  const float* K0   = (const float*)d_in[2];
  const float* Knet = (const float*)d_in[3];
  const float* W    = (const float*)d_in[4];
  const float* Wend = (const float*)d_in[5];
  float* out = (float*)d_out;

  // d_out dist region (64 MB): Wp fp16 (32 MB) | Dp fp16 (32 MB)
  ush* Wp = (ush*)out;
  ush* Dp = Wp + (size_t)BB * NN * NN;
  float* outZ = out + (size_t)BB * NN * NN;

  float* p = (float*)d_ws;
  // union: gram phase {Yth | Ytl fp16 [NN][CH]}; GEMM phase {Cpack u32 | C2h | C2l fp16}
  float* uni = p; p += (size_t)BB * 768 * NN;     // 50.33 MB
  ush* Yth = (ush*)uni;
  ush* Ytl = Yth + (size_t)BB * NN * CH;
  unsigned int* Cpack = (unsigned int*)uni;
  ush* C2h = (ush*)(uni + (size_t)BB * 512 * NN);
  ush* C2l = C2h + (size_t)BB * 256 * NN;

  float* Zcur = p; p += (size_t)BB * CH * NN;
  ush* Thb = (ush*)p; p += (size_t)BB * NN * CH / 2;   // T / A-splits (shared)
  ush* Tlb = (ush*)p; p += (size_t)BB * NN * CH / 2;
  ush* Zsh = (ush*)p; p += (size_t)BB * NN * CH / 2;   // Z transposed fp16 splits
  ush* Zsl = (ush*)p; p += (size_t)BB * NN * CH / 2;
  ush* Wm = (ush*)p; p += (size_t)18 * CH * CH / 2;
  ush* Wt = (ush*)p; p += (size_t)18 * CH * CH / 2;
  float* msum  = p; p += BB;
  float* posv  = p; p += BB * NN;
  float* sigp  = p; p += BB * 64;
  float* statS1= p; p += (size_t)BB * CH * 8;
  float* statS2= p; p += (size_t)BB * CH * 8;
  float* n2part= p; p += (size_t)BB * 8 * NN;
  float* partb = p; p += (size_t)BB * 16 * NN;
  float* Zcent = p; p += BB * 3 * NN;

  const dim3 gtsZ(NN / 64, CH / 32, BB);
  const size_t sC = (size_t)512 * NN;
  const size_t sT = (size_t)CH * NN;

  masksum_kernel<<<BB, 256, 0, stream>>>(mask, msum, posv);
  wprep_kernel<<<dim3(16, 18), 256, 0, stream>>>(W, Wm, Wt);
  k0_kernel<<<dim3(CH / 8, BB), 256, 0, stream>>>(Zin, K0, mask, Zcur, statS1, statS2);
  tsplitZ_kernel<<<gtsZ, 256, 0, stream>>>(Zcur, Zsh, Zsl);

  for (int layer = 0; layer < NLAYERS; layer++) {
    tsplitY2_kernel<<<gtsZ, 256, 0, stream>>>(Zsh, Zsl, mask, statS1, statS2, msum,
                                              Yth, Ytl, n2part);
    gram_v7_kernel<<<576, 256, 0, stream>>>(Yth, Ytl, n2part, mask, posv, Dp, sigp);
    expw4_kernel<<<dim3(NN, BB), 256, 0, stream>>>(Dp, mask, sigp, msum, Wp);

    const ush* Am = Wm + (size_t)layer * 3 * CH * CH;
    const ush* At = Wt + (size_t)layer * 3 * CH * CH;
    const float* Ki = Knet + layer * 3;

    // ---- Ai = C0 + (C1 + C2@L)@L, C = Ki*(Wi@Z)*mask, L rows = W' ----
    cvall_kernel<<<768, 256, 0, stream>>>(Am, Zsh, Zsl, mask, Ki, Cpack, C2h, C2l);
    mm1_v6_kernel<0, 0><<<512, 256, 0, stream>>>(C2h, C2l, sT, Wp,
        Cpack + (size_t)256 * NN, sC, nullptr, nullptr, nullptr, Thb, Tlb, nullptr, nullptr);
    mm1_v6_kernel<0, 1><<<512, 256, 0, stream>>>(Thb, Tlb, sT, Wp,
        Cpack, sC, nullptr, mask, nullptr, C2h, C2l, statS1, statS2);

    csq_kernel<<<dim3(16, BB), 256, 0, stream>>>(C2h, C2l, mask, statS1, msum, partb);
    tsplitN2_kernel<<<gtsZ, 256, 0, stream>>>(C2h, C2l, mask, statS1, msum, partb, Thb, Tlb);

    // ---- Z -= 0.01 * (C0 + (C1 + C2@L)@L), C = Ki*(Wi^T@A)*mask ----
    cvall_kernel<<<768, 256, 0, stream>>>(At, Thb, Tlb, mask, Ki, Cpack, C2h, C2l);
    mm1_v6_kernel<0, 0><<<512, 256, 0, stream>>>(C2h, C2l, sT, Wp,
        Cpack + (size_t)256 * NN, sC, nullptr, nullptr, nullptr, Thb, Tlb, nullptr, nullptr);
    mm1_v6_kernel<2, 1><<<512, 256, 0, stream>>>(Thb, Tlb, sT, Wp,
        Cpack, sC, Zcur, mask, Zcur, Zsh, Zsl, statS1, statS2);
  }

  zout_kernel<<<BB, 256, 0, stream>>>(Zcur, Wend, mask, outZ, Zcent);
  dist_kernel<<<dim3(NN / 256, NN, BB), 256, 0, stream>>>(Zcent, out);
}

// Round 15
// 1759.394 us; speedup vs baseline: 1.0541x; 1.0243x over previous
//
#include <hip/hip_runtime.h>
#include <hip/hip_fp16.h>
#include <math.h>

#define BB 16
#define CIN 40
#define CH 256
#define NN 1024
#define NLAYERS 6

typedef unsigned short ush;
typedef __attribute__((ext_vector_type(8))) _Float16 h8;
typedef __attribute__((ext_vector_type(4))) float f4;

__device__ __forceinline__ ush f2h(float x) {
  __half h = __float2half(x);
  return *(ush*)&h;
}
__device__ __forceinline__ float h2f(ush u) {
  __half h = *(__half*)&u;
  return __half2float(h);
}
__device__ __forceinline__ float fast_tanh(float x) {
  const float e = __expf(2.0f * x);
  return (e - 1.0f) / (e + 1.0f);
}

#define GLD16(gp, lp) __builtin_amdgcn_global_load_lds( \
    (const __attribute__((address_space(1))) void*)(gp), \
    (__attribute__((address_space(3))) void*)(lp), 16, 0, 0)

// ---------- block reduction (256 threads = 4 waves) ----------
__device__ __forceinline__ float blockReduceSum(float v) {
  __shared__ float sred[4];
  const int lane = threadIdx.x & 63;
  const int wid  = threadIdx.x >> 6;
  #pragma unroll
  for (int off = 32; off > 0; off >>= 1) v += __shfl_down(v, off, 64);
  __syncthreads();
  if (lane == 0) sred[wid] = v;
  __syncthreads();
  return sred[0] + sred[1] + sred[2] + sred[3];
}

// ================= gram core (fp16, asym 2-product): A pair + B hi plane, 128x128 ==========
__device__ __forceinline__ void stageG(
    const ush* __restrict__ Ah, const ush* __restrict__ Al,
    const ush* __restrict__ Bh, const int s, const int kt, ush* buf) {
  const int lane = threadIdx.x & 63;
  const int wid = threadIdx.x >> 6;
  const int srow = lane >> 2;
  const int sl = (lane & 3) ^ ((srow >> 1) & 3);
  #pragma unroll
  for (int cc = 0; cc < 6; cc++) {
    const int c = wid * 6 + cc;
    const ush* src;
    if (c < 8)       src = Ah + (size_t)(c * 16 + srow) * s + kt + sl * 8;
    else if (c < 16) src = Al + (size_t)((c - 8) * 16 + srow) * s + kt + sl * 8;
    else             src = Bh + (size_t)((c - 16) * 16 + srow) * s + kt + sl * 8;
    GLD16(src, buf + c * 512 + lane * 8);
  }
}

__device__ __forceinline__ void computeG(const ush* buf, f4 acc[4][4]) {
  const int lane = threadIdx.x & 63;
  const int wid = threadIdx.x >> 6;
  const int wr = wid >> 1, wc = wid & 1;
  const int frow = lane & 15;
  const int slot8 = (((lane >> 4) ^ ((frow >> 1) & 3)) << 3);
  h8 ah[4], al[4], b_[4];
  #pragma unroll
  for (int mi = 0; mi < 4; mi++) {
    const int off = (wr * 64 + mi * 16 + frow) * 32 + slot8;
    ah[mi] = *(const h8*)&buf[off];
    al[mi] = *(const h8*)&buf[4096 + off];
  }
  #pragma unroll
  for (int ni = 0; ni < 4; ni++) {
    const int off = (wc * 64 + ni * 16 + frow) * 32 + slot8;
    b_[ni] = *(const h8*)&buf[8192 + off];
  }
  #pragma unroll
  for (int mi = 0; mi < 4; mi++)
    #pragma unroll
    for (int ni = 0; ni < 4; ni++) {
      acc[mi][ni] = __builtin_amdgcn_mfma_f32_16x16x32_f16(ah[mi], b_[ni], acc[mi][ni], 0, 0, 0);
      acc[mi][ni] = __builtin_amdgcn_mfma_f32_16x16x32_f16(al[mi], b_[ni], acc[mi][ni], 0, 0, 0);
    }
}

// ================= cvall core (fp16): A 1 plane + B 2 planes, 128x128, 2 products ==========
__device__ __forceinline__ void stageCV(
    const ush* __restrict__ Ap, const int sA,
    const ush* __restrict__ Bh, const ush* __restrict__ Bl, const int sB,
    const int kt, ush* buf) {
  const int lane = threadIdx.x & 63;
  const int wid = threadIdx.x >> 6;
  const int srow = lane >> 2;
  const int sl = (lane & 3) ^ ((srow >> 1) & 3);
  #pragma unroll
  for (int cc = 0; cc < 6; cc++) {
    const int c = wid * 6 + cc;
    const ush* src;
    if (c < 8)       src = Ap + (size_t)(c * 16 + srow) * sA + kt + sl * 8;
    else if (c < 16) src = Bh + (size_t)((c - 8) * 16 + srow) * sB + kt + sl * 8;
    else             src = Bl + (size_t)((c - 16) * 16 + srow) * sB + kt + sl * 8;
    GLD16(src, buf + c * 512 + lane * 8);
  }
}

__device__ __forceinline__ void computeCV(const ush* buf, f4 acc[4][4]) {
  const int lane = threadIdx.x & 63;
  const int wid = threadIdx.x >> 6;
  const int wr = wid >> 1, wc = wid & 1;
  const int frow = lane & 15;
  const int slot8 = (((lane >> 4) ^ ((frow >> 1) & 3)) << 3);
  h8 a_[4], bh_[4], bl_[4];
  #pragma unroll
  for (int mi = 0; mi < 4; mi++) {
    const int off = (wr * 64 + mi * 16 + frow) * 32 + slot8;
    a_[mi] = *(const h8*)&buf[off];
  }
  #pragma unroll
  for (int ni = 0; ni < 4; ni++) {
    const int off = (wc * 64 + ni * 16 + frow) * 32 + slot8;
    bh_[ni] = *(const h8*)&buf[4096 + off];
    bl_[ni] = *(const h8*)&buf[8192 + off];
  }
  #pragma unroll
  for (int mi = 0; mi < 4; mi++)
    #pragma unroll
    for (int ni = 0; ni < 4; ni++) {
      acc[mi][ni] = __builtin_amdgcn_mfma_f32_16x16x32_f16(a_[mi], bh_[ni], acc[mi][ni], 0, 0, 0);
      acc[mi][ni] = __builtin_amdgcn_mfma_f32_16x16x32_f16(a_[mi], bl_[ni], acc[mi][ni], 0, 0, 0);
    }
}

// ================= mm1 core (fp16): A 2 planes + B 1 plane, 64x128, 2 products =============
__device__ __forceinline__ void stageMM(
    const ush* __restrict__ Ah, const ush* __restrict__ Al, const int sA,
    const ush* __restrict__ Bp, const int sB, const int kt, ush* buf) {
  const int lane = threadIdx.x & 63;
  const int wid = threadIdx.x >> 6;
  const int srow = lane >> 2;
  const int sl = (lane & 3) ^ ((srow >> 1) & 3);
  #pragma unroll
  for (int cc = 0; cc < 4; cc++) {
    const int c = wid * 4 + cc;
    const ush* src;
    if (c < 4)       src = Ah + (size_t)(c * 16 + srow) * sA + kt + sl * 8;
    else if (c < 8)  src = Al + (size_t)((c - 4) * 16 + srow) * sA + kt + sl * 8;
    else             src = Bp + (size_t)((c - 8) * 16 + srow) * sB + kt + sl * 8;
    GLD16(src, buf + c * 512 + lane * 8);
  }
}

__device__ __forceinline__ void computeMM(const ush* buf, f4 acc[4][2]) {
  const int lane = threadIdx.x & 63;
  const int wid = threadIdx.x >> 6;
  const int frow = lane & 15;
  const int slot8 = (((lane >> 4) ^ ((frow >> 1) & 3)) << 3);
  h8 ah[4], al[4], b_[2];
  #pragma unroll
  for (int mi = 0; mi < 4; mi++) {
    const int off = (mi * 16 + frow) * 32 + slot8;
    ah[mi] = *(const h8*)&buf[off];
    al[mi] = *(const h8*)&buf[2048 + off];
  }
  #pragma unroll
  for (int ni = 0; ni < 2; ni++) {
    const int off = (wid * 32 + ni * 16 + frow) * 32 + slot8;
    b_[ni] = *(const h8*)&buf[4096 + off];
  }
  #pragma unroll
  for (int mi = 0; mi < 4; mi++)
    #pragma unroll
    for (int ni = 0; ni < 2; ni++) {
      acc[mi][ni] = __builtin_amdgcn_mfma_f32_16x16x32_f16(ah[mi], b_[ni], acc[mi][ni], 0, 0, 0);
      acc[mi][ni] = __builtin_amdgcn_mfma_f32_16x16x32_f16(al[mi], b_[ni], acc[mi][ni], 0, 0, 0);
    }
}

// ---------- Z0 = tanh(K0 @ Zin) * mask, 8 outputs/block, 256-VGPR budget (no spill) --------
__global__ __launch_bounds__(256, 2)
void k0_kernel(const float* __restrict__ Zin, const float* __restrict__ K0,
               const float* __restrict__ mask, float* __restrict__ Zc,
               float* __restrict__ statS1, float* __restrict__ statS2) {
  const int b = blockIdx.y;
  const int o0 = blockIdx.x * 8;
  __shared__ float w[8][CIN];
  __shared__ float sred1[4][8];
  __shared__ float sred2[4][8];
  for (int i = threadIdx.x; i < 8 * CIN; i += 256)
    w[i / CIN][i % CIN] = K0[(o0 + i / CIN) * CIN + i % CIN];
  __syncthreads();
  float s1[8], s2[8];
  #pragma unroll
  for (int o = 0; o < 8; o++) { s1[o] = 0.f; s2[o] = 0.f; }
  for (int n = threadIdx.x; n < NN; n += 256) {
    const float mn = mask[b * NN + n];
    float acc[8];
    #pragma unroll
    for (int o = 0; o < 8; o++) acc[o] = 0.f;
    for (int c = 0; c < CIN; c++) {
      const float zv = Zin[((size_t)b * CIN + c) * NN + n];
      #pragma unroll
      for (int o = 0; o < 8; o++) acc[o] += w[o][c] * zv;
    }
    #pragma unroll
    for (int o = 0; o < 8; o++) {
      const float z = fast_tanh(acc[o]) * mn;
      Zc[((size_t)b * CH + o0 + o) * NN + n] = z;
      s1[o] += z; s2[o] += z * z;
    }
  }
  const int lane = threadIdx.x & 63;
  const int wid = threadIdx.x >> 6;
  #pragma unroll
  for (int o = 0; o < 8; o++) {
    float r1 = s1[o], r2 = s2[o];
    #pragma unroll
    for (int off = 32; off > 0; off >>= 1) {
      r1 += __shfl_down(r1, off, 64);
      r2 += __shfl_down(r2, off, 64);
    }
    if (lane == 0) { sred1[wid][o] = r1; sred2[wid][o] = r2; }
  }
  __syncthreads();
  if (threadIdx.x < 8) {
    const int o = threadIdx.x;
    const float r1 = sred1[0][o] + sred1[1][o] + sred1[2][o] + sred1[3][o];
    const float r2 = sred2[0][o] + sred2[1][o] + sred2[2][o] + sred2[3][o];
    const size_t base = ((size_t)b * CH + o0 + o) * 8;
    statS1[base] = r1; statS2[base] = r2;
    #pragma unroll
    for (int k = 1; k < 8; k++) { statS1[base + k] = 0.f; statS2[base + k] = 0.f; }
  }
}

// ---------- masksum + centered pos-row values ----------
__global__ void masksum_kernel(const float* __restrict__ mask, float* __restrict__ msum,
                               float* __restrict__ posv) {
  const int b = blockIdx.x;
  float v = 0.f, p = 0.f;
  for (int n = threadIdx.x; n < NN; n += 256) {
    const float m = mask[b * NN + n];
    v += m;
    p += 0.5f * ((float)n * (1.0f / (NN - 1))) * m;
  }
  v = blockReduceSum(v);
  p = blockReduceSum(p);
  const float pm = p * (1.0f / NN);
  if (threadIdx.x == 0) msum[b] = v;
  for (int n = threadIdx.x; n < NN; n += 256)
    posv[b * NN + n] = 0.5f * ((float)n * (1.0f / (NN - 1))) * mask[b * NN + n] - pm;
}

// ---------- W prep: fp16 single plane of W and W^T for all 18 matrices ----------
__global__ void wprep_kernel(const float* __restrict__ W, ush* __restrict__ Wm,
                             ush* __restrict__ Wt) {
  __shared__ float t[64][65];
  const int mat = blockIdx.y;
  const int ty = blockIdx.x >> 2, tx = blockIdx.x & 3;
  const float* src = W + (size_t)mat * CH * CH;
  const int tid = threadIdx.x;
  const int lr = tid >> 2;
  const int lc = (tid & 3) * 16;
  float v[16];
  #pragma unroll
  for (int j = 0; j < 16; j += 4)
    *(float4*)&v[j] = *(const float4*)&src[(size_t)(ty * 64 + lr) * CH + tx * 64 + lc + j];
  ush hv[16];
  #pragma unroll
  for (int j = 0; j < 16; j++) {
    hv[j] = f2h(v[j]);
    t[lr][lc + j] = v[j];
  }
  const size_t offm = (size_t)mat * CH * CH + (size_t)(ty * 64 + lr) * CH + tx * 64 + lc;
  #pragma unroll
  for (int j = 0; j < 16; j += 4)
    *(ushort4*)&Wm[offm + j] = *(ushort4*)&hv[j];
  __syncthreads();
  #pragma unroll
  for (int j = 0; j < 16; j++) hv[j] = f2h(t[lc + j][lr]);
  const size_t offt = (size_t)mat * CH * CH + (size_t)(tx * 64 + lr) * CH + ty * 64 + lc;
  #pragma unroll
  for (int j = 0; j < 16; j += 4)
    *(ushort4*)&Wt[offt + j] = *(ushort4*)&hv[j];
}

// ---------- transpose+split: Zcur fp32 [CH][NN] -> fp16 splits [NN][CH] (pre-loop) ----------
__global__ void tsplitZ_kernel(const float* __restrict__ in, ush* __restrict__ Th,
                               ush* __restrict__ Tl) {
  __shared__ float t[32][65];
  const int b = blockIdx.z;
  const int n0 = blockIdx.x * 64;
  const int k0 = blockIdx.y * 32;
  const float* src = in + (size_t)b * CH * NN;
  const int tid = threadIdx.x;
  const int lr = tid >> 3;
  const int lc = (tid & 7) * 8;
  const int gk = k0 + lr;
  *(float4*)&t[lr][lc]     = *(const float4*)&src[(size_t)gk * NN + n0 + lc];
  *(float4*)&t[lr][lc + 4] = *(const float4*)&src[(size_t)gk * NN + n0 + lc + 4];
  __syncthreads();
  const int on = tid >> 2;
  const int ok = (tid & 3) * 8;
  ush hv[8], lv[8];
  #pragma unroll
  for (int j = 0; j < 8; j++) {
    const float v = t[ok + j][on];
    hv[j] = f2h(v); lv[j] = f2h(v - h2f(hv[j]));
  }
  const size_t off = ((size_t)b * NN + n0 + on) * CH + k0 + ok;
  *(ushort4*)&Th[off] = *(ushort4*)&hv[0];
  *(ushort4*)&Th[off + 4] = *(ushort4*)&hv[4];
  *(ushort4*)&Tl[off] = *(ushort4*)&lv[0];
  *(ushort4*)&Tl[off + 4] = *(ushort4*)&lv[4];
}

// ---------- tsplitY2: Z splits -> normalized Y fp16 splits + n2 partials (stats inlined) ----
__global__ void tsplitY2_kernel(const ush* __restrict__ Zsh, const ush* __restrict__ Zsl,
                                const float* __restrict__ mask,
                                const float* __restrict__ statS1, const float* __restrict__ statS2,
                                const float* __restrict__ msum, ush* __restrict__ Th,
                                ush* __restrict__ Tl, float* __restrict__ n2part) {
  __shared__ float smu[32], srs[32];
  const int b = blockIdx.z;
  const int n0 = blockIdx.x * 64;
  const int k0 = blockIdx.y * 32;
  const int tid = threadIdx.x;
  if (tid < 32) {
    const size_t base = ((size_t)b * CH + k0 + tid) * 8;
    float S1 = 0.f, S2 = 0.f;
    #pragma unroll
    for (int k = 0; k < 8; k++) { S1 += statS1[base + k]; S2 += statS2[base + k]; }
    const float M = msum[b];
    const float mu = S1 / M;
    const float q = fmaxf(S2 - mu * S1, 0.f);
    smu[tid] = mu;
    srs[tid] = 1.0f / sqrtf(q / M + 1e-4f);
  }
  __syncthreads();
  const int n = n0 + (tid >> 2);
  const int kl = (tid & 3) * 8;
  const int kc = k0 + kl;
  const float mn = mask[b * NN + n];
  const size_t zoff = ((size_t)b * NN + n) * CH + kc;
  const ushort4 h0 = *(const ushort4*)&Zsh[zoff];
  const ushort4 h1 = *(const ushort4*)&Zsh[zoff + 4];
  const ushort4 l0 = *(const ushort4*)&Zsl[zoff];
  const ushort4 l1 = *(const ushort4*)&Zsl[zoff + 4];
  float val[8];
  val[0] = (h2f(h0.x) + h2f(l0.x) - smu[kl + 0] * mn) * srs[kl + 0];
  val[1] = (h2f(h0.y) + h2f(l0.y) - smu[kl + 1] * mn) * srs[kl + 1];
  val[2] = (h2f(h0.z) + h2f(l0.z) - smu[kl + 2] * mn) * srs[kl + 2];
  val[3] = (h2f(h0.w) + h2f(l0.w) - smu[kl + 3] * mn) * srs[kl + 3];
  val[4] = (h2f(h1.x) + h2f(l1.x) - smu[kl + 4] * mn) * srs[kl + 4];
  val[5] = (h2f(h1.y) + h2f(l1.y) - smu[kl + 5] * mn) * srs[kl + 5];
  val[6] = (h2f(h1.z) + h2f(l1.z) - smu[kl + 6] * mn) * srs[kl + 6];
  val[7] = (h2f(h1.w) + h2f(l1.w) - smu[kl + 7] * mn) * srs[kl + 7];
  float s = 0.f;
  ush hv[8], lv[8];
  #pragma unroll
  for (int j = 0; j < 8; j++) {
    s += val[j] * val[j];
    hv[j] = f2h(val[j]);
    lv[j] = f2h(val[j] - h2f(hv[j]));
  }
  const size_t off = ((size_t)b * NN + n) * CH + kc;
  *(ushort4*)&Th[off] = *(ushort4*)&hv[0];
  *(ushort4*)&Th[off + 4] = *(ushort4*)&hv[4];
  *(ushort4*)&Tl[off] = *(ushort4*)&lv[0];
  *(ushort4*)&Tl[off + 4] = *(ushort4*)&lv[4];
  s += __shfl_xor(s, 1, 64);
  s += __shfl_xor(s, 2, 64);
  if ((tid & 3) == 0) n2part[((size_t)b * 8 + blockIdx.y) * NN + n] = s;
}

// ---------- gram v7: fp16 2-product asym, upper-tri tiles, fp16 D direct stores ----------
__global__ __launch_bounds__(256, 3)
void gram_v7_kernel(const ush* __restrict__ Yth, const ush* __restrict__ Ytl,
                    const float* __restrict__ n2part, const float* __restrict__ mask,
                    const float* __restrict__ posv, ush* __restrict__ Dp,
                    float* __restrict__ sigpart) {
  __shared__ ush lds[24576];           // 2 x 12288 dbuf (48 KB)
  __shared__ float sn2[256];
  __shared__ float spv[256];
  const int bid = blockIdx.x;
  const int logical = (bid & 7) * 72 + (bid >> 3);
  const int b = logical / 36;
  int t = logical - b * 36;
  int ty = 0;
  while (t >= 8 - ty) { t -= 8 - ty; ++ty; }
  const int tx = ty + t;
  const int i0 = ty * 128;
  const int j0 = tx * 128;
  {
    const int tt = threadIdx.x;
    const int nn = (tt < 128) ? (i0 + tt) : (j0 + tt - 128);
    const float pv = posv[b * NN + nn];
    float s = pv * pv;
    #pragma unroll
    for (int kb = 0; kb < 8; kb++) s += n2part[((size_t)b * 8 + kb) * NN + nn];
    sn2[tt] = s;
    spv[tt] = pv;
  }
  const ush* Ah = Yth + (size_t)b * NN * CH + (size_t)i0 * CH;
  const ush* Al = Ytl + (size_t)b * NN * CH + (size_t)i0 * CH;
  const ush* Bh = Yth + (size_t)b * NN * CH + (size_t)j0 * CH;
  f4 acc[4][4];
  const f4 z4 = {0.f, 0.f, 0.f, 0.f};
  #pragma unroll
  for (int mi = 0; mi < 4; mi++)
    #pragma unroll
    for (int ni = 0; ni < 4; ni++) acc[mi][ni] = z4;
  stageG(Ah, Al, Bh, CH, 0, lds);
  __syncthreads();
  int pb = 0;
  for (int kt = 32; kt < CH; kt += 32) {
    stageG(Ah, Al, Bh, CH, kt, lds + (pb ^ 1) * 12288);
    computeG(lds + pb * 12288, acc);
    __syncthreads();
    pb ^= 1;
  }
  computeG(lds + pb * 12288, acc);
  const int lane = threadIdx.x & 63;
  const int wid = threadIdx.x >> 6;
  const int wr = wid >> 1, wc = wid & 1;
  const int frow = lane & 15, hh = lane >> 4;
  const float scale = 3.0f / 257.0f;
  float lsum = 0.f;
  #pragma unroll
  for (int ni = 0; ni < 4; ni++) {
    const int jl = wc * 64 + ni * 16 + frow;
    const int j = j0 + jl;
    const float n2j = sn2[128 + jl];
    const float pj = spv[128 + jl];
    const float mkj = mask[b * NN + j];
    #pragma unroll
    for (int mi = 0; mi < 4; mi++) {
      const int il = wr * 64 + mi * 16 + hh * 4;
      ush dv[4];
      #pragma unroll
      for (int r = 0; r < 4; r++) {
        const int i = i0 + il + r;
        const float g = acc[mi][ni][r] + spv[il + r] * pj;
        const float D = scale * (sn2[il + r] + n2j - 2.0f * g);
        const float d = sqrtf(fmaxf(D, 1e-12f));
        const float mmv = mask[b * NN + i] * mkj;
        const float wd = d * mmv;
        lsum += wd * mmv;
        dv[r] = f2h(wd);
      }
      if (ty != tx) {
        uint2 mr;
        mr.x = (unsigned)dv[0] | ((unsigned)dv[1] << 16);
        mr.y = (unsigned)dv[2] | ((unsigned)dv[3] << 16);
        *(uint2*)&Dp[((size_t)b * NN + j) * NN + i0 + il] = mr;
      }
      #pragma unroll
      for (int r = 0; r < 4; r++) {
        const unsigned v = dv[r];
        const unsigned vp = (unsigned)__shfl_xor((int)v, 1, 64);
        if ((frow & 1) == 0)
          *(unsigned*)&Dp[((size_t)b * NN + i0 + il + r) * NN + j] = v | (vp << 16);
      }
    }
  }
  if (ty != tx) lsum *= 2.0f;
  #pragma unroll
  for (int off = 32; off > 0; off >>= 1) lsum += __shfl_down(lsum, off, 64);
  __syncthreads();
  float* rbuf = (float*)lds;
  if (lane == 0) rbuf[wid] = lsum;
  __syncthreads();
  if (threadIdx.x == 0)
    sigpart[(size_t)b * 64 + ty * 8 + tx] = rbuf[0] + rbuf[1] + rbuf[2] + rbuf[3];
}

// ---------- expw v4: sigma reduce inlined; read fp16 D, write W' fp16 plane ----------
__global__ void expw4_kernel(const ush* __restrict__ Dp, const float* __restrict__ mask,
                             const float* __restrict__ sigpart, const float* __restrict__ msum,
                             ush* __restrict__ Wp) {
  __shared__ float sfb;
  const int b = blockIdx.y, n = blockIdx.x;
  const int t = threadIdx.x;
  {
    float v = 0.f;
    if (t < 64) {
      const int sy = t >> 3, sx = t & 7;
      if (sy <= sx) v = sigpart[b * 64 + t];
    }
    v = blockReduceSum(v);
    if (t == 0) { const float ms = msum[b]; sfb = -10.0f * ms * ms / v; }
  }
  __syncthreads();
  const float fb = sfb;
  const float mn = mask[b * NN + n];
  const size_t roff = ((size_t)b * NN + n) * NN;
  const float4 mk = ((const float4*)(mask + b * NN))[t];
  const ushort4 dp = *(const ushort4*)&Dp[roff + t * 4];
  const float w0 = __expf(fb * h2f(dp.x)) * mn * mk.x;
  const float w1 = __expf(fb * h2f(dp.y)) * mn * mk.y;
  const float w2 = __expf(fb * h2f(dp.z)) * mn * mk.z;
  const float w3 = __expf(fb * h2f(dp.w)) * mn * mk.w;
  const float s = blockReduceSum(w0 + w1 + w2 + w3);
  float v0 = -w0, v1 = -w1, v2 = -w2, v3 = -w3;
  if ((n >> 2) == t) {
    const int r = n & 3;
    if (r == 0) v0 += s; else if (r == 1) v1 += s; else if (r == 2) v2 += s; else v3 += s;
  }
  ushort4 h4;
  h4.x = f2h(v0); h4.y = f2h(v1); h4.z = f2h(v2); h4.w = f2h(v3);
  *(ushort4*)&Wp[roff + t * 4] = h4;
}

// ---------- cvall v4 (fp16): C[g] = Kis[g]*(W[g]@X)*mask; direct fragment stores ----------
__global__ __launch_bounds__(256, 3)
void cvall_kernel(const ush* __restrict__ Ap, const ush* __restrict__ Bth,
                  const ush* __restrict__ Btl, const float* __restrict__ mask,
                  const float* __restrict__ Kis, unsigned int* __restrict__ Cpack,
                  ush* __restrict__ C2h, ush* __restrict__ C2l) {
  __shared__ ush lds[24576];
  const int bid = blockIdx.x;
  const int logical = (bid & 7) * 96 + (bid >> 3);
  const int b = logical / 48;
  const int inner = logical - b * 48;
  const int c0g = inner & 7;
  const int r0g = inner >> 3;
  const int r0 = r0g * 128;
  const int c0 = c0g * 128;
  const ush* Aq = Ap + (size_t)r0 * CH;
  const ush* Bh = Bth + (size_t)b * NN * CH + (size_t)c0 * CH;
  const ush* Bl = Btl + (size_t)b * NN * CH + (size_t)c0 * CH;
  f4 acc[4][4];
  const f4 z4 = {0.f, 0.f, 0.f, 0.f};
  #pragma unroll
  for (int mi = 0; mi < 4; mi++)
    #pragma unroll
    for (int ni = 0; ni < 4; ni++) acc[mi][ni] = z4;
  stageCV(Aq, CH, Bh, Bl, CH, 0, lds);
  __syncthreads();
  int pb = 0;
  for (int kt = 32; kt < CH; kt += 32) {
    stageCV(Aq, CH, Bh, Bl, CH, kt, lds + (pb ^ 1) * 12288);
    computeCV(lds + pb * 12288, acc);
    __syncthreads();
    pb ^= 1;
  }
  computeCV(lds + pb * 12288, acc);
  const int lane = threadIdx.x & 63;
  const int wid = threadIdx.x >> 6;
  const int wr = wid >> 1, wc = wid & 1;
  const int frow = lane & 15, hh = lane >> 4;
  const float alpha = Kis[r0g >> 1];
  #pragma unroll
  for (int ni = 0; ni < 4; ni++) {
    const int jl = wc * 64 + ni * 16 + frow;
    const int col = c0 + jl;
    const float am = alpha * mask[b * NN + col];
    #pragma unroll
    for (int mi = 0; mi < 4; mi++) {
      const int il = wr * 64 + mi * 16 + hh * 4;
      #pragma unroll
      for (int r = 0; r < 4; r++) {
        const int row = r0 + il + r;
        const float v = acc[mi][ni][r] * am;
        const ush h = f2h(v);
        const ush l = f2h(v - h2f(h));
        const unsigned pv = (unsigned)h | ((unsigned)l << 16);
        const unsigned pvp = (unsigned)__shfl_xor((int)pv, 1, 64);
        if ((frow & 1) == 0) {
          if (r0g < 4) {
            uint2 w2; w2.x = pv; w2.y = pvp;
            *(uint2*)&Cpack[((size_t)b * 512 + row) * NN + col] = w2;
          } else {
            const size_t obase = ((size_t)b * 256 + (row - 512)) * NN + col;
            const unsigned hw = (pv & 0xffffu) | (pvp << 16);
            const unsigned lw = (pv >> 16) | (pvp & 0xffff0000u);
            *(unsigned*)&C2h[obase] = hw;
            *(unsigned*)&C2l[obase] = lw;
          }
        }
      }
    }
  }
}

// ---------- mm1 v6 (fp16): out = X@W' + add(packed) ----------
// OUTMODE 0: row-major fp16 split out (+STATS on o)
// OUTMODE 2: outF = zin - 0.01*o (fp32) + transposed fp16 Z-splits [NN][CH] (+STATS on val)
template <int OUTMODE, int STATS>
__global__ __launch_bounds__(256, 5)
void mm1_v6_kernel(const ush* __restrict__ Xh, const ush* __restrict__ Xl, const size_t xStride,
                   const ush* __restrict__ Wp,
                   const unsigned int* __restrict__ addp, const size_t aStride,
                   const float* __restrict__ zin, const float* __restrict__ mask,
                   float* __restrict__ outF, ush* __restrict__ outH, ush* __restrict__ outL,
                   float* __restrict__ statS1, float* __restrict__ statS2) {
  __shared__ ush lds[16384];
  const int bid = blockIdx.x;
  const int logical = (bid & 7) * 64 + (bid >> 3);
  const int b = logical >> 5;
  const int inner = logical & 31;
  const int n0 = (inner & 7) * 128;
  const int r0 = (inner >> 3) * 64;
  const ush* Ah = Xh + (size_t)b * xStride + (size_t)r0 * NN;
  const ush* Al = Xl + (size_t)b * xStride + (size_t)r0 * NN;
  const ush* Bp = Wp + (size_t)b * NN * NN + (size_t)n0 * NN;
  f4 acc[4][2];
  const f4 z4 = {0.f, 0.f, 0.f, 0.f};
  #pragma unroll
  for (int mi = 0; mi < 4; mi++) { acc[mi][0] = z4; acc[mi][1] = z4; }
  stageMM(Ah, Al, NN, Bp, NN, 0, lds);
  __syncthreads();
  int pb = 0;
  for (int kt = 32; kt < NN; kt += 32) {
    stageMM(Ah, Al, NN, Bp, NN, kt, lds + (pb ^ 1) * 8192);
    computeMM(lds + pb * 8192, acc);
    __syncthreads();
    pb ^= 1;
  }
  computeMM(lds + pb * 8192, acc);
  const int lane = threadIdx.x & 63;
  const int wid = threadIdx.x >> 6;
  const int frow = lane & 15, hh = lane >> 4;
  float a1[4][4];
  float a2[4][4];
  if (STATS) {
    #pragma unroll
    for (int mi = 0; mi < 4; mi++)
      #pragma unroll
      for (int r = 0; r < 4; r++) { a1[mi][r] = 0.f; a2[mi][r] = 0.f; }
  }
  __syncthreads();
  unsigned int* tl = (unsigned int*)lds;   // [128][64] swizzled packed splits
  #pragma unroll
  for (int ni = 0; ni < 2; ni++) {
    const int jl = wid * 32 + ni * 16 + frow;
    const int col = n0 + jl;
    const float mk = STATS ? mask[b * NN + col] : 0.f;
    #pragma unroll
    for (int mi = 0; mi < 4; mi++) {
      const int il = mi * 16 + hh * 4;
      unsigned int pv[4];
      #pragma unroll
      for (int r = 0; r < 4; r++) {
        const int row = r0 + il + r;
        const unsigned int av = addp[(size_t)b * aStride + (size_t)row * NN + col];
        const float o = acc[mi][ni][r] + h2f((ush)(av & 0xffffu)) + h2f((ush)(av >> 16));
        float val;
        if (OUTMODE == 2) {
          const size_t ooff = (size_t)b * CH * NN + (size_t)row * NN + col;
          val = zin[ooff] - 0.01f * o;
          outF[ooff] = val;
        } else {
          val = o;
        }
        if (STATS) { a1[mi][r] += val * mk; a2[mi][r] += val * val * mk; }
        const ush h = f2h(val);
        const ush l = f2h(val - h2f(h));
        pv[r] = (unsigned int)h | ((unsigned int)l << 16);
      }
      const int slot = (il >> 2) ^ (jl & 15);
      *(uint4*)&tl[jl * 64 + slot * 4] = *(uint4*)pv;
    }
  }
  __syncthreads();
  if (OUTMODE == 0) {
    const int rrow = threadIdx.x >> 2;
    const int rch = (threadIdx.x & 3) * 32;
    const size_t obase = ((size_t)b * 256 + r0 + rrow) * NN + n0 + rch;
    #pragma unroll
    for (int g = 0; g < 4; g++) {
      unsigned int hw[4], lw[4];
      #pragma unroll
      for (int q = 0; q < 4; q++) {
        unsigned int h2[2], l2[2];
        #pragma unroll
        for (int e = 0; e < 2; e++) {
          const int jl = rch + g * 8 + q * 2 + e;
          const int slot = (rrow >> 2) ^ (jl & 15);
          const unsigned int v = tl[jl * 64 + slot * 4 + (rrow & 3)];
          h2[e] = v & 0xffffu; l2[e] = v >> 16;
        }
        hw[q] = h2[0] | (h2[1] << 16);
        lw[q] = l2[0] | (l2[1] << 16);
      }
      *(uint4*)&outH[obase + g * 8] = *(uint4*)hw;
      *(uint4*)&outL[obase + g * 8] = *(uint4*)lw;
    }
  } else {
    const int nloc = threadIdx.x >> 1;
    const int ch0 = (threadIdx.x & 1) * 32;
    #pragma unroll
    for (int half = 0; half < 2; half++) {
      unsigned int hw[8], lw[8];
      #pragma unroll
      for (int q = 0; q < 8; q++) {
        const int ila = ch0 + half * 16 + q * 2;
        const int ilb = ila + 1;
        const unsigned int va = tl[nloc * 64 + (((ila >> 2) ^ (nloc & 15)) << 2) + (ila & 3)];
        const unsigned int vb = tl[nloc * 64 + (((ilb >> 2) ^ (nloc & 15)) << 2) + (ilb & 3)];
        hw[q] = (va & 0xffffu) | (vb << 16);
        lw[q] = (va >> 16) | (vb & 0xffff0000u);
      }
      const size_t zoff = ((size_t)b * NN + n0 + nloc) * CH + r0 + ch0 + half * 16;
      *(uint4*)&outH[zoff] = *(uint4*)&hw[0];
      *(uint4*)&outH[zoff + 8] = *(uint4*)&hw[4];
      *(uint4*)&outL[zoff] = *(uint4*)&lw[0];
      *(uint4*)&outL[zoff + 8] = *(uint4*)&lw[4];
    }
  }
  if (STATS) {
    #pragma unroll
    for (int mi = 0; mi < 4; mi++)
      #pragma unroll
      for (int r = 0; r < 4; r++) {
        #pragma unroll
        for (int d = 1; d < 16; d <<= 1) {
          a1[mi][r] += __shfl_xor(a1[mi][r], d, 64);
          a2[mi][r] += __shfl_xor(a2[mi][r], d, 64);
        }
      }
    __syncthreads();
    float* s1b = (float*)lds;
    float* s2b = s1b + 256;
    if (frow == 0) {
      #pragma unroll
      for (int mi = 0; mi < 4; mi++)
        #pragma unroll
        for (int r = 0; r < 4; r++) {
          const int row = mi * 16 + hh * 4 + r;
          s1b[wid * 64 + row] = a1[mi][r];
          s2b[wid * 64 + row] = a2[mi][r];
        }
    }
    __syncthreads();
    if (threadIdx.x < 64) {
      const int row = threadIdx.x;
      const float p1 = s1b[row] + s1b[64 + row] + s1b[128 + row] + s1b[192 + row];
      const float p2 = s2b[row] + s2b[64 + row] + s2b[128 + row] + s2b[192 + row];
      const int nblk = n0 >> 7;
      statS1[((size_t)b * CH + r0 + row) * 8 + nblk] = p1;
      statS2[((size_t)b * CH + r0 + row) * 8 + nblk] = p2;
    }
  }
}

// ---------- csq: partial col sums of ((U-rmean)*mask)^2; rmean inlined ----------
__global__ void csq_kernel(const ush* __restrict__ Uh, const ush* __restrict__ Ul,
                           const float* __restrict__ mask, const float* __restrict__ statS1,
                           const float* __restrict__ msum, float* __restrict__ part) {
  __shared__ float srm[16];
  const int b = blockIdx.y, cc = blockIdx.x;
  if (threadIdx.x < 16) {
    const size_t base = ((size_t)b * CH + cc * 16 + threadIdx.x) * 8;
    float S1 = 0.f;
    #pragma unroll
    for (int k = 0; k < 8; k++) S1 += statS1[base + k];
    srm[threadIdx.x] = S1 / msum[b];
  }
  __syncthreads();
  const int n = threadIdx.x * 4;
  const float4 m4 = *(const float4*)&mask[b * NN + n];
  float4 s4 = {0.f, 0.f, 0.f, 0.f};
  for (int r = 0; r < 16; r++) {
    const int c = cc * 16 + r;
    const float rm = srm[r];
    const size_t uoff = ((size_t)b * 256 + c) * NN + n;
    const ushort4 uh = *(const ushort4*)&Uh[uoff];
    const ushort4 ul = *(const ushort4*)&Ul[uoff];
    float a;
    a = (h2f(uh.x) + h2f(ul.x) - rm) * m4.x; s4.x += a * a;
    a = (h2f(uh.y) + h2f(ul.y) - rm) * m4.y; s4.y += a * a;
    a = (h2f(uh.z) + h2f(ul.z) - rm) * m4.z; s4.z += a * a;
    a = (h2f(uh.w) + h2f(ul.w) - rm) * m4.w; s4.w += a * a;
  }
  *(float4*)&part[((size_t)(b * 16 + cc)) * NN + n] = s4;
}

// ---------- tsplitN2: A=relu((U-rmean)*mask*rs); rmean+rs inlined ----------
__global__ void tsplitN2_kernel(const ush* __restrict__ Uh, const ush* __restrict__ Ul,
                                const float* __restrict__ mask, const float* __restrict__ statS1,
                                const float* __restrict__ msum, const float* __restrict__ part,
                                ush* __restrict__ Th, ush* __restrict__ Tl) {
  __shared__ float t[32][65];
  __shared__ float srm[32];
  __shared__ float srsl[64];
  const int b = blockIdx.z;
  const int n0 = blockIdx.x * 64;
  const int k0 = blockIdx.y * 32;
  const int tid = threadIdx.x;
  if (tid < 32) {
    const size_t base = ((size_t)b * CH + k0 + tid) * 8;
    float S1 = 0.f;
    #pragma unroll
    for (int k = 0; k < 8; k++) S1 += statS1[base + k];
    srm[tid] = S1 / msum[b];
  } else if (tid < 96) {
    const int n = n0 + tid - 32;
    float s = 0.001f;
    #pragma unroll
    for (int cc = 0; cc < 16; cc++) s += part[((size_t)(b * 16 + cc)) * NN + n];
    srsl[tid - 32] = 1.0f / sqrtf(s);
  }
  __syncthreads();
  const int lr = tid >> 3;
  const int lc = (tid & 7) * 8;
  const int gc = k0 + lr;
  const float rm = srm[lr];
  const float4 ma = *(const float4*)&mask[b * NN + n0 + lc];
  const float4 mb = *(const float4*)&mask[b * NN + n0 + lc + 4];
  const size_t uoff = ((size_t)b * 256 + gc) * NN + n0 + lc;
  const ushort4 ha = *(const ushort4*)&Uh[uoff];
  const ushort4 hb = *(const ushort4*)&Uh[uoff + 4];
  const ushort4 la = *(const ushort4*)&Ul[uoff];
  const ushort4 lb = *(const ushort4*)&Ul[uoff + 4];
  t[lr][lc + 0] = fmaxf((h2f(ha.x) + h2f(la.x) - rm) * ma.x * srsl[lc + 0], 0.f);
  t[lr][lc + 1] = fmaxf((h2f(ha.y) + h2f(la.y) - rm) * ma.y * srsl[lc + 1], 0.f);
  t[lr][lc + 2] = fmaxf((h2f(ha.z) + h2f(la.z) - rm) * ma.z * srsl[lc + 2], 0.f);
  t[lr][lc + 3] = fmaxf((h2f(ha.w) + h2f(la.w) - rm) * ma.w * srsl[lc + 3], 0.f);
  t[lr][lc + 4] = fmaxf((h2f(hb.x) + h2f(lb.x) - rm) * mb.x * srsl[lc + 4], 0.f);
  t[lr][lc + 5] = fmaxf((h2f(hb.y) + h2f(lb.y) - rm) * mb.y * srsl[lc + 5], 0.f);
  t[lr][lc + 6] = fmaxf((h2f(hb.z) + h2f(lb.z) - rm) * mb.z * srsl[lc + 6], 0.f);
  t[lr][lc + 7] = fmaxf((h2f(hb.w) + h2f(lb.w) - rm) * mb.w * srsl[lc + 7], 0.f);
  __syncthreads();
  const int on = tid >> 2;
  const int ok = (tid & 3) * 8;
  ush hv[8], lv[8];
  #pragma unroll
  for (int j = 0; j < 8; j++) {
    const float v = t[ok + j][on];
    hv[j] = f2h(v); lv[j] = f2h(v - h2f(hv[j]));
  }
  const size_t off = ((size_t)b * NN + n0 + on) * CH + k0 + ok;
  *(ushort4*)&Th[off] = *(ushort4*)&hv[0];
  *(ushort4*)&Th[off + 4] = *(ushort4*)&hv[4];
  *(ushort4*)&Tl[off] = *(ushort4*)&lv[0];
  *(ushort4*)&Tl[off + 4] = *(ushort4*)&lv[4];
}

// ---------- Zout = (Wend @ Z)*mask; write + centered copy ----------
__global__ void zout_kernel(const float* __restrict__ Z, const float* __restrict__ Wend,
                            const float* __restrict__ mask, float* __restrict__ outZ,
                            float* __restrict__ Zcent) {
  const int b = blockIdx.x;
  __shared__ float w[3 * CH];
  for (int i = threadIdx.x; i < 3 * CH; i += 256) w[i] = Wend[i];
  __syncthreads();
  float a[3][4];
  #pragma unroll
  for (int j = 0; j < 4; j++) { a[0][j] = 0.f; a[1][j] = 0.f; a[2][j] = 0.f; }
  const float* Zb = Z + (size_t)b * CH * NN;
  for (int c = 0; c < CH; c++) {
    const float w0 = w[c], w1 = w[CH + c], w2 = w[2 * CH + c];
    #pragma unroll
    for (int j = 0; j < 4; j++) {
      float zv = Zb[(size_t)c * NN + threadIdx.x + j * 256];
      a[0][j] += w0 * zv; a[1][j] += w1 * zv; a[2][j] += w2 * zv;
    }
  }
  float sum[3] = {0.f, 0.f, 0.f};
  #pragma unroll
  for (int j = 0; j < 4; j++) {
    const int n = threadIdx.x + j * 256;
    const float mv = mask[b * NN + n];
    #pragma unroll
    for (int o = 0; o < 3; o++) {
      a[o][j] *= mv;
      outZ[((size_t)b * 3 + o) * NN + n] = a[o][j];
      sum[o] += a[o][j];
    }
  }
  for (int o = 0; o < 3; o++) {
    float s = blockReduceSum(sum[o]);
    const float mean = s * (1.0f / NN);
    #pragma unroll
    for (int j = 0; j < 4; j++) {
      const int n = threadIdx.x + j * 256;
      Zcent[((size_t)b * 3 + o) * NN + n] = a[o][j] - mean;
    }
  }
}

// ---------- final distances ----------
__global__ void dist_kernel(const float* __restrict__ Zcent, float* __restrict__ outD) {
  const int b = blockIdx.z;
  const int n = blockIdx.y;
  const int m = blockIdx.x * 256 + threadIdx.x;
  const float* Zb = Zcent + (size_t)b * 3 * NN;
  const float x0 = Zb[n], x1 = Zb[NN + n], x2 = Zb[2 * NN + n];
  const float d0 = x0 - Zb[m], d1 = x1 - Zb[NN + m], d2 = x2 - Zb[2 * NN + m];
  const float D = d0 * d0 + d1 * d1 + d2 * d2;
  outD[((size_t)b * NN + n) * NN + m] = sqrtf(fmaxf(D, 1e-12f));
}

extern "C" void kernel_launch(void* const* d_in, const int* in_sizes, int n_in,
                              void* d_out, int out_size, void* d_ws, size_t ws_size,
                              hipStream_t stream) {
  const float* Zin  = (const float*)d_in[0];
  const float* mask = (const float*)d_in[1];
  const float* K0   = (const float*)d_in[2];
  const float* Knet = (const float*)d_in[3];
  const float* W    = (const float*)d_in[4];
  const float* Wend = (const float*)d_in[5];
  float* out = (float*)d_out;

  // d_out dist region (64 MB): Wp fp16 (32 MB) | Dp fp16 (32 MB)
  ush* Wp = (ush*)out;
  ush* Dp = Wp + (size_t)BB * NN * NN;
  float* outZ = out + (size_t)BB * NN * NN;

  float* p = (float*)d_ws;
  // union: gram phase {Yth | Ytl fp16 [NN][CH]}; GEMM phase {Cpack u32 | C2h | C2l fp16}
  float* uni = p; p += (size_t)BB * 768 * NN;     // 50.33 MB
  ush* Yth = (ush*)uni;
  ush* Ytl = Yth + (size_t)BB * NN * CH;
  unsigned int* Cpack = (unsigned int*)uni;
  ush* C2h = (ush*)(uni + (size_t)BB * 512 * NN);
  ush* C2l = C2h + (size_t)BB * 256 * NN;

  float* Zcur = p; p += (size_t)BB * CH * NN;
  ush* Thb = (ush*)p; p += (size_t)BB * NN * CH / 2;   // T / A-splits (shared)
  ush* Tlb = (ush*)p; p += (size_t)BB * NN * CH / 2;
  ush* Zsh = (ush*)p; p += (size_t)BB * NN * CH / 2;   // Z transposed fp16 splits
  ush* Zsl = (ush*)p; p += (size_t)BB * NN * CH / 2;
  ush* Wm = (ush*)p; p += (size_t)18 * CH * CH / 2;
  ush* Wt = (ush*)p; p += (size_t)18 * CH * CH / 2;
  float* msum  = p; p += BB;
  float* posv  = p; p += BB * NN;
  float* sigp  = p; p += BB * 64;
  float* statS1= p; p += (size_t)BB * CH * 8;
  float* statS2= p; p += (size_t)BB * CH * 8;
  float* n2part= p; p += (size_t)BB * 8 * NN;
  float* partb = p; p += (size_t)BB * 16 * NN;
  float* Zcent = p; p += BB * 3 * NN;

  const dim3 gtsZ(NN / 64, CH / 32, BB);
  const size_t sC = (size_t)512 * NN;
  const size_t sT = (size_t)CH * NN;

  masksum_kernel<<<BB, 256, 0, stream>>>(mask, msum, posv);
  wprep_kernel<<<dim3(16, 18), 256, 0, stream>>>(W, Wm, Wt);
  k0_kernel<<<dim3(CH / 8, BB), 256, 0, stream>>>(Zin, K0, mask, Zcur, statS1, statS2);
  tsplitZ_kernel<<<gtsZ, 256, 0, stream>>>(Zcur, Zsh, Zsl);

  for (int layer = 0; layer < NLAYERS; layer++) {
    tsplitY2_kernel<<<gtsZ, 256, 0, stream>>>(Zsh, Zsl, mask, statS1, statS2, msum,
                                              Yth, Ytl, n2part);
    gram_v7_kernel<<<576, 256, 0, stream>>>(Yth, Ytl, n2part, mask, posv, Dp, sigp);
    expw4_kernel<<<dim3(NN, BB), 256, 0, stream>>>(Dp, mask, sigp, msum, Wp);

    const ush* Am = Wm + (size_t)layer * 3 * CH * CH;
    const ush* At = Wt + (size_t)layer * 3 * CH * CH;
    const float* Ki = Knet + layer * 3;

    // ---- Ai = C0 + (C1 + C2@L)@L, C = Ki*(Wi@Z)*mask, L rows = W' ----
    cvall_kernel<<<768, 256, 0, stream>>>(Am, Zsh, Zsl, mask, Ki, Cpack, C2h, C2l);
    mm1_v6_kernel<0, 0><<<512, 256, 0, stream>>>(C2h, C2l, sT, Wp,
        Cpack + (size_t)256 * NN, sC, nullptr, nullptr, nullptr, Thb, Tlb, nullptr, nullptr);
    mm1_v6_kernel<0, 1><<<512, 256, 0, stream>>>(Thb, Tlb, sT, Wp,
        Cpack, sC, nullptr, mask, nullptr, C2h, C2l, statS1, statS2);

    csq_kernel<<<dim3(16, BB), 256, 0, stream>>>(C2h, C2l, mask, statS1, msum, partb);
    tsplitN2_kernel<<<gtsZ, 256, 0, stream>>>(C2h, C2l, mask, statS1, msum, partb, Thb, Tlb);

    // ---- Z -= 0.01 * (C0 + (C1 + C2@L)@L), C = Ki*(Wi^T@A)*mask ----
    cvall_kernel<<<768, 256, 0, stream>>>(At, Thb, Tlb, mask, Ki, Cpack, C2h, C2l);
    mm1_v6_kernel<0, 0><<<512, 256, 0, stream>>>(C2h, C2l, sT, Wp,
        Cpack + (size_t)256 * NN, sC, nullptr, nullptr, nullptr, Thb, Tlb, nullptr, nullptr);
    mm1_v6_kernel<2, 1><<<512, 256, 0, stream>>>(Thb, Tlb, sT, Wp,
        Cpack, sC, Zcur, mask, Zcur, Zsh, Zsl, statS1, statS2);
  }

  zout_kernel<<<BB, 256, 0, stream>>>(Zcur, Wend, mask, outZ, Zcent);
  dist_kernel<<<dim3(NN / 256, NN, BB), 256, 0, stream>>>(Zcent, out);
}

// Round 16
// 1666.226 us; speedup vs baseline: 1.1131x; 1.0559x over previous
//
#include <hip/hip_runtime.h>
#include <hip/hip_fp16.h>
#include <math.h>

#define BB 16
#define CIN 40
#define CH 256
#define NN 1024
#define NLAYERS 6

typedef unsigned short ush;
typedef __attribute__((ext_vector_type(8))) _Float16 h8;
typedef __attribute__((ext_vector_type(4))) float f4;

__device__ __forceinline__ ush f2h(float x) {
  __half h = __float2half(x);
  return *(ush*)&h;
}
__device__ __forceinline__ float h2f(ush u) {
  __half h = *(__half*)&u;
  return __half2float(h);
}
__device__ __forceinline__ float fast_tanh(float x) {
  const float e = __expf(2.0f * x);
  return (e - 1.0f) / (e + 1.0f);
}

#define GLD16(gp, lp) __builtin_amdgcn_global_load_lds( \
    (const __attribute__((address_space(1))) void*)(gp), \
    (__attribute__((address_space(3))) void*)(lp), 16, 0, 0)

// ---------- block reduction (256 threads = 4 waves) ----------
__device__ __forceinline__ float blockReduceSum(float v) {
  __shared__ float sred[4];
  const int lane = threadIdx.x & 63;
  const int wid  = threadIdx.x >> 6;
  #pragma unroll
  for (int off = 32; off > 0; off >>= 1) v += __shfl_down(v, off, 64);
  __syncthreads();
  if (lane == 0) sred[wid] = v;
  __syncthreads();
  return sred[0] + sred[1] + sred[2] + sred[3];
}

// ================= gram core (fp16, asym 2-product): A pair + B hi plane, 128x128 ==========
__device__ __forceinline__ void stageG(
    const ush* __restrict__ Ah, const ush* __restrict__ Al,
    const ush* __restrict__ Bh, const int s, const int kt, ush* buf) {
  const int lane = threadIdx.x & 63;
  const int wid = threadIdx.x >> 6;
  const int srow = lane >> 2;
  const int sl = (lane & 3) ^ ((srow >> 1) & 3);
  #pragma unroll
  for (int cc = 0; cc < 6; cc++) {
    const int c = wid * 6 + cc;
    const ush* src;
    if (c < 8)       src = Ah + (size_t)(c * 16 + srow) * s + kt + sl * 8;
    else if (c < 16) src = Al + (size_t)((c - 8) * 16 + srow) * s + kt + sl * 8;
    else             src = Bh + (size_t)((c - 16) * 16 + srow) * s + kt + sl * 8;
    GLD16(src, buf + c * 512 + lane * 8);
  }
}

__device__ __forceinline__ void computeG(const ush* buf, f4 acc[4][4]) {
  const int lane = threadIdx.x & 63;
  const int wid = threadIdx.x >> 6;
  const int wr = wid >> 1, wc = wid & 1;
  const int frow = lane & 15;
  const int slot8 = (((lane >> 4) ^ ((frow >> 1) & 3)) << 3);
  h8 ah[4], al[4], b_[4];
  #pragma unroll
  for (int mi = 0; mi < 4; mi++) {
    const int off = (wr * 64 + mi * 16 + frow) * 32 + slot8;
    ah[mi] = *(const h8*)&buf[off];
    al[mi] = *(const h8*)&buf[4096 + off];
  }
  #pragma unroll
  for (int ni = 0; ni < 4; ni++) {
    const int off = (wc * 64 + ni * 16 + frow) * 32 + slot8;
    b_[ni] = *(const h8*)&buf[8192 + off];
  }
  #pragma unroll
  for (int mi = 0; mi < 4; mi++)
    #pragma unroll
    for (int ni = 0; ni < 4; ni++) {
      acc[mi][ni] = __builtin_amdgcn_mfma_f32_16x16x32_f16(ah[mi], b_[ni], acc[mi][ni], 0, 0, 0);
      acc[mi][ni] = __builtin_amdgcn_mfma_f32_16x16x32_f16(al[mi], b_[ni], acc[mi][ni], 0, 0, 0);
    }
}

// ================= cvall core (fp16): A 1 plane + B 2 planes, 128x128, 2 products ==========
__device__ __forceinline__ void stageCV(
    const ush* __restrict__ Ap, const int sA,
    const ush* __restrict__ Bh, const ush* __restrict__ Bl, const int sB,
    const int kt, ush* buf) {
  const int lane = threadIdx.x & 63;
  const int wid = threadIdx.x >> 6;
  const int srow = lane >> 2;
  const int sl = (lane & 3) ^ ((srow >> 1) & 3);
  #pragma unroll
  for (int cc = 0; cc < 6; cc++) {
    const int c = wid * 6 + cc;
    const ush* src;
    if (c < 8)       src = Ap + (size_t)(c * 16 + srow) * sA + kt + sl * 8;
    else if (c < 16) src = Bh + (size_t)((c - 8) * 16 + srow) * sB + kt + sl * 8;
    else             src = Bl + (size_t)((c - 16) * 16 + srow) * sB + kt + sl * 8;
    GLD16(src, buf + c * 512 + lane * 8);
  }
}

__device__ __forceinline__ void computeCV(const ush* buf, f4 acc[4][4]) {
  const int lane = threadIdx.x & 63;
  const int wid = threadIdx.x >> 6;
  const int wr = wid >> 1, wc = wid & 1;
  const int frow = lane & 15;
  const int slot8 = (((lane >> 4) ^ ((frow >> 1) & 3)) << 3);
  h8 a_[4], bh_[4], bl_[4];
  #pragma unroll
  for (int mi = 0; mi < 4; mi++) {
    const int off = (wr * 64 + mi * 16 + frow) * 32 + slot8;
    a_[mi] = *(const h8*)&buf[off];
  }
  #pragma unroll
  for (int ni = 0; ni < 4; ni++) {
    const int off = (wc * 64 + ni * 16 + frow) * 32 + slot8;
    bh_[ni] = *(const h8*)&buf[4096 + off];
    bl_[ni] = *(const h8*)&buf[8192 + off];
  }
  #pragma unroll
  for (int mi = 0; mi < 4; mi++)
    #pragma unroll
    for (int ni = 0; ni < 4; ni++) {
      acc[mi][ni] = __builtin_amdgcn_mfma_f32_16x16x32_f16(a_[mi], bh_[ni], acc[mi][ni], 0, 0, 0);
      acc[mi][ni] = __builtin_amdgcn_mfma_f32_16x16x32_f16(a_[mi], bl_[ni], acc[mi][ni], 0, 0, 0);
    }
}

// ================= mm1 core (fp16): A 2 planes + B 1 plane, 64x128, 2 products =============
__device__ __forceinline__ void stageMM(
    const ush* __restrict__ Ah, const ush* __restrict__ Al, const int sA,
    const ush* __restrict__ Bp, const int sB, const int kt, ush* buf) {
  const int lane = threadIdx.x & 63;
  const int wid = threadIdx.x >> 6;
  const int srow = lane >> 2;
  const int sl = (lane & 3) ^ ((srow >> 1) & 3);
  #pragma unroll
  for (int cc = 0; cc < 4; cc++) {
    const int c = wid * 4 + cc;
    const ush* src;
    if (c < 4)       src = Ah + (size_t)(c * 16 + srow) * sA + kt + sl * 8;
    else if (c < 8)  src = Al + (size_t)((c - 4) * 16 + srow) * sA + kt + sl * 8;
    else             src = Bp + (size_t)((c - 8) * 16 + srow) * sB + kt + sl * 8;
    GLD16(src, buf + c * 512 + lane * 8);
  }
}

__device__ __forceinline__ void computeMM(const ush* buf, f4 acc[4][2]) {
  const int lane = threadIdx.x & 63;
  const int wid = threadIdx.x >> 6;
  const int frow = lane & 15;
  const int slot8 = (((lane >> 4) ^ ((frow >> 1) & 3)) << 3);
  h8 ah[4], al[4], b_[2];
  #pragma unroll
  for (int mi = 0; mi < 4; mi++) {
    const int off = (mi * 16 + frow) * 32 + slot8;
    ah[mi] = *(const h8*)&buf[off];
    al[mi] = *(const h8*)&buf[2048 + off];
  }
  #pragma unroll
  for (int ni = 0; ni < 2; ni++) {
    const int off = (wid * 32 + ni * 16 + frow) * 32 + slot8;
    b_[ni] = *(const h8*)&buf[4096 + off];
  }
  #pragma unroll
  for (int mi = 0; mi < 4; mi++)
    #pragma unroll
    for (int ni = 0; ni < 2; ni++) {
      acc[mi][ni] = __builtin_amdgcn_mfma_f32_16x16x32_f16(ah[mi], b_[ni], acc[mi][ni], 0, 0, 0);
      acc[mi][ni] = __builtin_amdgcn_mfma_f32_16x16x32_f16(al[mi], b_[ni], acc[mi][ni], 0, 0, 0);
    }
}

// ---------- Z0 = tanh(K0 @ Zin) * mask, 8 outputs/block, LDS-staged Zin (no spill) ---------
__global__ __launch_bounds__(256, 2)
void k0_kernel(const float* __restrict__ Zin, const float* __restrict__ K0,
               const float* __restrict__ mask, float* __restrict__ Zc,
               float* __restrict__ statS1, float* __restrict__ statS2) {
  const int b = blockIdx.y;
  const int o0 = blockIdx.x * 8;
  __shared__ float w[8][CIN];
  __shared__ float zt[CIN][257];
  __shared__ float sred1[4][8];
  __shared__ float sred2[4][8];
  const int tid = threadIdx.x;
  for (int i = tid; i < 8 * CIN; i += 256)
    w[i / CIN][i % CIN] = K0[(o0 + i / CIN) * CIN + i % CIN];
  float s1[8], s2[8];
  #pragma unroll
  for (int o = 0; o < 8; o++) { s1[o] = 0.f; s2[o] = 0.f; }
  for (int step = 0; step < 4; step++) {
    const int nb = step * 256;
    __syncthreads();   // protects zt from previous step's reads (and covers w on step 0)
    for (int c = 0; c < CIN; c++)
      zt[c][tid] = Zin[((size_t)b * CIN + c) * NN + nb + tid];
    __syncthreads();
    const int n = nb + tid;
    const float mn = mask[b * NN + n];
    float acc[8];
    #pragma unroll
    for (int o = 0; o < 8; o++) acc[o] = 0.f;
    for (int c = 0; c < CIN; c++) {
      const float zv = zt[c][tid];
      #pragma unroll
      for (int o = 0; o < 8; o++) acc[o] += w[o][c] * zv;
    }
    #pragma unroll
    for (int o = 0; o < 8; o++) {
      const float z = fast_tanh(acc[o]) * mn;
      Zc[((size_t)b * CH + o0 + o) * NN + n] = z;
      s1[o] += z; s2[o] += z * z;
    }
  }
  const int lane = tid & 63;
  const int wid = tid >> 6;
  #pragma unroll
  for (int o = 0; o < 8; o++) {
    float r1 = s1[o], r2 = s2[o];
    #pragma unroll
    for (int off = 32; off > 0; off >>= 1) {
      r1 += __shfl_down(r1, off, 64);
      r2 += __shfl_down(r2, off, 64);
    }
    if (lane == 0) { sred1[wid][o] = r1; sred2[wid][o] = r2; }
  }
  __syncthreads();
  if (tid < 8) {
    const int o = tid;
    const float r1 = sred1[0][o] + sred1[1][o] + sred1[2][o] + sred1[3][o];
    const float r2 = sred2[0][o] + sred2[1][o] + sred2[2][o] + sred2[3][o];
    const size_t base = ((size_t)b * CH + o0 + o) * 8;
    statS1[base] = r1; statS2[base] = r2;
    #pragma unroll
    for (int k = 1; k < 8; k++) { statS1[base + k] = 0.f; statS2[base + k] = 0.f; }
  }
}

// ---------- masksum + centered pos-row values ----------
__global__ void masksum_kernel(const float* __restrict__ mask, float* __restrict__ msum,
                               float* __restrict__ posv) {
  const int b = blockIdx.x;
  float v = 0.f, p = 0.f;
  for (int n = threadIdx.x; n < NN; n += 256) {
    const float m = mask[b * NN + n];
    v += m;
    p += 0.5f * ((float)n * (1.0f / (NN - 1))) * m;
  }
  v = blockReduceSum(v);
  p = blockReduceSum(p);
  const float pm = p * (1.0f / NN);
  if (threadIdx.x == 0) msum[b] = v;
  for (int n = threadIdx.x; n < NN; n += 256)
    posv[b * NN + n] = 0.5f * ((float)n * (1.0f / (NN - 1))) * mask[b * NN + n] - pm;
}

// ---------- W prep: fp16 single plane of W and W^T for all 18 matrices ----------
__global__ void wprep_kernel(const float* __restrict__ W, ush* __restrict__ Wm,
                             ush* __restrict__ Wt) {
  __shared__ float t[64][65];
  const int mat = blockIdx.y;
  const int ty = blockIdx.x >> 2, tx = blockIdx.x & 3;
  const float* src = W + (size_t)mat * CH * CH;
  const int tid = threadIdx.x;
  const int lr = tid >> 2;
  const int lc = (tid & 3) * 16;
  float v[16];
  #pragma unroll
  for (int j = 0; j < 16; j += 4)
    *(float4*)&v[j] = *(const float4*)&src[(size_t)(ty * 64 + lr) * CH + tx * 64 + lc + j];
  ush hv[16];
  #pragma unroll
  for (int j = 0; j < 16; j++) {
    hv[j] = f2h(v[j]);
    t[lr][lc + j] = v[j];
  }
  const size_t offm = (size_t)mat * CH * CH + (size_t)(ty * 64 + lr) * CH + tx * 64 + lc;
  #pragma unroll
  for (int j = 0; j < 16; j += 4)
    *(ushort4*)&Wm[offm + j] = *(ushort4*)&hv[j];
  __syncthreads();
  #pragma unroll
  for (int j = 0; j < 16; j++) hv[j] = f2h(t[lc + j][lr]);
  const size_t offt = (size_t)mat * CH * CH + (size_t)(tx * 64 + lr) * CH + ty * 64 + lc;
  #pragma unroll
  for (int j = 0; j < 16; j += 4)
    *(ushort4*)&Wt[offt + j] = *(ushort4*)&hv[j];
}

// ---------- transpose+split: Zcur fp32 [CH][NN] -> fp16 splits [NN][CH] (pre-loop) ----------
__global__ void tsplitZ_kernel(const float* __restrict__ in, ush* __restrict__ Th,
                               ush* __restrict__ Tl) {
  __shared__ float t[32][65];
  const int b = blockIdx.z;
  const int n0 = blockIdx.x * 64;
  const int k0 = blockIdx.y * 32;
  const float* src = in + (size_t)b * CH * NN;
  const int tid = threadIdx.x;
  const int lr = tid >> 3;
  const int lc = (tid & 7) * 8;
  const int gk = k0 + lr;
  *(float4*)&t[lr][lc]     = *(const float4*)&src[(size_t)gk * NN + n0 + lc];
  *(float4*)&t[lr][lc + 4] = *(const float4*)&src[(size_t)gk * NN + n0 + lc + 4];
  __syncthreads();
  const int on = tid >> 2;
  const int ok = (tid & 3) * 8;
  ush hv[8], lv[8];
  #pragma unroll
  for (int j = 0; j < 8; j++) {
    const float v = t[ok + j][on];
    hv[j] = f2h(v); lv[j] = f2h(v - h2f(hv[j]));
  }
  const size_t off = ((size_t)b * NN + n0 + on) * CH + k0 + ok;
  *(ushort4*)&Th[off] = *(ushort4*)&hv[0];
  *(ushort4*)&Th[off + 4] = *(ushort4*)&hv[4];
  *(ushort4*)&Tl[off] = *(ushort4*)&lv[0];
  *(ushort4*)&Tl[off + 4] = *(ushort4*)&lv[4];
}

// ---------- tsplitY2: Z splits -> normalized Y fp16 splits + n2 partials (stats inlined) ----
__global__ void tsplitY2_kernel(const ush* __restrict__ Zsh, const ush* __restrict__ Zsl,
                                const float* __restrict__ mask,
                                const float* __restrict__ statS1, const float* __restrict__ statS2,
                                const float* __restrict__ msum, ush* __restrict__ Th,
                                ush* __restrict__ Tl, float* __restrict__ n2part) {
  __shared__ float smu[32], srs[32];
  const int b = blockIdx.z;
  const int n0 = blockIdx.x * 64;
  const int k0 = blockIdx.y * 32;
  const int tid = threadIdx.x;
  if (tid < 32) {
    const size_t base = ((size_t)b * CH + k0 + tid) * 8;
    float S1 = 0.f, S2 = 0.f;
    #pragma unroll
    for (int k = 0; k < 8; k++) { S1 += statS1[base + k]; S2 += statS2[base + k]; }
    const float M = msum[b];
    const float mu = S1 / M;
    const float q = fmaxf(S2 - mu * S1, 0.f);
    smu[tid] = mu;
    srs[tid] = 1.0f / sqrtf(q / M + 1e-4f);
  }
  __syncthreads();
  const int n = n0 + (tid >> 2);
  const int kl = (tid & 3) * 8;
  const int kc = k0 + kl;
  const float mn = mask[b * NN + n];
  const size_t zoff = ((size_t)b * NN + n) * CH + kc;
  const ushort4 h0 = *(const ushort4*)&Zsh[zoff];
  const ushort4 h1 = *(const ushort4*)&Zsh[zoff + 4];
  const ushort4 l0 = *(const ushort4*)&Zsl[zoff];
  const ushort4 l1 = *(const ushort4*)&Zsl[zoff + 4];
  float val[8];
  val[0] = (h2f(h0.x) + h2f(l0.x) - smu[kl + 0] * mn) * srs[kl + 0];
  val[1] = (h2f(h0.y) + h2f(l0.y) - smu[kl + 1] * mn) * srs[kl + 1];
  val[2] = (h2f(h0.z) + h2f(l0.z) - smu[kl + 2] * mn) * srs[kl + 2];
  val[3] = (h2f(h0.w) + h2f(l0.w) - smu[kl + 3] * mn) * srs[kl + 3];
  val[4] = (h2f(h1.x) + h2f(l1.x) - smu[kl + 4] * mn) * srs[kl + 4];
  val[5] = (h2f(h1.y) + h2f(l1.y) - smu[kl + 5] * mn) * srs[kl + 5];
  val[6] = (h2f(h1.z) + h2f(l1.z) - smu[kl + 6] * mn) * srs[kl + 6];
  val[7] = (h2f(h1.w) + h2f(l1.w) - smu[kl + 7] * mn) * srs[kl + 7];
  float s = 0.f;
  ush hv[8], lv[8];
  #pragma unroll
  for (int j = 0; j < 8; j++) {
    s += val[j] * val[j];
    hv[j] = f2h(val[j]);
    lv[j] = f2h(val[j] - h2f(hv[j]));
  }
  const size_t off = ((size_t)b * NN + n) * CH + kc;
  *(ushort4*)&Th[off] = *(ushort4*)&hv[0];
  *(ushort4*)&Th[off + 4] = *(ushort4*)&hv[4];
  *(ushort4*)&Tl[off] = *(ushort4*)&lv[0];
  *(ushort4*)&Tl[off + 4] = *(ushort4*)&lv[4];
  s += __shfl_xor(s, 1, 64);
  s += __shfl_xor(s, 2, 64);
  if ((tid & 3) == 0) n2part[((size_t)b * 8 + blockIdx.y) * NN + n] = s;
}

// ---------- gram v7: fp16 2-product asym, upper-tri tiles, fp16 D direct stores ----------
__global__ __launch_bounds__(256, 3)
void gram_v7_kernel(const ush* __restrict__ Yth, const ush* __restrict__ Ytl,
                    const float* __restrict__ n2part, const float* __restrict__ mask,
                    const float* __restrict__ posv, ush* __restrict__ Dp,
                    float* __restrict__ sigpart) {
  __shared__ ush lds[24576];           // 2 x 12288 dbuf (48 KB)
  __shared__ float sn2[256];
  __shared__ float spv[256];
  const int bid = blockIdx.x;
  const int logical = (bid & 7) * 72 + (bid >> 3);
  const int b = logical / 36;
  int t = logical - b * 36;
  int ty = 0;
  while (t >= 8 - ty) { t -= 8 - ty; ++ty; }
  const int tx = ty + t;
  const int i0 = ty * 128;
  const int j0 = tx * 128;
  {
    const int tt = threadIdx.x;
    const int nn = (tt < 128) ? (i0 + tt) : (j0 + tt - 128);
    const float pv = posv[b * NN + nn];
    float s = pv * pv;
    #pragma unroll
    for (int kb = 0; kb < 8; kb++) s += n2part[((size_t)b * 8 + kb) * NN + nn];
    sn2[tt] = s;
    spv[tt] = pv;
  }
  const ush* Ah = Yth + (size_t)b * NN * CH + (size_t)i0 * CH;
  const ush* Al = Ytl + (size_t)b * NN * CH + (size_t)i0 * CH;
  const ush* Bh = Yth + (size_t)b * NN * CH + (size_t)j0 * CH;
  f4 acc[4][4];
  const f4 z4 = {0.f, 0.f, 0.f, 0.f};
  #pragma unroll
  for (int mi = 0; mi < 4; mi++)
    #pragma unroll
    for (int ni = 0; ni < 4; ni++) acc[mi][ni] = z4;
  stageG(Ah, Al, Bh, CH, 0, lds);
  __syncthreads();
  int pb = 0;
  for (int kt = 32; kt < CH; kt += 32) {
    stageG(Ah, Al, Bh, CH, kt, lds + (pb ^ 1) * 12288);
    computeG(lds + pb * 12288, acc);
    __syncthreads();
    pb ^= 1;
  }
  computeG(lds + pb * 12288, acc);
  const int lane = threadIdx.x & 63;
  const int wid = threadIdx.x >> 6;
  const int wr = wid >> 1, wc = wid & 1;
  const int frow = lane & 15, hh = lane >> 4;
  const float scale = 3.0f / 257.0f;
  float lsum = 0.f;
  #pragma unroll
  for (int ni = 0; ni < 4; ni++) {
    const int jl = wc * 64 + ni * 16 + frow;
    const int j = j0 + jl;
    const float n2j = sn2[128 + jl];
    const float pj = spv[128 + jl];
    const float mkj = mask[b * NN + j];
    #pragma unroll
    for (int mi = 0; mi < 4; mi++) {
      const int il = wr * 64 + mi * 16 + hh * 4;
      ush dv[4];
      #pragma unroll
      for (int r = 0; r < 4; r++) {
        const int i = i0 + il + r;
        const float g = acc[mi][ni][r] + spv[il + r] * pj;
        const float D = scale * (sn2[il + r] + n2j - 2.0f * g);
        const float d = sqrtf(fmaxf(D, 1e-12f));
        const float mmv = mask[b * NN + i] * mkj;
        const float wd = d * mmv;
        lsum += wd * mmv;
        dv[r] = f2h(wd);
      }
      if (ty != tx) {
        uint2 mr;
        mr.x = (unsigned)dv[0] | ((unsigned)dv[1] << 16);
        mr.y = (unsigned)dv[2] | ((unsigned)dv[3] << 16);
        *(uint2*)&Dp[((size_t)b * NN + j) * NN + i0 + il] = mr;
      }
      #pragma unroll
      for (int r = 0; r < 4; r++) {
        const unsigned v = dv[r];
        const unsigned vp = (unsigned)__shfl_xor((int)v, 1, 64);
        if ((frow & 1) == 0)
          *(unsigned*)&Dp[((size_t)b * NN + i0 + il + r) * NN + j] = v | (vp << 16);
      }
    }
  }
  if (ty != tx) lsum *= 2.0f;
  #pragma unroll
  for (int off = 32; off > 0; off >>= 1) lsum += __shfl_down(lsum, off, 64);
  __syncthreads();
  float* rbuf = (float*)lds;
  if (lane == 0) rbuf[wid] = lsum;
  __syncthreads();
  if (threadIdx.x == 0)
    sigpart[(size_t)b * 64 + ty * 8 + tx] = rbuf[0] + rbuf[1] + rbuf[2] + rbuf[3];
}

// ---------- expw v4: sigma reduce inlined; read fp16 D, write W' fp16 plane ----------
__global__ void expw4_kernel(const ush* __restrict__ Dp, const float* __restrict__ mask,
                             const float* __restrict__ sigpart, const float* __restrict__ msum,
                             ush* __restrict__ Wp) {
  __shared__ float sfb;
  const int b = blockIdx.y, n = blockIdx.x;
  const int t = threadIdx.x;
  {
    float v = 0.f;
    if (t < 64) {
      const int sy = t >> 3, sx = t & 7;
      if (sy <= sx) v = sigpart[b * 64 + t];
    }
    v = blockReduceSum(v);
    if (t == 0) { const float ms = msum[b]; sfb = -10.0f * ms * ms / v; }
  }
  __syncthreads();
  const float fb = sfb;
  const float mn = mask[b * NN + n];
  const size_t roff = ((size_t)b * NN + n) * NN;
  const float4 mk = ((const float4*)(mask + b * NN))[t];
  const ushort4 dp = *(const ushort4*)&Dp[roff + t * 4];
  const float w0 = __expf(fb * h2f(dp.x)) * mn * mk.x;
  const float w1 = __expf(fb * h2f(dp.y)) * mn * mk.y;
  const float w2 = __expf(fb * h2f(dp.z)) * mn * mk.z;
  const float w3 = __expf(fb * h2f(dp.w)) * mn * mk.w;
  const float s = blockReduceSum(w0 + w1 + w2 + w3);
  float v0 = -w0, v1 = -w1, v2 = -w2, v3 = -w3;
  if ((n >> 2) == t) {
    const int r = n & 3;
    if (r == 0) v0 += s; else if (r == 1) v1 += s; else if (r == 2) v2 += s; else v3 += s;
  }
  ushort4 h4;
  h4.x = f2h(v0); h4.y = f2h(v1); h4.z = f2h(v2); h4.w = f2h(v3);
  *(ushort4*)&Wp[roff + t * 4] = h4;
}

// ---------- cvall v4 (fp16): C[g] = Kis[g]*(W[g]@X)*mask; direct fragment stores ----------
__global__ __launch_bounds__(256, 3)
void cvall_kernel(const ush* __restrict__ Ap, const ush* __restrict__ Bth,
                  const ush* __restrict__ Btl, const float* __restrict__ mask,
                  const float* __restrict__ Kis, unsigned int* __restrict__ Cpack,
                  ush* __restrict__ C2h, ush* __restrict__ C2l) {
  __shared__ ush lds[24576];
  const int bid = blockIdx.x;
  const int logical = (bid & 7) * 96 + (bid >> 3);
  const int b = logical / 48;
  const int inner = logical - b * 48;
  const int c0g = inner & 7;
  const int r0g = inner >> 3;
  const int r0 = r0g * 128;
  const int c0 = c0g * 128;
  const ush* Aq = Ap + (size_t)r0 * CH;
  const ush* Bh = Bth + (size_t)b * NN * CH + (size_t)c0 * CH;
  const ush* Bl = Btl + (size_t)b * NN * CH + (size_t)c0 * CH;
  f4 acc[4][4];
  const f4 z4 = {0.f, 0.f, 0.f, 0.f};
  #pragma unroll
  for (int mi = 0; mi < 4; mi++)
    #pragma unroll
    for (int ni = 0; ni < 4; ni++) acc[mi][ni] = z4;
  stageCV(Aq, CH, Bh, Bl, CH, 0, lds);
  __syncthreads();
  int pb = 0;
  for (int kt = 32; kt < CH; kt += 32) {
    stageCV(Aq, CH, Bh, Bl, CH, kt, lds + (pb ^ 1) * 12288);
    computeCV(lds + pb * 12288, acc);
    __syncthreads();
    pb ^= 1;
  }
  computeCV(lds + pb * 12288, acc);
  const int lane = threadIdx.x & 63;
  const int wid = threadIdx.x >> 6;
  const int wr = wid >> 1, wc = wid & 1;
  const int frow = lane & 15, hh = lane >> 4;
  const float alpha = Kis[r0g >> 1];
  #pragma unroll
  for (int ni = 0; ni < 4; ni++) {
    const int jl = wc * 64 + ni * 16 + frow;
    const int col = c0 + jl;
    const float am = alpha * mask[b * NN + col];
    #pragma unroll
    for (int mi = 0; mi < 4; mi++) {
      const int il = wr * 64 + mi * 16 + hh * 4;
      #pragma unroll
      for (int r = 0; r < 4; r++) {
        const int row = r0 + il + r;
        const float v = acc[mi][ni][r] * am;
        const ush h = f2h(v);
        const ush l = f2h(v - h2f(h));
        const unsigned pv = (unsigned)h | ((unsigned)l << 16);
        const unsigned pvp = (unsigned)__shfl_xor((int)pv, 1, 64);
        if ((frow & 1) == 0) {
          if (r0g < 4) {
            uint2 w2; w2.x = pv; w2.y = pvp;
            *(uint2*)&Cpack[((size_t)b * 512 + row) * NN + col] = w2;
          } else {
            const size_t obase = ((size_t)b * 256 + (row - 512)) * NN + col;
            const unsigned hw = (pv & 0xffffu) | (pvp << 16);
            const unsigned lw = (pv >> 16) | (pvp & 0xffff0000u);
            *(unsigned*)&C2h[obase] = hw;
            *(unsigned*)&C2l[obase] = lw;
          }
        }
      }
    }
  }
}

// ---------- mm1 v6 (fp16): out = X@W' + add(packed) ----------
// OUTMODE 0: row-major fp16 split out (+STATS on o)
// OUTMODE 2: outF = zin - 0.01*o (fp32) + transposed fp16 Z-splits [NN][CH] (+STATS on val)
template <int OUTMODE, int STATS>
__global__ __launch_bounds__(256, 5)
void mm1_v6_kernel(const ush* __restrict__ Xh, const ush* __restrict__ Xl, const size_t xStride,
                   const ush* __restrict__ Wp,
                   const unsigned int* __restrict__ addp, const size_t aStride,
                   const float* __restrict__ zin, const float* __restrict__ mask,
                   float* __restrict__ outF, ush* __restrict__ outH, ush* __restrict__ outL,
                   float* __restrict__ statS1, float* __restrict__ statS2) {
  __shared__ ush lds[16384];
  const int bid = blockIdx.x;
  const int logical = (bid & 7) * 64 + (bid >> 3);
  const int b = logical >> 5;
  const int inner = logical & 31;
  const int n0 = (inner & 7) * 128;
  const int r0 = (inner >> 3) * 64;
  const ush* Ah = Xh + (size_t)b * xStride + (size_t)r0 * NN;
  const ush* Al = Xl + (size_t)b * xStride + (size_t)r0 * NN;
  const ush* Bp = Wp + (size_t)b * NN * NN + (size_t)n0 * NN;
  f4 acc[4][2];
  const f4 z4 = {0.f, 0.f, 0.f, 0.f};
  #pragma unroll
  for (int mi = 0; mi < 4; mi++) { acc[mi][0] = z4; acc[mi][1] = z4; }
  stageMM(Ah, Al, NN, Bp, NN, 0, lds);
  __syncthreads();
  int pb = 0;
  for (int kt = 32; kt < NN; kt += 32) {
    stageMM(Ah, Al, NN, Bp, NN, kt, lds + (pb ^ 1) * 8192);
    computeMM(lds + pb * 8192, acc);
    __syncthreads();
    pb ^= 1;
  }
  computeMM(lds + pb * 8192, acc);
  const int lane = threadIdx.x & 63;
  const int wid = threadIdx.x >> 6;
  const int frow = lane & 15, hh = lane >> 4;
  float a1[4][4];
  float a2[4][4];
  if (STATS) {
    #pragma unroll
    for (int mi = 0; mi < 4; mi++)
      #pragma unroll
      for (int r = 0; r < 4; r++) { a1[mi][r] = 0.f; a2[mi][r] = 0.f; }
  }
  __syncthreads();
  unsigned int* tl = (unsigned int*)lds;   // [128][64] swizzled packed splits
  #pragma unroll
  for (int ni = 0; ni < 2; ni++) {
    const int jl = wid * 32 + ni * 16 + frow;
    const int col = n0 + jl;
    const float mk = STATS ? mask[b * NN + col] : 0.f;
    #pragma unroll
    for (int mi = 0; mi < 4; mi++) {
      const int il = mi * 16 + hh * 4;
      unsigned int pv[4];
      #pragma unroll
      for (int r = 0; r < 4; r++) {
        const int row = r0 + il + r;
        const unsigned int av = addp[(size_t)b * aStride + (size_t)row * NN + col];
        const float o = acc[mi][ni][r] + h2f((ush)(av & 0xffffu)) + h2f((ush)(av >> 16));
        float val;
        if (OUTMODE == 2) {
          const size_t ooff = (size_t)b * CH * NN + (size_t)row * NN + col;
          val = zin[ooff] - 0.01f * o;
          outF[ooff] = val;
        } else {
          val = o;
        }
        if (STATS) { a1[mi][r] += val * mk; a2[mi][r] += val * val * mk; }
        const ush h = f2h(val);
        const ush l = f2h(val - h2f(h));
        pv[r] = (unsigned int)h | ((unsigned int)l << 16);
      }
      const int slot = (il >> 2) ^ (jl & 15);
      *(uint4*)&tl[jl * 64 + slot * 4] = *(uint4*)pv;
    }
  }
  __syncthreads();
  if (OUTMODE == 0) {
    const int rrow = threadIdx.x >> 2;
    const int rch = (threadIdx.x & 3) * 32;
    const size_t obase = ((size_t)b * 256 + r0 + rrow) * NN + n0 + rch;
    #pragma unroll
    for (int g = 0; g < 4; g++) {
      unsigned int hw[4], lw[4];
      #pragma unroll
      for (int q = 0; q < 4; q++) {
        unsigned int h2[2], l2[2];
        #pragma unroll
        for (int e = 0; e < 2; e++) {
          const int jl = rch + g * 8 + q * 2 + e;
          const int slot = (rrow >> 2) ^ (jl & 15);
          const unsigned int v = tl[jl * 64 + slot * 4 + (rrow & 3)];
          h2[e] = v & 0xffffu; l2[e] = v >> 16;
        }
        hw[q] = h2[0] | (h2[1] << 16);
        lw[q] = l2[0] | (l2[1] << 16);
      }
      *(uint4*)&outH[obase + g * 8] = *(uint4*)hw;
      *(uint4*)&outL[obase + g * 8] = *(uint4*)lw;
    }
  } else {
    const int nloc = threadIdx.x >> 1;
    const int ch0 = (threadIdx.x & 1) * 32;
    #pragma unroll
    for (int half = 0; half < 2; half++) {
      unsigned int hw[8], lw[8];
      #pragma unroll
      for (int q = 0; q < 8; q++) {
        const int ila = ch0 + half * 16 + q * 2;
        const int ilb = ila + 1;
        const unsigned int va = tl[nloc * 64 + (((ila >> 2) ^ (nloc & 15)) << 2) + (ila & 3)];
        const unsigned int vb = tl[nloc * 64 + (((ilb >> 2) ^ (nloc & 15)) << 2) + (ilb & 3)];
        hw[q] = (va & 0xffffu) | (vb << 16);
        lw[q] = (va >> 16) | (vb & 0xffff0000u);
      }
      const size_t zoff = ((size_t)b * NN + n0 + nloc) * CH + r0 + ch0 + half * 16;
      *(uint4*)&outH[zoff] = *(uint4*)&hw[0];
      *(uint4*)&outH[zoff + 8] = *(uint4*)&hw[4];
      *(uint4*)&outL[zoff] = *(uint4*)&lw[0];
      *(uint4*)&outL[zoff + 8] = *(uint4*)&lw[4];
    }
  }
  if (STATS) {
    #pragma unroll
    for (int mi = 0; mi < 4; mi++)
      #pragma unroll
      for (int r = 0; r < 4; r++) {
        #pragma unroll
        for (int d = 1; d < 16; d <<= 1) {
          a1[mi][r] += __shfl_xor(a1[mi][r], d, 64);
          a2[mi][r] += __shfl_xor(a2[mi][r], d, 64);
        }
      }
    __syncthreads();
    float* s1b = (float*)lds;
    float* s2b = s1b + 256;
    if (frow == 0) {
      #pragma unroll
      for (int mi = 0; mi < 4; mi++)
        #pragma unroll
        for (int r = 0; r < 4; r++) {
          const int row = mi * 16 + hh * 4 + r;
          s1b[wid * 64 + row] = a1[mi][r];
          s2b[wid * 64 + row] = a2[mi][r];
        }
    }
    __syncthreads();
    if (threadIdx.x < 64) {
      const int row = threadIdx.x;
      const float p1 = s1b[row] + s1b[64 + row] + s1b[128 + row] + s1b[192 + row];
      const float p2 = s2b[row] + s2b[64 + row] + s2b[128 + row] + s2b[192 + row];
      const int nblk = n0 >> 7;
      statS1[((size_t)b * CH + r0 + row) * 8 + nblk] = p1;
      statS2[((size_t)b * CH + r0 + row) * 8 + nblk] = p2;
    }
  }
}

// ---------- csq: partial col sums of ((U-rmean)*mask)^2; rmean inlined ----------
__global__ void csq_kernel(const ush* __restrict__ Uh, const ush* __restrict__ Ul,
                           const float* __restrict__ mask, const float* __restrict__ statS1,
                           const float* __restrict__ msum, float* __restrict__ part) {
  __shared__ float srm[16];
  const int b = blockIdx.y, cc = blockIdx.x;
  if (threadIdx.x < 16) {
    const size_t base = ((size_t)b * CH + cc * 16 + threadIdx.x) * 8;
    float S1 = 0.f;
    #pragma unroll
    for (int k = 0; k < 8; k++) S1 += statS1[base + k];
    srm[threadIdx.x] = S1 / msum[b];
  }
  __syncthreads();
  const int n = threadIdx.x * 4;
  const float4 m4 = *(const float4*)&mask[b * NN + n];
  float4 s4 = {0.f, 0.f, 0.f, 0.f};
  for (int r = 0; r < 16; r++) {
    const int c = cc * 16 + r;
    const float rm = srm[r];
    const size_t uoff = ((size_t)b * 256 + c) * NN + n;
    const ushort4 uh = *(const ushort4*)&Uh[uoff];
    const ushort4 ul = *(const ushort4*)&Ul[uoff];
    float a;
    a = (h2f(uh.x) + h2f(ul.x) - rm) * m4.x; s4.x += a * a;
    a = (h2f(uh.y) + h2f(ul.y) - rm) * m4.y; s4.y += a * a;
    a = (h2f(uh.z) + h2f(ul.z) - rm) * m4.z; s4.z += a * a;
    a = (h2f(uh.w) + h2f(ul.w) - rm) * m4.w; s4.w += a * a;
  }
  *(float4*)&part[((size_t)(b * 16 + cc)) * NN + n] = s4;
}

// ---------- tsplitN2: A=relu((U-rmean)*mask*rs); rmean+rs inlined ----------
__global__ void tsplitN2_kernel(const ush* __restrict__ Uh, const ush* __restrict__ Ul,
                                const float* __restrict__ mask, const float* __restrict__ statS1,
                                const float* __restrict__ msum, const float* __restrict__ part,
                                ush* __restrict__ Th, ush* __restrict__ Tl) {
  __shared__ float t[32][65];
  __shared__ float srm[32];
  __shared__ float srsl[64];
  const int b = blockIdx.z;
  const int n0 = blockIdx.x * 64;
  const int k0 = blockIdx.y * 32;
  const int tid = threadIdx.x;
  if (tid < 32) {
    const size_t base = ((size_t)b * CH + k0 + tid) * 8;
    float S1 = 0.f;
    #pragma unroll
    for (int k = 0; k < 8; k++) S1 += statS1[base + k];
    srm[tid] = S1 / msum[b];
  } else if (tid < 96) {
    const int n = n0 + tid - 32;
    float s = 0.001f;
    #pragma unroll
    for (int cc = 0; cc < 16; cc++) s += part[((size_t)(b * 16 + cc)) * NN + n];
    srsl[tid - 32] = 1.0f / sqrtf(s);
  }
  __syncthreads();
  const int lr = tid >> 3;
  const int lc = (tid & 7) * 8;
  const int gc = k0 + lr;
  const float rm = srm[lr];
  const float4 ma = *(const float4*)&mask[b * NN + n0 + lc];
  const float4 mb = *(const float4*)&mask[b * NN + n0 + lc + 4];
  const size_t uoff = ((size_t)b * 256 + gc) * NN + n0 + lc;
  const ushort4 ha = *(const ushort4*)&Uh[uoff];
  const ushort4 hb = *(const ushort4*)&Uh[uoff + 4];
  const ushort4 la = *(const ushort4*)&Ul[uoff];
  const ushort4 lb = *(const ushort4*)&Ul[uoff + 4];
  t[lr][lc + 0] = fmaxf((h2f(ha.x) + h2f(la.x) - rm) * ma.x * srsl[lc + 0], 0.f);
  t[lr][lc + 1] = fmaxf((h2f(ha.y) + h2f(la.y) - rm) * ma.y * srsl[lc + 1], 0.f);
  t[lr][lc + 2] = fmaxf((h2f(ha.z) + h2f(la.z) - rm) * ma.z * srsl[lc + 2], 0.f);
  t[lr][lc + 3] = fmaxf((h2f(ha.w) + h2f(la.w) - rm) * ma.w * srsl[lc + 3], 0.f);
  t[lr][lc + 4] = fmaxf((h2f(hb.x) + h2f(lb.x) - rm) * mb.x * srsl[lc + 4], 0.f);
  t[lr][lc + 5] = fmaxf((h2f(hb.y) + h2f(lb.y) - rm) * mb.y * srsl[lc + 5], 0.f);
  t[lr][lc + 6] = fmaxf((h2f(hb.z) + h2f(lb.z) - rm) * mb.z * srsl[lc + 6], 0.f);
  t[lr][lc + 7] = fmaxf((h2f(hb.w) + h2f(lb.w) - rm) * mb.w * srsl[lc + 7], 0.f);
  __syncthreads();
  const int on = tid >> 2;
  const int ok = (tid & 3) * 8;
  ush hv[8], lv[8];
  #pragma unroll
  for (int j = 0; j < 8; j++) {
    const float v = t[ok + j][on];
    hv[j] = f2h(v); lv[j] = f2h(v - h2f(hv[j]));
  }
  const size_t off = ((size_t)b * NN + n0 + on) * CH + k0 + ok;
  *(ushort4*)&Th[off] = *(ushort4*)&hv[0];
  *(ushort4*)&Th[off + 4] = *(ushort4*)&hv[4];
  *(ushort4*)&Tl[off] = *(ushort4*)&lv[0];
  *(ushort4*)&Tl[off + 4] = *(ushort4*)&lv[4];
}

// ---------- Zout = (Wend @ Z)*mask; write + centered copy ----------
__global__ void zout_kernel(const float* __restrict__ Z, const float* __restrict__ Wend,
                            const float* __restrict__ mask, float* __restrict__ outZ,
                            float* __restrict__ Zcent) {
  const int b = blockIdx.x;
  __shared__ float w[3 * CH];
  for (int i = threadIdx.x; i < 3 * CH; i += 256) w[i] = Wend[i];
  __syncthreads();
  float a[3][4];
  #pragma unroll
  for (int j = 0; j < 4; j++) { a[0][j] = 0.f; a[1][j] = 0.f; a[2][j] = 0.f; }
  const float* Zb = Z + (size_t)b * CH * NN;
  for (int c = 0; c < CH; c++) {
    const float w0 = w[c], w1 = w[CH + c], w2 = w[2 * CH + c];
    #pragma unroll
    for (int j = 0; j < 4; j++) {
      float zv = Zb[(size_t)c * NN + threadIdx.x + j * 256];
      a[0][j] += w0 * zv; a[1][j] += w1 * zv; a[2][j] += w2 * zv;
    }
  }
  float sum[3] = {0.f, 0.f, 0.f};
  #pragma unroll
  for (int j = 0; j < 4; j++) {
    const int n = threadIdx.x + j * 256;
    const float mv = mask[b * NN + n];
    #pragma unroll
    for (int o = 0; o < 3; o++) {
      a[o][j] *= mv;
      outZ[((size_t)b * 3 + o) * NN + n] = a[o][j];
      sum[o] += a[o][j];
    }
  }
  for (int o = 0; o < 3; o++) {
    float s = blockReduceSum(sum[o]);
    const float mean = s * (1.0f / NN);
    #pragma unroll
    for (int j = 0; j < 4; j++) {
      const int n = threadIdx.x + j * 256;
      Zcent[((size_t)b * 3 + o) * NN + n] = a[o][j] - mean;
    }
  }
}

// ---------- final distances ----------
__global__ void dist_kernel(const float* __restrict__ Zcent, float* __restrict__ outD) {
  const int b = blockIdx.z;
  const int n = blockIdx.y;
  const int m = blockIdx.x * 256 + threadIdx.x;
  const float* Zb = Zcent + (size_t)b * 3 * NN;
  const float x0 = Zb[n], x1 = Zb[NN + n], x2 = Zb[2 * NN + n];
  const float d0 = x0 - Zb[m], d1 = x1 - Zb[NN + m], d2 = x2 - Zb[2 * NN + m];
  const float D = d0 * d0 + d1 * d1 + d2 * d2;
  outD[((size_t)b * NN + n) * NN + m] = sqrtf(fmaxf(D, 1e-12f));
}

extern "C" void kernel_launch(void* const* d_in, const int* in_sizes, int n_in,
                              void* d_out, int out_size, void* d_ws, size_t ws_size,
                              hipStream_t stream) {
  const float* Zin  = (const float*)d_in[0];
  const float* mask = (const float*)d_in[1];
  const float* K0   = (const float*)d_in[2];
  const float* Knet = (const float*)d_in[3];
  const float* W    = (const float*)d_in[4];
  const float* Wend = (const float*)d_in[5];
  float* out = (float*)d_out;

  // d_out dist region (64 MB): Wp fp16 (32 MB) | Dp fp16 (32 MB)
  ush* Wp = (ush*)out;
  ush* Dp = Wp + (size_t)BB * NN * NN;
  float* outZ = out + (size_t)BB * NN * NN;

  float* p = (float*)d_ws;
  // union: gram phase {Yth | Ytl fp16 [NN][CH]}; GEMM phase {Cpack u32 | C2h | C2l fp16}
  float* uni = p; p += (size_t)BB * 768 * NN;     // 50.33 MB
  ush* Yth = (ush*)uni;
  ush* Ytl = Yth + (size_t)BB * NN * CH;
  unsigned int* Cpack = (unsigned int*)uni;
  ush* C2h = (ush*)(uni + (size_t)BB * 512 * NN);
  ush* C2l = C2h + (size_t)BB * 256 * NN;

  float* Zcur = p; p += (size_t)BB * CH * NN;
  ush* Thb = (ush*)p; p += (size_t)BB * NN * CH / 2;   // T / A-splits (shared)
  ush* Tlb = (ush*)p; p += (size_t)BB * NN * CH / 2;
  ush* Zsh = (ush*)p; p += (size_t)BB * NN * CH / 2;   // Z transposed fp16 splits
  ush* Zsl = (ush*)p; p += (size_t)BB * NN * CH / 2;
  ush* Wm = (ush*)p; p += (size_t)18 * CH * CH / 2;
  ush* Wt = (ush*)p; p += (size_t)18 * CH * CH / 2;
  float* msum  = p; p += BB;
  float* posv  = p; p += BB * NN;
  float* sigp  = p; p += BB * 64;
  float* statS1= p; p += (size_t)BB * CH * 8;
  float* statS2= p; p += (size_t)BB * CH * 8;
  float* n2part= p; p += (size_t)BB * 8 * NN;
  float* partb = p; p += (size_t)BB * 16 * NN;
  float* Zcent = p; p += BB * 3 * NN;

  const dim3 gtsZ(NN / 64, CH / 32, BB);
  const size_t sC = (size_t)512 * NN;
  const size_t sT = (size_t)CH * NN;

  masksum_kernel<<<BB, 256, 0, stream>>>(mask, msum, posv);
  wprep_kernel<<<dim3(16, 18), 256, 0, stream>>>(W, Wm, Wt);
  k0_kernel<<<dim3(CH / 8, BB), 256, 0, stream>>>(Zin, K0, mask, Zcur, statS1, statS2);
  tsplitZ_kernel<<<gtsZ, 256, 0, stream>>>(Zcur, Zsh, Zsl);

  for (int layer = 0; layer < NLAYERS; layer++) {
    tsplitY2_kernel<<<gtsZ, 256, 0, stream>>>(Zsh, Zsl, mask, statS1, statS2, msum,
                                              Yth, Ytl, n2part);
    gram_v7_kernel<<<576, 256, 0, stream>>>(Yth, Ytl, n2part, mask, posv, Dp, sigp);
    expw4_kernel<<<dim3(NN, BB), 256, 0, stream>>>(Dp, mask, sigp, msum, Wp);

    const ush* Am = Wm + (size_t)layer * 3 * CH * CH;
    const ush* At = Wt + (size_t)layer * 3 * CH * CH;
    const float* Ki = Knet + layer * 3;

    // ---- Ai = C0 + (C1 + C2@L)@L, C = Ki*(Wi@Z)*mask, L rows = W' ----
    cvall_kernel<<<768, 256, 0, stream>>>(Am, Zsh, Zsl, mask, Ki, Cpack, C2h, C2l);
    mm1_v6_kernel<0, 0><<<512, 256, 0, stream>>>(C2h, C2l, sT, Wp,
        Cpack + (size_t)256 * NN, sC, nullptr, nullptr, nullptr, Thb, Tlb, nullptr, nullptr);
    mm1_v6_kernel<0, 1><<<512, 256, 0, stream>>>(Thb, Tlb, sT, Wp,
        Cpack, sC, nullptr, mask, nullptr, C2h, C2l, statS1, statS2);

    csq_kernel<<<dim3(16, BB), 256, 0, stream>>>(C2h, C2l, mask, statS1, msum, partb);
    tsplitN2_kernel<<<gtsZ, 256, 0, stream>>>(C2h, C2l, mask, statS1, msum, partb, Thb, Tlb);

    // ---- Z -= 0.01 * (C0 + (C1 + C2@L)@L), C = Ki*(Wi^T@A)*mask ----
    cvall_kernel<<<768, 256, 0, stream>>>(At, Thb, Tlb, mask, Ki, Cpack, C2h, C2l);
    mm1_v6_kernel<0, 0><<<512, 256, 0, stream>>>(C2h, C2l, sT, Wp,
        Cpack + (size_t)256 * NN, sC, nullptr, nullptr, nullptr, Thb, Tlb, nullptr, nullptr);
    mm1_v6_kernel<2, 1><<<512, 256, 0, stream>>>(Thb, Tlb, sT, Wp,
        Cpack, sC, Zcur, mask, Zcur, Zsh, Zsl, statS1, statS2);
  }

  zout_kernel<<<BB, 256, 0, stream>>>(Zcur, Wend, mask, outZ, Zcent);
  dist_kernel<<<dim3(NN / 256, NN, BB), 256, 0, stream>>>(Zcent, out);
}